// Round 1
// baseline (3578.144 us; speedup 1.0000x reference)
//
#include <hip/hip_runtime.h>
#include <math.h>

// CrossTransformer block, fp32 baseline (round 0: correctness first).
// B=4, SQ=1024, SK=2048, C=1024, H=16, DH=64, L=C.
// Outputs: out (B*SQ*C fp32) then energy (B*H*SQ*SK fp32), concatenated in d_out.

namespace {
constexpr int BB  = 4;
constexpr int SQ_ = 1024;
constexpr int SK_ = 2048;
constexpr int CC  = 1024;
constexpr int HH  = 16;
constexpr float SCALE  = 0.03125f;   // 1/sqrt(1024)
constexpr float LN_EPS = 1e-5f;
}

// ---------------- LayerNorm (+optional SiLU) ----------------
// one block (256 threads) per row
template<int NCOLS>
__global__ __launch_bounds__(256)
void ln_kernel(const float* __restrict__ x, const float* __restrict__ g,
               const float* __restrict__ b, float* __restrict__ out, int do_silu) {
    constexpr int PER = NCOLS / 256;
    const size_t row = blockIdx.x;
    const float* xr = x + row * NCOLS;
    float vals[PER];
    float s = 0.f, ss = 0.f;
#pragma unroll
    for (int i = 0; i < PER; ++i) {
        vals[i] = xr[threadIdx.x + i * 256];
        s += vals[i];
        ss += vals[i] * vals[i];
    }
    for (int off = 32; off > 0; off >>= 1) {
        s  += __shfl_down(s, off, 64);
        ss += __shfl_down(ss, off, 64);
    }
    __shared__ float red[10];
    const int wid = threadIdx.x >> 6, lane = threadIdx.x & 63;
    if (lane == 0) { red[wid] = s; red[wid + 4] = ss; }
    __syncthreads();
    if (threadIdx.x == 0) {
        const float ts  = red[0] + red[1] + red[2] + red[3];
        const float tss = red[4] + red[5] + red[6] + red[7];
        const float mu  = ts / NCOLS;
        const float var = tss / NCOLS - mu * mu;
        red[8] = mu;
        red[9] = rsqrtf(var + LN_EPS);
    }
    __syncthreads();
    const float mu = red[8], rstd = red[9];
    float* outr = out + row * NCOLS;
#pragma unroll
    for (int i = 0; i < PER; ++i) {
        const int c = threadIdx.x + i * 256;
        float y = (vals[i] - mu) * rstd * g[c] + b[c];
        if (do_silu) y = y / (1.f + __expf(-y));
        outr[c] = y;
    }
}

// ---------------- GEMM: C[M,N] = A[M,K] @ B[N,K]^T (+bias)(+residual) -----
// 64x64 tile, BK=16, 256 threads, 4x4 micro-tile per thread.
#define BM 64
#define BN 64
#define BKt 16

__global__ __launch_bounds__(256)
void gemm_bt(const float* __restrict__ A, const float* __restrict__ B,
             float* __restrict__ C, int M, int N, int K,
             const float* __restrict__ bias, const float* __restrict__ resid) {
    __shared__ float As[BKt][BM + 1];
    __shared__ float Bs[BKt][BN + 1];
    const int tid = threadIdx.x;
    const int tx = tid & 15, ty = tid >> 4;
    const int m0 = blockIdx.y * BM, n0 = blockIdx.x * BN;
    float acc[4][4] = {};
    for (int k0 = 0; k0 < K; k0 += BKt) {
        const int idx = tid * 4;
        const int r = idx >> 4;      // 0..63
        const int c = idx & 15;      // {0,4,8,12}
        const float4 a4 = *(const float4*)(A + (size_t)(m0 + r) * K + k0 + c);
        As[c + 0][r] = a4.x; As[c + 1][r] = a4.y; As[c + 2][r] = a4.z; As[c + 3][r] = a4.w;
        const float4 b4 = *(const float4*)(B + (size_t)(n0 + r) * K + k0 + c);
        Bs[c + 0][r] = b4.x; Bs[c + 1][r] = b4.y; Bs[c + 2][r] = b4.z; Bs[c + 3][r] = b4.w;
        __syncthreads();
#pragma unroll
        for (int kk = 0; kk < BKt; ++kk) {
            float a[4], bb[4];
#pragma unroll
            for (int i = 0; i < 4; ++i) a[i]  = As[kk][ty * 4 + i];
#pragma unroll
            for (int j = 0; j < 4; ++j) bb[j] = Bs[kk][tx * 4 + j];
#pragma unroll
            for (int i = 0; i < 4; ++i)
#pragma unroll
                for (int j = 0; j < 4; ++j)
                    acc[i][j] += a[i] * bb[j];
        }
        __syncthreads();
    }
#pragma unroll
    for (int i = 0; i < 4; ++i) {
        const int m = m0 + ty * 4 + i;
#pragma unroll
        for (int j = 0; j < 4; ++j) {
            const int n = n0 + tx * 4 + j;
            float v = acc[i][j];
            if (bias)  v += bias[n];
            if (resid) v += resid[(size_t)m * N + n];
            C[(size_t)m * N + n] = v;
        }
    }
}

// ------- Batched strided scores: C_z[M,N] = A_z[M,K] @ B_z[N,K]^T (raw) ----
// z = b*H + h; A_z = A + b*aStrB + h*aStrH (lda), same for B; C_z = C + z*cStrZ (ldc=N)
__global__ __launch_bounds__(256)
void bgemm_abt(const float* __restrict__ Abase, const float* __restrict__ Bbase,
               float* __restrict__ Cbase, int M, int N, int K,
               int lda, int ldb,
               long long aStrB, long long aStrH, long long bStrB, long long bStrH,
               long long cStrZ, int H) {
    const int z = blockIdx.z;
    const int b = z / H, h = z % H;
    const float* A = Abase + (size_t)b * aStrB + (size_t)h * aStrH;
    const float* B = Bbase + (size_t)b * bStrB + (size_t)h * bStrH;
    float* C = Cbase + (size_t)z * cStrZ;

    __shared__ float As[BKt][BM + 1];
    __shared__ float Bs[BKt][BN + 1];
    const int tid = threadIdx.x;
    const int tx = tid & 15, ty = tid >> 4;
    const int m0 = blockIdx.y * BM, n0 = blockIdx.x * BN;
    float acc[4][4] = {};
    for (int k0 = 0; k0 < K; k0 += BKt) {
        const int idx = tid * 4;
        const int r = idx >> 4;
        const int c = idx & 15;
        const float4 a4 = *(const float4*)(A + (size_t)(m0 + r) * lda + k0 + c);
        As[c + 0][r] = a4.x; As[c + 1][r] = a4.y; As[c + 2][r] = a4.z; As[c + 3][r] = a4.w;
        const float4 b4 = *(const float4*)(B + (size_t)(n0 + r) * ldb + k0 + c);
        Bs[c + 0][r] = b4.x; Bs[c + 1][r] = b4.y; Bs[c + 2][r] = b4.z; Bs[c + 3][r] = b4.w;
        __syncthreads();
#pragma unroll
        for (int kk = 0; kk < BKt; ++kk) {
            float a[4], bb[4];
#pragma unroll
            for (int i = 0; i < 4; ++i) a[i]  = As[kk][ty * 4 + i];
#pragma unroll
            for (int j = 0; j < 4; ++j) bb[j] = Bs[kk][tx * 4 + j];
#pragma unroll
            for (int i = 0; i < 4; ++i)
#pragma unroll
                for (int j = 0; j < 4; ++j)
                    acc[i][j] += a[i] * bb[j];
        }
        __syncthreads();
    }
#pragma unroll
    for (int i = 0; i < 4; ++i) {
        const int m = m0 + ty * 4 + i;
#pragma unroll
        for (int j = 0; j < 4; ++j) {
            const int n = n0 + tx * 4 + j;
            C[(size_t)m * N + n] = acc[i][j];
        }
    }
}

// ------------- Row stats for softmax: m' = max(e*scale), l = sum exp ------
template<int NCOLS>
__global__ __launch_bounds__(256)
void rowstat(const float* __restrict__ E, float* __restrict__ stats, float scale) {
    constexpr int PER = NCOLS / 256;
    const size_t row = blockIdx.x;
    const float* er = E + row * NCOLS;
    float v[PER];
    float mx = -INFINITY;
#pragma unroll
    for (int i = 0; i < PER; ++i) {
        v[i] = er[threadIdx.x + i * 256] * scale;
        mx = fmaxf(mx, v[i]);
    }
    for (int off = 32; off > 0; off >>= 1) mx = fmaxf(mx, __shfl_xor(mx, off, 64));
    __shared__ float red[8];
    const int wid = threadIdx.x >> 6, lane = threadIdx.x & 63;
    if (lane == 0) red[wid] = mx;
    __syncthreads();
    const float mAll = fmaxf(fmaxf(red[0], red[1]), fmaxf(red[2], red[3]));
    float sum = 0.f;
#pragma unroll
    for (int i = 0; i < PER; ++i) sum += __expf(v[i] - mAll);
    for (int off = 32; off > 0; off >>= 1) sum += __shfl_xor(sum, off, 64);
    if (lane == 0) red[4 + wid] = sum;
    __syncthreads();
    if (threadIdx.x == 0) {
        stats[row * 2]     = mAll;
        stats[row * 2 + 1] = red[4] + red[5] + red[6] + red[7];
    }
}

// ------- Batched PV: O_z[M,64] = softmax-P_z[M,K] @ V_z[K,64] --------------
// P element = exp(e*scale - m[row]); epilogue multiplies 1/l[row].
__global__ __launch_bounds__(256)
void bgemm_pv(const float* __restrict__ Pbase, const float* __restrict__ Vbase,
              float* __restrict__ Obase, int M, int K,
              long long pStrZ, int ldp,
              long long vStrB, long long vStrH, int ldv,
              long long oStrB, long long oStrH, int ldo, int H,
              const float* __restrict__ stats, float scale) {
    const int z = blockIdx.z;
    const int b = z / H, h = z % H;
    const float* P = Pbase + (size_t)z * pStrZ;
    const float* V = Vbase + (size_t)b * vStrB + (size_t)h * vStrH;
    float* O = Obase + (size_t)b * oStrB + (size_t)h * oStrH;
    const float* st = stats + (size_t)z * M * 2;

    __shared__ float Ps[BKt][BM + 1];
    __shared__ float Vs[BKt][BN + 1];
    const int tid = threadIdx.x;
    const int tx = tid & 15, ty = tid >> 4;
    const int m0 = blockIdx.y * BM;   // n0 = 0 (N = 64 exactly one tile)
    float acc[4][4] = {};
    for (int k0 = 0; k0 < K; k0 += BKt) {
        {
            const int idx = tid * 4;
            const int r = idx >> 4;      // 0..63 (row within m-tile)
            const int c = idx & 15;
            const float mrow = st[(size_t)(m0 + r) * 2];
            const float4 a4 = *(const float4*)(P + (size_t)(m0 + r) * ldp + k0 + c);
            Ps[c + 0][r] = __expf(a4.x * scale - mrow);
            Ps[c + 1][r] = __expf(a4.y * scale - mrow);
            Ps[c + 2][r] = __expf(a4.z * scale - mrow);
            Ps[c + 3][r] = __expf(a4.w * scale - mrow);
        }
        {
            const int idx = tid * 4;
            const int r = idx >> 6;      // 0..15 (k within tile)
            const int c = idx & 63;      // col 0..63
            const float4 v4 = *(const float4*)(V + (size_t)(k0 + r) * ldv + c);
            Vs[r][c + 0] = v4.x; Vs[r][c + 1] = v4.y; Vs[r][c + 2] = v4.z; Vs[r][c + 3] = v4.w;
        }
        __syncthreads();
#pragma unroll
        for (int kk = 0; kk < BKt; ++kk) {
            float a[4], bb[4];
#pragma unroll
            for (int i = 0; i < 4; ++i) a[i]  = Ps[kk][ty * 4 + i];
#pragma unroll
            for (int j = 0; j < 4; ++j) bb[j] = Vs[kk][tx * 4 + j];
#pragma unroll
            for (int i = 0; i < 4; ++i)
#pragma unroll
                for (int j = 0; j < 4; ++j)
                    acc[i][j] += a[i] * bb[j];
        }
        __syncthreads();
    }
#pragma unroll
    for (int i = 0; i < 4; ++i) {
        const int m = m0 + ty * 4 + i;
        const float rl = 1.f / st[(size_t)m * 2 + 1];
#pragma unroll
        for (int j = 0; j < 4; ++j) {
            const int n = tx * 4 + j;
            O[(size_t)m * ldo + n] = acc[i][j] * rl;
        }
    }
}

extern "C" void kernel_launch(void* const* d_in, const int* in_sizes, int n_in,
                              void* d_out, int out_size, void* d_ws, size_t ws_size,
                              hipStream_t stream) {
    const float* queries  = (const float*)d_in[0];   // (4,1024,1024)
    const float* contexts = (const float*)d_in[1];   // (4,2048,1024)
    const float* sa_ln_g  = (const float*)d_in[2];
    const float* sa_ln_b  = (const float*)d_in[3];
    const float* sa_qkv_w = (const float*)d_in[4];   // (3072,1024)
    const float* sa_out_w = (const float*)d_in[5];   // (1024,1024)
    const float* sa_out_b = (const float*)d_in[6];
    const float* ca_ln_g  = (const float*)d_in[7];
    const float* ca_ln_b  = (const float*)d_in[8];
    const float* ca_q_w   = (const float*)d_in[9];
    const float* ca_k_w   = (const float*)d_in[10];
    const float* ca_v_w   = (const float*)d_in[11];
    const float* ca_out_w = (const float*)d_in[12];
    const float* ca_out_b = (const float*)d_in[13];
    const float* ff_ln1_g = (const float*)d_in[14];
    const float* ff_ln1_b = (const float*)d_in[15];
    const float* ff_w1    = (const float*)d_in[16];  // (2048,1024)
    const float* ff_ln2_g = (const float*)d_in[17];  // (2048)
    const float* ff_ln2_b = (const float*)d_in[18];
    const float* ff_w2    = (const float*)d_in[19];  // (1024,2048)

    float* out    = (float*)d_out;                        // 4M floats
    float* energy = out + (size_t)BB * SQ_ * CC;          // 128M floats (also SA-score scratch)

    // Workspace layout (floats). Total 32M + 128K floats ~= 135 MB.
    float* ws = (float*)d_ws;
    float* A_buf = ws;                       // 8M floats: LN outputs; aliases o_buf (D)
    float* B_buf = ws + (size_t)8  * 1024 * 1024;  // 12M: qkv; later q_ca(4M)+k_ca(8M)
    float* C_buf = ws + (size_t)20 * 1024 * 1024;  // 8M:  v_ca; later ffn mid
    float* E_buf = ws + (size_t)28 * 1024 * 1024;  // 4M:  x1; later x2 (in-place resid)
    float* G_buf = ws + (size_t)32 * 1024 * 1024;  // 128K floats: row stats
    float* D_buf = A_buf;                    // o_buf alias (A dead while D live)

    const int M1 = BB * SQ_;   // 4096
    const int M2 = BB * SK_;   // 8192
    const dim3 thr(256);

    // ---- Self attention ----
    // 1. h = LN(queries)
    ln_kernel<1024><<<M1, thr, 0, stream>>>(queries, sa_ln_g, sa_ln_b, A_buf, 0);
    // 2. qkv = h @ sa_qkv_w^T  (4096 x 3072)
    gemm_bt<<<dim3(3072 / BN, M1 / BM), thr, 0, stream>>>(A_buf, sa_qkv_w, B_buf,
                                                          M1, 3072, 1024, nullptr, nullptr);
    // 3. scores = Q @ K^T  per (b,h), into energy region as scratch (64M floats)
    bgemm_abt<<<dim3(SQ_ / BN, SQ_ / BM, BB * HH), thr, 0, stream>>>(
        B_buf, B_buf + 64, energy, SQ_, SQ_, 64,
        3072, 3072,
        (long long)SQ_ * 3072, 192, (long long)SQ_ * 3072, 192,
        (long long)SQ_ * SQ_, HH);
    // 4. row stats
    rowstat<1024><<<BB * HH * SQ_, thr, 0, stream>>>(energy, G_buf, SCALE);
    // 5. o = softmax(scores) @ V
    bgemm_pv<<<dim3(1, SQ_ / BM, BB * HH), thr, 0, stream>>>(
        energy, B_buf + 128, D_buf, SQ_, SQ_,
        (long long)SQ_ * SQ_, SQ_,
        (long long)SQ_ * 3072, 192, 3072,
        (long long)SQ_ * CC, 64, CC, HH, G_buf, SCALE);
    // 6. x1 = o @ sa_out_w^T + b + queries
    gemm_bt<<<dim3(CC / BN, M1 / BM), thr, 0, stream>>>(D_buf, sa_out_w, E_buf,
                                                        M1, CC, CC, sa_out_b, queries);

    // ---- Cross attention ----
    // 7. h2 = LN(x1)
    ln_kernel<1024><<<M1, thr, 0, stream>>>(E_buf, ca_ln_g, ca_ln_b, A_buf, 0);
    float* q_ca = B_buf;
    float* k_ca = B_buf + (size_t)4 * 1024 * 1024;
    float* v_ca = C_buf;
    // 8. q_ca = h2 @ ca_q_w^T
    gemm_bt<<<dim3(CC / BN, M1 / BM), thr, 0, stream>>>(A_buf, ca_q_w, q_ca,
                                                        M1, CC, CC, nullptr, nullptr);
    // 9. k_ca = contexts @ ca_k_w^T
    gemm_bt<<<dim3(CC / BN, M2 / BM), thr, 0, stream>>>(contexts, ca_k_w, k_ca,
                                                        M2, CC, CC, nullptr, nullptr);
    // 10. v_ca = contexts @ ca_v_w^T
    gemm_bt<<<dim3(CC / BN, M2 / BM), thr, 0, stream>>>(contexts, ca_v_w, v_ca,
                                                        M2, CC, CC, nullptr, nullptr);
    // 11. energy = Qca @ Kca^T  (final output 1, raw/unscaled)
    bgemm_abt<<<dim3(SK_ / BN, SQ_ / BM, BB * HH), thr, 0, stream>>>(
        q_ca, k_ca, energy, SQ_, SK_, 64,
        CC, CC,
        (long long)SQ_ * CC, 64, (long long)SK_ * CC, 64,
        (long long)SQ_ * SK_, HH);
    // 12. row stats over 2048
    rowstat<2048><<<BB * HH * SQ_, thr, 0, stream>>>(energy, G_buf, SCALE);
    // 13. o_ca = softmax(energy) @ Vca
    bgemm_pv<<<dim3(1, SQ_ / BM, BB * HH), thr, 0, stream>>>(
        energy, v_ca, D_buf, SQ_, SK_,
        (long long)SQ_ * SK_, SK_,
        (long long)SK_ * CC, 64, CC,
        (long long)SQ_ * CC, 64, CC, HH, G_buf, SCALE);
    // 14. x2 = o_ca @ ca_out_w^T + b + x1   (writes over E_buf in place: safe, 1:1 rw)
    gemm_bt<<<dim3(CC / BN, M1 / BM), thr, 0, stream>>>(D_buf, ca_out_w, E_buf,
                                                        M1, CC, CC, ca_out_b, E_buf);

    // ---- FFN ----
    // 15. f = silu(LN(x2))
    ln_kernel<1024><<<M1, thr, 0, stream>>>(E_buf, ff_ln1_g, ff_ln1_b, A_buf, 1);
    // 16. f1 = f @ ff_w1^T  (4096 x 2048)
    gemm_bt<<<dim3(2048 / BN, M1 / BM), thr, 0, stream>>>(A_buf, ff_w1, C_buf,
                                                          M1, 2048, 1024, nullptr, nullptr);
    // 17. f2 = silu(LN2(f1))
    ln_kernel<2048><<<M1, thr, 0, stream>>>(C_buf, ff_ln2_g, ff_ln2_b, A_buf, 1);
    // 18. out = f2 @ ff_w2^T + x2
    gemm_bt<<<dim3(CC / BN, M1 / BM), thr, 0, stream>>>(A_buf, ff_w2, out,
                                                        M1, CC, 2048, nullptr, E_buf);
}

// Round 2
// 1653.457 us; speedup vs baseline: 2.1640x; 2.1640x over previous
//
#include <hip/hip_runtime.h>
#include <hip/hip_bf16.h>
#include <math.h>

// CrossTransformer block. Round 2: dense GEMMs -> bf16 MFMA (m97 structure).
// B=4, SQ=1024, SK=2048, C=1024, H=16, DH=64.

namespace {
constexpr int BB  = 4;
constexpr int SQ_ = 1024;
constexpr int SK_ = 2048;
constexpr int CC  = 1024;
constexpr int HH  = 16;
constexpr float SCALE  = 0.03125f;   // 1/sqrt(1024)
constexpr float LN_EPS = 1e-5f;
}

typedef __hip_bfloat16 bf16;
typedef __attribute__((ext_vector_type(8))) short short8;
typedef __attribute__((ext_vector_type(4))) float f32x4;

__device__ __forceinline__ void gload16(const void* g, void* l) {
    __builtin_amdgcn_global_load_lds((const __attribute__((address_space(1))) unsigned int*)g,
                                     (__attribute__((address_space(3))) unsigned int*)l,
                                     16, 0, 0);
}

// ---------------- fp32 -> bf16 convert (8 elems/thread) ----------------
__global__ __launch_bounds__(256)
void cvt_bf16(const float* __restrict__ in, bf16* __restrict__ out, int n8) {
    const int i = blockIdx.x * 256 + threadIdx.x;
    if (i >= n8) return;
    const float4 a = ((const float4*)in)[2 * i];
    const float4 b = ((const float4*)in)[2 * i + 1];
    union { ushort4 v; bf16 h[4]; } lo, hi;
    lo.h[0] = __float2bfloat16(a.x); lo.h[1] = __float2bfloat16(a.y);
    lo.h[2] = __float2bfloat16(a.z); lo.h[3] = __float2bfloat16(a.w);
    hi.h[0] = __float2bfloat16(b.x); hi.h[1] = __float2bfloat16(b.y);
    hi.h[2] = __float2bfloat16(b.z); hi.h[3] = __float2bfloat16(b.w);
    ((ushort4*)out)[2 * i]     = lo.v;
    ((ushort4*)out)[2 * i + 1] = hi.v;
}

// ---------------- LayerNorm (+optional SiLU), bf16 out ----------------
template<int NCOLS>
__global__ __launch_bounds__(256)
void ln_kernel(const float* __restrict__ x, const float* __restrict__ g,
               const float* __restrict__ b, bf16* __restrict__ out, int do_silu) {
    constexpr int PER = NCOLS / 256;
    const size_t row = blockIdx.x;
    const float* xr = x + row * NCOLS;
    float vals[PER];
    float s = 0.f, ss = 0.f;
#pragma unroll
    for (int i = 0; i < PER; ++i) {
        vals[i] = xr[threadIdx.x + i * 256];
        s += vals[i];
        ss += vals[i] * vals[i];
    }
    for (int off = 32; off > 0; off >>= 1) {
        s  += __shfl_down(s, off, 64);
        ss += __shfl_down(ss, off, 64);
    }
    __shared__ float red[10];
    const int wid = threadIdx.x >> 6, lane = threadIdx.x & 63;
    if (lane == 0) { red[wid] = s; red[wid + 4] = ss; }
    __syncthreads();
    if (threadIdx.x == 0) {
        const float ts  = red[0] + red[1] + red[2] + red[3];
        const float tss = red[4] + red[5] + red[6] + red[7];
        const float mu  = ts / NCOLS;
        const float var = tss / NCOLS - mu * mu;
        red[8] = mu;
        red[9] = rsqrtf(var + LN_EPS);
    }
    __syncthreads();
    const float mu = red[8], rstd = red[9];
    bf16* outr = out + row * NCOLS;
#pragma unroll
    for (int i = 0; i < PER; ++i) {
        const int c = threadIdx.x + i * 256;
        float y = (vals[i] - mu) * rstd * g[c] + b[c];
        if (do_silu) y = y / (1.f + __expf(-y));
        outr[c] = __float2bfloat16(y);
    }
}

// ------------- bf16 MFMA GEMM: C[M,N] = A[M,K] @ B[N,K]^T (+bias)(+resid) ---
// 128x128 tile, BK=32, 256 threads (4 waves, 2x2), 4x4 fragments of 16x16x32.
__global__ __launch_bounds__(256)
void gemm_bt16(const bf16* __restrict__ A, const bf16* __restrict__ B,
               float* __restrict__ C, int M, int N, int K,
               const float* __restrict__ bias, const float* __restrict__ resid) {
    __shared__ bf16 As[128 * 32];
    __shared__ bf16 Bs[128 * 32];
    const int tid  = threadIdx.x;
    const int lane = tid & 63;
    const int w    = tid >> 6;
    const int wr = w >> 1, wc = w & 1;
    const int m0 = blockIdx.y * 128, n0 = blockIdx.x * 128;

    f32x4 acc[4][4] = {};

    const int srow = tid >> 2;          // 0..63
    const int scol = (tid & 3) * 8;     // 0,8,16,24
    const bf16* Ap  = A + (size_t)(m0 + srow) * K + scol;
    const bf16* Ap2 = Ap + (size_t)64 * K;
    const bf16* Bp  = B + (size_t)(n0 + srow) * K + scol;
    const bf16* Bp2 = Bp + (size_t)64 * K;

    char* AsB = (char*)As + w * 1024;   // wave-uniform LDS staging bases
    char* BsB = (char*)Bs + w * 1024;

    // fragment LDS byte offsets (row*64 + kgrp*16)
    const int arow = wr * 64 + (lane & 15);
    const int brow = wc * 64 + (lane & 15);
    const int kgrp = (lane >> 4) * 16;

    for (int k0 = 0; k0 < K; k0 += 32) {
        gload16(Ap  + k0, AsB);
        gload16(Ap2 + k0, AsB + 4096);
        gload16(Bp  + k0, BsB);
        gload16(Bp2 + k0, BsB + 4096);
        __syncthreads();
        short8 aF[4], bF[4];
#pragma unroll
        for (int m = 0; m < 4; ++m)
            aF[m] = *(const short8*)((const char*)As + ((arow + m * 16) * 64 + kgrp));
#pragma unroll
        for (int n = 0; n < 4; ++n)
            bF[n] = *(const short8*)((const char*)Bs + ((brow + n * 16) * 64 + kgrp));
#pragma unroll
        for (int m = 0; m < 4; ++m)
#pragma unroll
            for (int n = 0; n < 4; ++n)
                acc[m][n] = __builtin_amdgcn_mfma_f32_16x16x32_bf16(aF[m], bF[n], acc[m][n], 0, 0, 0);
        __syncthreads();
    }

    const int crow0 = m0 + wr * 64 + (lane >> 4) * 4;
    const int ccol0 = n0 + wc * 64 + (lane & 15);
#pragma unroll
    for (int m = 0; m < 4; ++m) {
#pragma unroll
        for (int n = 0; n < 4; ++n) {
            const int col = ccol0 + n * 16;
            const float bv = bias ? bias[col] : 0.f;
#pragma unroll
            for (int j = 0; j < 4; ++j) {
                const int row = crow0 + m * 16 + j;
                float v = acc[m][n][j] + bv;
                if (resid) v += resid[(size_t)row * N + col];
                C[(size_t)row * N + col] = v;
            }
        }
    }
}

// ------- Batched strided scores (fp32): C_z[M,N] = A_z[M,K] @ B_z[N,K]^T ----
#define BM 64
#define BN 64
#define BKt 16
__global__ __launch_bounds__(256)
void bgemm_abt(const float* __restrict__ Abase, const float* __restrict__ Bbase,
               float* __restrict__ Cbase, int M, int N, int K,
               int lda, int ldb,
               long long aStrB, long long aStrH, long long bStrB, long long bStrH,
               long long cStrZ, int H) {
    const int z = blockIdx.z;
    const int b = z / H, h = z % H;
    const float* A = Abase + (size_t)b * aStrB + (size_t)h * aStrH;
    const float* B = Bbase + (size_t)b * bStrB + (size_t)h * bStrH;
    float* C = Cbase + (size_t)z * cStrZ;

    __shared__ float As[BKt][BM + 1];
    __shared__ float Bs[BKt][BN + 1];
    const int tid = threadIdx.x;
    const int tx = tid & 15, ty = tid >> 4;
    const int m0 = blockIdx.y * BM, n0 = blockIdx.x * BN;
    float acc[4][4] = {};
    for (int k0 = 0; k0 < K; k0 += BKt) {
        const int idx = tid * 4;
        const int r = idx >> 4;
        const int c = idx & 15;
        const float4 a4 = *(const float4*)(A + (size_t)(m0 + r) * lda + k0 + c);
        As[c + 0][r] = a4.x; As[c + 1][r] = a4.y; As[c + 2][r] = a4.z; As[c + 3][r] = a4.w;
        const float4 b4 = *(const float4*)(B + (size_t)(n0 + r) * ldb + k0 + c);
        Bs[c + 0][r] = b4.x; Bs[c + 1][r] = b4.y; Bs[c + 2][r] = b4.z; Bs[c + 3][r] = b4.w;
        __syncthreads();
#pragma unroll
        for (int kk = 0; kk < BKt; ++kk) {
            float a[4], bb[4];
#pragma unroll
            for (int i = 0; i < 4; ++i) a[i]  = As[kk][ty * 4 + i];
#pragma unroll
            for (int j = 0; j < 4; ++j) bb[j] = Bs[kk][tx * 4 + j];
#pragma unroll
            for (int i = 0; i < 4; ++i)
#pragma unroll
                for (int j = 0; j < 4; ++j)
                    acc[i][j] += a[i] * bb[j];
        }
        __syncthreads();
    }
#pragma unroll
    for (int i = 0; i < 4; ++i) {
        const int m = m0 + ty * 4 + i;
#pragma unroll
        for (int j = 0; j < 4; ++j) {
            const int n = n0 + tx * 4 + j;
            C[(size_t)m * N + n] = acc[i][j];
        }
    }
}

// ------------- Row stats for softmax: m = max(e*scale), l = sum exp ------
template<int NCOLS>
__global__ __launch_bounds__(256)
void rowstat(const float* __restrict__ E, float* __restrict__ stats, float scale) {
    constexpr int PER = NCOLS / 256;
    const size_t row = blockIdx.x;
    const float* er = E + row * NCOLS;
    float v[PER];
    float mx = -INFINITY;
#pragma unroll
    for (int i = 0; i < PER; ++i) {
        v[i] = er[threadIdx.x + i * 256] * scale;
        mx = fmaxf(mx, v[i]);
    }
    for (int off = 32; off > 0; off >>= 1) mx = fmaxf(mx, __shfl_xor(mx, off, 64));
    __shared__ float red[8];
    const int wid = threadIdx.x >> 6, lane = threadIdx.x & 63;
    if (lane == 0) red[wid] = mx;
    __syncthreads();
    const float mAll = fmaxf(fmaxf(red[0], red[1]), fmaxf(red[2], red[3]));
    float sum = 0.f;
#pragma unroll
    for (int i = 0; i < PER; ++i) sum += __expf(v[i] - mAll);
    for (int off = 32; off > 0; off >>= 1) sum += __shfl_xor(sum, off, 64);
    if (lane == 0) red[4 + wid] = sum;
    __syncthreads();
    if (threadIdx.x == 0) {
        stats[row * 2]     = mAll;
        stats[row * 2 + 1] = red[4] + red[5] + red[6] + red[7];
    }
}

// ------- Batched PV (fp32 math): O_z[M,64] = softmax(P_z) @ V_z, bf16 out ---
__global__ __launch_bounds__(256)
void bgemm_pv(const float* __restrict__ Pbase, const float* __restrict__ Vbase,
              bf16* __restrict__ Obase, int M, int K,
              long long pStrZ, int ldp,
              long long vStrB, long long vStrH, int ldv,
              long long oStrB, long long oStrH, int ldo, int H,
              const float* __restrict__ stats, float scale) {
    const int z = blockIdx.z;
    const int b = z / H, h = z % H;
    const float* P = Pbase + (size_t)z * pStrZ;
    const float* V = Vbase + (size_t)b * vStrB + (size_t)h * vStrH;
    bf16* O = Obase + (size_t)b * oStrB + (size_t)h * oStrH;
    const float* st = stats + (size_t)z * M * 2;

    __shared__ float Ps[BKt][BM + 1];
    __shared__ float Vs[BKt][BN + 1];
    const int tid = threadIdx.x;
    const int tx = tid & 15, ty = tid >> 4;
    const int m0 = blockIdx.y * BM;
    float acc[4][4] = {};
    for (int k0 = 0; k0 < K; k0 += BKt) {
        {
            const int idx = tid * 4;
            const int r = idx >> 4;
            const int c = idx & 15;
            const float mrow = st[(size_t)(m0 + r) * 2];
            const float4 a4 = *(const float4*)(P + (size_t)(m0 + r) * ldp + k0 + c);
            Ps[c + 0][r] = __expf(a4.x * scale - mrow);
            Ps[c + 1][r] = __expf(a4.y * scale - mrow);
            Ps[c + 2][r] = __expf(a4.z * scale - mrow);
            Ps[c + 3][r] = __expf(a4.w * scale - mrow);
        }
        {
            const int idx = tid * 4;
            const int r = idx >> 6;
            const int c = idx & 63;
            const float4 v4 = *(const float4*)(V + (size_t)(k0 + r) * ldv + c);
            Vs[r][c + 0] = v4.x; Vs[r][c + 1] = v4.y; Vs[r][c + 2] = v4.z; Vs[r][c + 3] = v4.w;
        }
        __syncthreads();
#pragma unroll
        for (int kk = 0; kk < BKt; ++kk) {
            float a[4], bb[4];
#pragma unroll
            for (int i = 0; i < 4; ++i) a[i]  = Ps[kk][ty * 4 + i];
#pragma unroll
            for (int j = 0; j < 4; ++j) bb[j] = Vs[kk][tx * 4 + j];
#pragma unroll
            for (int i = 0; i < 4; ++i)
#pragma unroll
                for (int j = 0; j < 4; ++j)
                    acc[i][j] += a[i] * bb[j];
        }
        __syncthreads();
    }
#pragma unroll
    for (int i = 0; i < 4; ++i) {
        const int m = m0 + ty * 4 + i;
        const float rl = 1.f / st[(size_t)m * 2 + 1];
#pragma unroll
        for (int j = 0; j < 4; ++j) {
            const int n = tx * 4 + j;
            O[(size_t)m * ldo + n] = __float2bfloat16(acc[i][j] * rl);
        }
    }
}

extern "C" void kernel_launch(void* const* d_in, const int* in_sizes, int n_in,
                              void* d_out, int out_size, void* d_ws, size_t ws_size,
                              hipStream_t stream) {
    const float* queries  = (const float*)d_in[0];
    const float* contexts = (const float*)d_in[1];
    const float* sa_ln_g  = (const float*)d_in[2];
    const float* sa_ln_b  = (const float*)d_in[3];
    const float* sa_qkv_w = (const float*)d_in[4];
    const float* sa_out_w = (const float*)d_in[5];
    const float* sa_out_b = (const float*)d_in[6];
    const float* ca_ln_g  = (const float*)d_in[7];
    const float* ca_ln_b  = (const float*)d_in[8];
    const float* ca_q_w   = (const float*)d_in[9];
    const float* ca_k_w   = (const float*)d_in[10];
    const float* ca_v_w   = (const float*)d_in[11];
    const float* ca_out_w = (const float*)d_in[12];
    const float* ca_out_b = (const float*)d_in[13];
    const float* ff_ln1_g = (const float*)d_in[14];
    const float* ff_ln1_b = (const float*)d_in[15];
    const float* ff_w1    = (const float*)d_in[16];
    const float* ff_ln2_g = (const float*)d_in[17];
    const float* ff_ln2_b = (const float*)d_in[18];
    const float* ff_w2    = (const float*)d_in[19];

    float* out    = (float*)d_out;                     // 4M floats
    float* energy = out + (size_t)BB * SQ_ * CC;       // 128M floats

    const size_t MEG = 1024 * 1024;
    // ---- ws layout (float units) ----
    float* ws = (float*)d_ws;
    bf16*  BF    = (bf16*)ws;                 // [0,8M) floats = 16M bf16 slots
    bf16*  X0_16 = BF;                        // 8M bf16: h/h2/f/f2
    bf16*  o16   = BF + 8 * MEG;              // 4M bf16: attention out
    bf16*  ca_out_w16 = BF + 12 * MEG;        // 1M
    bf16*  ff_w1_16   = BF + 13 * MEG;        // 2M
    float* B_buf = ws + 8  * MEG;             // 12M fp32: qkv; later q_ca+k_ca
    float* C_buf = ws + 20 * MEG;             // 8M fp32: v_ca; f1
    float* E_buf = ws + 28 * MEG;             // 4M fp32: x1/x2
    float* G_buf = ws + 32 * MEG;             // 131072 floats: row stats
    bf16*  ff_w2_16 = (bf16*)(ws + 32 * MEG + 131072);  // 2M bf16

    // ---- early bf16 scratch inside energy region (dead before step 11) ----
    bf16* WE        = (bf16*)(energy + 64 * MEG);   // 8M bf16 capacity
    bf16* qkv_w16   = WE;                           // 3M
    bf16* sa_out_w16= WE + 3 * MEG;                 // 1M
    bf16* ca_q_w16  = WE + 4 * MEG;                 // 1M
    bf16* ca_k_w16  = WE + 5 * MEG;                 // 1M
    bf16* ca_v_w16  = WE + 6 * MEG;                 // 1M
    bf16* ctx16     = (bf16*)(energy + 68 * MEG);   // 8M

    const int M1 = BB * SQ_;   // 4096
    const int M2 = BB * SK_;   // 8192
    const dim3 thr(256);
    auto cvt = [&](const float* src, bf16* dst, size_t n) {
        int n8 = (int)(n / 8);
        cvt_bf16<<<(n8 + 255) / 256, thr, 0, stream>>>(src, dst, n8);
    };

    // ---- weight / context conversions ----
    cvt(sa_qkv_w, qkv_w16,    3 * MEG);
    cvt(sa_out_w, sa_out_w16, 1 * MEG);
    cvt(ca_q_w,   ca_q_w16,   1 * MEG);
    cvt(ca_k_w,   ca_k_w16,   1 * MEG);
    cvt(ca_v_w,   ca_v_w16,   1 * MEG);
    cvt(ca_out_w, ca_out_w16, 1 * MEG);
    cvt(ff_w1,    ff_w1_16,   2 * MEG);
    cvt(ff_w2,    ff_w2_16,   2 * MEG);
    cvt(contexts, ctx16,      8 * MEG);

    // ---- Self attention ----
    ln_kernel<1024><<<M1, thr, 0, stream>>>(queries, sa_ln_g, sa_ln_b, X0_16, 0);
    gemm_bt16<<<dim3(3072 / 128, M1 / 128), thr, 0, stream>>>(X0_16, qkv_w16, B_buf,
                                                              M1, 3072, 1024, nullptr, nullptr);
    bgemm_abt<<<dim3(SQ_ / BN, SQ_ / BM, BB * HH), thr, 0, stream>>>(
        B_buf, B_buf + 64, energy, SQ_, SQ_, 64,
        3072, 3072,
        (long long)SQ_ * 3072, 192, (long long)SQ_ * 3072, 192,
        (long long)SQ_ * SQ_, HH);
    rowstat<1024><<<BB * HH * SQ_, thr, 0, stream>>>(energy, G_buf, SCALE);
    bgemm_pv<<<dim3(1, SQ_ / BM, BB * HH), thr, 0, stream>>>(
        energy, B_buf + 128, o16, SQ_, SQ_,
        (long long)SQ_ * SQ_, SQ_,
        (long long)SQ_ * 3072, 192, 3072,
        (long long)SQ_ * CC, 64, CC, HH, G_buf, SCALE);
    gemm_bt16<<<dim3(1024 / 128, M1 / 128), thr, 0, stream>>>(o16, sa_out_w16, E_buf,
                                                              M1, CC, CC, sa_out_b, queries);

    // ---- Cross attention ----
    ln_kernel<1024><<<M1, thr, 0, stream>>>(E_buf, ca_ln_g, ca_ln_b, X0_16, 0);
    float* q_ca = B_buf;
    float* k_ca = B_buf + 4 * MEG;
    float* v_ca = C_buf;
    gemm_bt16<<<dim3(1024 / 128, M1 / 128), thr, 0, stream>>>(X0_16, ca_q_w16, q_ca,
                                                              M1, CC, CC, nullptr, nullptr);
    gemm_bt16<<<dim3(1024 / 128, M2 / 128), thr, 0, stream>>>(ctx16, ca_k_w16, k_ca,
                                                              M2, CC, CC, nullptr, nullptr);
    gemm_bt16<<<dim3(1024 / 128, M2 / 128), thr, 0, stream>>>(ctx16, ca_v_w16, v_ca,
                                                              M2, CC, CC, nullptr, nullptr);
    // energy final write (overwrites early scratch, which is now dead)
    bgemm_abt<<<dim3(SK_ / BN, SQ_ / BM, BB * HH), thr, 0, stream>>>(
        q_ca, k_ca, energy, SQ_, SK_, 64,
        CC, CC,
        (long long)SQ_ * CC, 64, (long long)SK_ * CC, 64,
        (long long)SQ_ * SK_, HH);
    rowstat<2048><<<BB * HH * SQ_, thr, 0, stream>>>(energy, G_buf, SCALE);
    bgemm_pv<<<dim3(1, SQ_ / BM, BB * HH), thr, 0, stream>>>(
        energy, v_ca, o16, SQ_, SK_,
        (long long)SQ_ * SK_, SK_,
        (long long)SK_ * CC, 64, CC,
        (long long)SQ_ * CC, 64, CC, HH, G_buf, SCALE);
    gemm_bt16<<<dim3(1024 / 128, M1 / 128), thr, 0, stream>>>(o16, ca_out_w16, E_buf,
                                                              M1, CC, CC, ca_out_b, E_buf);

    // ---- FFN ----
    ln_kernel<1024><<<M1, thr, 0, stream>>>(E_buf, ff_ln1_g, ff_ln1_b, X0_16, 1);
    gemm_bt16<<<dim3(2048 / 128, M1 / 128), thr, 0, stream>>>(X0_16, ff_w1_16, C_buf,
                                                              M1, 2048, 1024, nullptr, nullptr);
    ln_kernel<2048><<<M1, thr, 0, stream>>>(C_buf, ff_ln2_g, ff_ln2_b, X0_16, 1);
    gemm_bt16<<<dim3(1024 / 128, M1 / 128), thr, 0, stream>>>(X0_16, ff_w2_16, out,
                                                              M1, CC, 2048, nullptr, E_buf);
}

// Round 3
// 904.798 us; speedup vs baseline: 3.9546x; 1.8274x over previous
//
#include <hip/hip_runtime.h>
#include <hip/hip_bf16.h>
#include <math.h>

// CrossTransformer block. Round 3: fused flash-attention (MFMA) for SA and CA.
// B=4, SQ=1024, SK=2048, C=1024, H=16, DH=64.

namespace {
constexpr int BB  = 4;
constexpr int SQ_ = 1024;
constexpr int SK_ = 2048;
constexpr int CC  = 1024;
constexpr int HH  = 16;
constexpr float SCALE  = 0.03125f;   // 1/sqrt(1024)
constexpr float LN_EPS = 1e-5f;
}

typedef __hip_bfloat16 bf16;
typedef __attribute__((ext_vector_type(8))) short short8;
typedef __attribute__((ext_vector_type(4))) float f32x4;

__device__ __forceinline__ void gload16(const void* g, void* l) {
    __builtin_amdgcn_global_load_lds((const __attribute__((address_space(1))) unsigned int*)g,
                                     (__attribute__((address_space(3))) unsigned int*)l,
                                     16, 0, 0);
}

// ---------------- fp32 -> bf16 convert (8 elems/thread) ----------------
__global__ __launch_bounds__(256)
void cvt_bf16(const float* __restrict__ in, bf16* __restrict__ out, int n8) {
    const int i = blockIdx.x * 256 + threadIdx.x;
    if (i >= n8) return;
    const float4 a = ((const float4*)in)[2 * i];
    const float4 b = ((const float4*)in)[2 * i + 1];
    union { ushort4 v; bf16 h[4]; } lo, hi;
    lo.h[0] = __float2bfloat16(a.x); lo.h[1] = __float2bfloat16(a.y);
    lo.h[2] = __float2bfloat16(a.z); lo.h[3] = __float2bfloat16(a.w);
    hi.h[0] = __float2bfloat16(b.x); hi.h[1] = __float2bfloat16(b.y);
    hi.h[2] = __float2bfloat16(b.z); hi.h[3] = __float2bfloat16(b.w);
    ((ushort4*)out)[2 * i]     = lo.v;
    ((ushort4*)out)[2 * i + 1] = hi.v;
}

// ---------------- LayerNorm (+optional SiLU), bf16 out ----------------
template<int NCOLS>
__global__ __launch_bounds__(256)
void ln_kernel(const float* __restrict__ x, const float* __restrict__ g,
               const float* __restrict__ b, bf16* __restrict__ out, int do_silu) {
    constexpr int PER = NCOLS / 256;
    const size_t row = blockIdx.x;
    const float* xr = x + row * NCOLS;
    float vals[PER];
    float s = 0.f, ss = 0.f;
#pragma unroll
    for (int i = 0; i < PER; ++i) {
        vals[i] = xr[threadIdx.x + i * 256];
        s += vals[i];
        ss += vals[i] * vals[i];
    }
    for (int off = 32; off > 0; off >>= 1) {
        s  += __shfl_down(s, off, 64);
        ss += __shfl_down(ss, off, 64);
    }
    __shared__ float red[10];
    const int wid = threadIdx.x >> 6, lane = threadIdx.x & 63;
    if (lane == 0) { red[wid] = s; red[wid + 4] = ss; }
    __syncthreads();
    if (threadIdx.x == 0) {
        const float ts  = red[0] + red[1] + red[2] + red[3];
        const float tss = red[4] + red[5] + red[6] + red[7];
        const float mu  = ts / NCOLS;
        const float var = tss / NCOLS - mu * mu;
        red[8] = mu;
        red[9] = rsqrtf(var + LN_EPS);
    }
    __syncthreads();
    const float mu = red[8], rstd = red[9];
    bf16* outr = out + row * NCOLS;
#pragma unroll
    for (int i = 0; i < PER; ++i) {
        const int c = threadIdx.x + i * 256;
        float y = (vals[i] - mu) * rstd * g[c] + b[c];
        if (do_silu) y = y / (1.f + __expf(-y));
        outr[c] = __float2bfloat16(y);
    }
}

// ------------- bf16 MFMA GEMM: C[M,N] = A[M,K] @ B[N,K]^T (+bias)(+resid) ---
// 128x128 tile, BK=32, 256 threads (4 waves 2x2), 4x4 frags of 16x16x32.
// OUT16: 1 -> bf16 C (no bias/resid), 0 -> fp32 C.
template<int OUT16>
__global__ __launch_bounds__(256)
void gemm_bt16(const bf16* __restrict__ A, const bf16* __restrict__ B,
               void* __restrict__ Cv, int M, int N, int K,
               const float* __restrict__ bias, const float* __restrict__ resid) {
    __shared__ bf16 As[128 * 32];
    __shared__ bf16 Bs[128 * 32];
    const int tid  = threadIdx.x;
    const int lane = tid & 63;
    const int w    = tid >> 6;
    const int wr = w >> 1, wc = w & 1;
    const int m0 = blockIdx.y * 128, n0 = blockIdx.x * 128;

    f32x4 acc[4][4] = {};

    const int srow = tid >> 2;
    const int scol = (tid & 3) * 8;
    const bf16* Ap  = A + (size_t)(m0 + srow) * K + scol;
    const bf16* Ap2 = Ap + (size_t)64 * K;
    const bf16* Bp  = B + (size_t)(n0 + srow) * K + scol;
    const bf16* Bp2 = Bp + (size_t)64 * K;

    char* AsB = (char*)As + w * 1024;
    char* BsB = (char*)Bs + w * 1024;

    const int arow = wr * 64 + (lane & 15);
    const int brow = wc * 64 + (lane & 15);
    const int kgrp = (lane >> 4) * 16;

    for (int k0 = 0; k0 < K; k0 += 32) {
        gload16(Ap  + k0, AsB);
        gload16(Ap2 + k0, AsB + 4096);
        gload16(Bp  + k0, BsB);
        gload16(Bp2 + k0, BsB + 4096);
        __syncthreads();
        short8 aF[4], bF[4];
#pragma unroll
        for (int m = 0; m < 4; ++m)
            aF[m] = *(const short8*)((const char*)As + ((arow + m * 16) * 64 + kgrp));
#pragma unroll
        for (int n = 0; n < 4; ++n)
            bF[n] = *(const short8*)((const char*)Bs + ((brow + n * 16) * 64 + kgrp));
#pragma unroll
        for (int m = 0; m < 4; ++m)
#pragma unroll
            for (int n = 0; n < 4; ++n)
                acc[m][n] = __builtin_amdgcn_mfma_f32_16x16x32_bf16(aF[m], bF[n], acc[m][n], 0, 0, 0);
        __syncthreads();
    }

    const int crow0 = m0 + wr * 64 + (lane >> 4) * 4;
    const int ccol0 = n0 + wc * 64 + (lane & 15);
#pragma unroll
    for (int m = 0; m < 4; ++m) {
#pragma unroll
        for (int n = 0; n < 4; ++n) {
            const int col = ccol0 + n * 16;
            const float bv = (!OUT16 && bias) ? bias[col] : 0.f;
#pragma unroll
            for (int j = 0; j < 4; ++j) {
                const int row = crow0 + m * 16 + j;
                float v = acc[m][n][j] + bv;
                if (!OUT16 && resid) v += resid[(size_t)row * N + col];
                if (OUT16) ((bf16*)Cv)[(size_t)row * N + col] = __float2bfloat16(v);
                else       ((float*)Cv)[(size_t)row * N + col] = v;
            }
        }
    }
}

// --------- tiled transpose: T[c][r] = X[r][(c/64)*cs + co + (c%64)] ---------
__global__ __launch_bounds__(256)
void transpose_v(const bf16* __restrict__ X, int ldx, int cs, int co,
                 bf16* __restrict__ T, int ldt) {
    __shared__ bf16 t[64][66];
    const int r0 = blockIdx.x * 64, c0 = blockIdx.y * 64;
#pragma unroll
    for (int s = 0; s < 16; ++s) {
        const int r = (threadIdx.x >> 6) + s * 4;
        const int c = threadIdx.x & 63;
        const int cc = c0 + c;
        t[r][c] = X[(size_t)(r0 + r) * ldx + (size_t)(cc >> 6) * cs + co + (cc & 63)];
    }
    __syncthreads();
#pragma unroll
    for (int s = 0; s < 16; ++s) {
        const int c = (threadIdx.x >> 6) + s * 4;
        const int r = threadIdx.x & 63;
        T[(size_t)(c0 + c) * ldt + r0 + r] = t[r][c];
    }
}

// --------------- fused flash attention (optionally writes raw energy) -------
// 128 q-rows per block, 4 waves x 32 rows, KV tiles of 128, DH=64, H=16.
// Q/K fragments loaded directly from global; V pre-transposed (Vt[d][kv]).
template<bool ENERGY>
__global__ __launch_bounds__(256)
void flash_attn(const bf16* __restrict__ Qb, int ldq, int qh_str,
                const bf16* __restrict__ Kb, int ldk, int kh_str, int kh_add,
                const bf16* __restrict__ Vt, int ldvt,
                bf16* __restrict__ O, float* __restrict__ energy,
                int SKV, int SQl, float scale) {
    __shared__ bf16 P[128][136];
    const int tid = threadIdx.x;
    const int lane = tid & 63, wid = tid >> 6;
    const int l15 = lane & 15, l4 = lane >> 4;
    const int z = blockIdx.y, b = z >> 4, h = z & 15;
    const int q0 = blockIdx.x * 128;

    const bf16* Qp = Qb + (size_t)b * SQl * ldq + (size_t)h * qh_str;
    const bf16* Kp = Kb + (size_t)b * SKV * ldk + (size_t)h * kh_str + kh_add;
    const bf16* Vp = Vt + (size_t)h * 64 * ldvt + (size_t)b * SKV;

    // Q fragments (held in registers for the whole block)
    short8 aQ[2][2];
#pragma unroll
    for (int m = 0; m < 2; ++m)
#pragma unroll
        for (int s = 0; s < 2; ++s)
            aQ[m][s] = *(const short8*)(Qp + (size_t)(q0 + wid * 32 + m * 16 + l15) * ldq + s * 32 + l4 * 8);

    f32x4 oacc[2][4] = {};
    float mst[2][4], lst[2][4];
#pragma unroll
    for (int m = 0; m < 2; ++m)
#pragma unroll
        for (int j = 0; j < 4; ++j) { mst[m][j] = -1e30f; lst[m][j] = 0.f; }

    for (int kv0 = 0; kv0 < SKV; kv0 += 128) {
        // ---- S = Q @ K^T (raw scores, fp32 accum) ----
        f32x4 sa[2][8] = {};
#pragma unroll
        for (int n = 0; n < 8; ++n) {
            const bf16* kr = Kp + (size_t)(kv0 + n * 16 + l15) * ldk + l4 * 8;
            const short8 b0 = *(const short8*)(kr);
            const short8 b1 = *(const short8*)(kr + 32);
#pragma unroll
            for (int m = 0; m < 2; ++m) {
                sa[m][n] = __builtin_amdgcn_mfma_f32_16x16x32_bf16(aQ[m][0], b0, sa[m][n], 0, 0, 0);
                sa[m][n] = __builtin_amdgcn_mfma_f32_16x16x32_bf16(aQ[m][1], b1, sa[m][n], 0, 0, 0);
            }
        }
        // ---- raw energy write (CA only) ----
        if (ENERGY) {
            float* Ez = energy + (size_t)z * SQl * SKV;
#pragma unroll
            for (int m = 0; m < 2; ++m)
#pragma unroll
                for (int j = 0; j < 4; ++j) {
                    float* er = Ez + (size_t)(q0 + wid * 32 + m * 16 + l4 * 4 + j) * SKV + kv0;
#pragma unroll
                    for (int n = 0; n < 8; ++n) er[n * 16 + l15] = sa[m][n][j];
                }
        }
        // ---- online softmax ----
#pragma unroll
        for (int m = 0; m < 2; ++m)
#pragma unroll
            for (int j = 0; j < 4; ++j) {
                float mx = sa[m][0][j];
#pragma unroll
                for (int n = 1; n < 8; ++n) mx = fmaxf(mx, sa[m][n][j]);
                mx *= scale;
                mx = fmaxf(mx, __shfl_xor(mx, 1));
                mx = fmaxf(mx, __shfl_xor(mx, 2));
                mx = fmaxf(mx, __shfl_xor(mx, 4));
                mx = fmaxf(mx, __shfl_xor(mx, 8));
                const float nm = fmaxf(mst[m][j], mx);
                const float f = __expf(mst[m][j] - nm);
                mst[m][j] = nm;
                float rs = 0.f;
#pragma unroll
                for (int n = 0; n < 8; ++n) {
                    const float p = __expf(sa[m][n][j] * scale - nm);
                    sa[m][n][j] = p;
                    rs += p;
                }
                rs += __shfl_xor(rs, 1);
                rs += __shfl_xor(rs, 2);
                rs += __shfl_xor(rs, 4);
                rs += __shfl_xor(rs, 8);
                lst[m][j] = lst[m][j] * f + rs;
#pragma unroll
                for (int n = 0; n < 4; ++n) oacc[m][n][j] *= f;
            }
        // ---- P -> LDS (wave-private rows; no barrier needed) ----
#pragma unroll
        for (int m = 0; m < 2; ++m)
#pragma unroll
            for (int n = 0; n < 8; ++n)
#pragma unroll
                for (int j = 0; j < 4; ++j)
                    P[wid * 32 + m * 16 + l4 * 4 + j][n * 16 + l15] = __float2bfloat16(sa[m][n][j]);
        // ---- O += P @ V ----
#pragma unroll
        for (int ks = 0; ks < 4; ++ks) {
            short8 aP[2];
#pragma unroll
            for (int m = 0; m < 2; ++m)
                aP[m] = *(const short8*)(&P[wid * 32 + m * 16 + l15][ks * 32 + l4 * 8]);
#pragma unroll
            for (int n = 0; n < 4; ++n) {
                const short8 bV = *(const short8*)(Vp + (size_t)(n * 16 + l15) * ldvt + kv0 + ks * 32 + l4 * 8);
#pragma unroll
                for (int m = 0; m < 2; ++m)
                    oacc[m][n] = __builtin_amdgcn_mfma_f32_16x16x32_bf16(aP[m], bV, oacc[m][n], 0, 0, 0);
            }
        }
    }
    // ---- epilogue: normalize + write O (bf16, [B*SQ][C] layout) ----
#pragma unroll
    for (int m = 0; m < 2; ++m)
#pragma unroll
        for (int j = 0; j < 4; ++j) {
            const float rl = 1.f / lst[m][j];
            const size_t row = (size_t)b * SQl + q0 + wid * 32 + m * 16 + l4 * 4 + j;
#pragma unroll
            for (int n = 0; n < 4; ++n)
                O[row * 1024 + h * 64 + n * 16 + l15] = __float2bfloat16(oacc[m][n][j] * rl);
        }
}

extern "C" void kernel_launch(void* const* d_in, const int* in_sizes, int n_in,
                              void* d_out, int out_size, void* d_ws, size_t ws_size,
                              hipStream_t stream) {
    const float* queries  = (const float*)d_in[0];
    const float* contexts = (const float*)d_in[1];
    const float* sa_ln_g  = (const float*)d_in[2];
    const float* sa_ln_b  = (const float*)d_in[3];
    const float* sa_qkv_w = (const float*)d_in[4];
    const float* sa_out_w = (const float*)d_in[5];
    const float* sa_out_b = (const float*)d_in[6];
    const float* ca_ln_g  = (const float*)d_in[7];
    const float* ca_ln_b  = (const float*)d_in[8];
    const float* ca_q_w   = (const float*)d_in[9];
    const float* ca_k_w   = (const float*)d_in[10];
    const float* ca_v_w   = (const float*)d_in[11];
    const float* ca_out_w = (const float*)d_in[12];
    const float* ca_out_b = (const float*)d_in[13];
    const float* ff_ln1_g = (const float*)d_in[14];
    const float* ff_ln1_b = (const float*)d_in[15];
    const float* ff_w1    = (const float*)d_in[16];
    const float* ff_ln2_g = (const float*)d_in[17];
    const float* ff_ln2_b = (const float*)d_in[18];
    const float* ff_w2    = (const float*)d_in[19];

    float* out    = (float*)d_out;                     // 4M floats
    float* energy = out + (size_t)BB * SQ_ * CC;       // 128M floats

    const size_t MEG = 1024 * 1024;

    // ---- ws layout ----
    float* ws = (float*)d_ws;
    bf16*  X0_16      = (bf16*)ws;                                  // 8M bf16
    bf16*  o16        = (bf16*)(ws + 4 * MEG);                      // 4M bf16
    bf16*  ca_out_w16 = (bf16*)(ws + 6 * MEG);                      // 1M
    bf16*  ff_w1_16   = (bf16*)(ws + (13 * MEG) / 2);               // 2M
    bf16*  ff_w2_16   = (bf16*)(ws + (15 * MEG) / 2);               // 2M
    bf16*  q_ca16     = (bf16*)(ws + (17 * MEG) / 2);               // 4M
    bf16*  k_ca16     = (bf16*)(ws + (21 * MEG) / 2);               // 8M
    bf16*  Vt_ca      = (bf16*)(ws + (29 * MEG) / 2);               // 8M
    float* E_buf      = ws + (37 * MEG) / 2;                        // 4M fp32
    float* C_buf      = ws + (45 * MEG) / 2;                        // 8M fp32
    bf16*  v_ca16     = (bf16*)C_buf;                               // 8M bf16 (dead before FFN)

    // ---- early scratch inside energy region (dead before CA flash) ----
    bf16* EZ         = (bf16*)energy;
    bf16* ctx16      = EZ;                 // 8M
    bf16* qkv16      = EZ + 8  * MEG;      // 12M
    bf16* Vt_sa      = EZ + 20 * MEG;      // 4M
    bf16* qkv_w16    = EZ + 24 * MEG;      // 3M
    bf16* sa_out_w16 = EZ + 27 * MEG;      // 1M
    bf16* ca_q_w16   = EZ + 28 * MEG;      // 1M
    bf16* ca_k_w16   = EZ + 29 * MEG;      // 1M
    bf16* ca_v_w16   = EZ + 30 * MEG;      // 1M

    const int M1 = BB * SQ_;   // 4096
    const int M2 = BB * SK_;   // 8192
    const dim3 thr(256);
    auto cvt = [&](const float* src, bf16* dst, size_t n) {
        int n8 = (int)(n / 8);
        cvt_bf16<<<(n8 + 255) / 256, thr, 0, stream>>>(src, dst, n8);
    };

    // ---- conversions ----
    cvt(sa_qkv_w, qkv_w16,    3 * MEG);
    cvt(sa_out_w, sa_out_w16, 1 * MEG);
    cvt(ca_q_w,   ca_q_w16,   1 * MEG);
    cvt(ca_k_w,   ca_k_w16,   1 * MEG);
    cvt(ca_v_w,   ca_v_w16,   1 * MEG);
    cvt(ca_out_w, ca_out_w16, 1 * MEG);
    cvt(ff_w1,    ff_w1_16,   2 * MEG);
    cvt(ff_w2,    ff_w2_16,   2 * MEG);
    cvt(contexts, ctx16,      8 * MEG);

    // ---- Self attention ----
    ln_kernel<1024><<<M1, thr, 0, stream>>>(queries, sa_ln_g, sa_ln_b, X0_16, 0);
    gemm_bt16<1><<<dim3(3072 / 128, M1 / 128), thr, 0, stream>>>(X0_16, qkv_w16, qkv16,
                                                                 M1, 3072, 1024, nullptr, nullptr);
    transpose_v<<<dim3(M1 / 64, 1024 / 64), thr, 0, stream>>>(qkv16, 3072, 192, 128, Vt_sa, M1);
    flash_attn<false><<<dim3(SQ_ / 128, BB * HH), thr, 0, stream>>>(
        qkv16, 3072, 192, qkv16, 3072, 192, 64, Vt_sa, M1,
        o16, nullptr, SQ_, SQ_, SCALE);
    gemm_bt16<0><<<dim3(1024 / 128, M1 / 128), thr, 0, stream>>>(o16, sa_out_w16, E_buf,
                                                                 M1, CC, CC, sa_out_b, queries);

    // ---- Cross attention ----
    ln_kernel<1024><<<M1, thr, 0, stream>>>(E_buf, ca_ln_g, ca_ln_b, X0_16, 0);
    gemm_bt16<1><<<dim3(1024 / 128, M1 / 128), thr, 0, stream>>>(X0_16, ca_q_w16, q_ca16,
                                                                 M1, CC, CC, nullptr, nullptr);
    gemm_bt16<1><<<dim3(1024 / 128, M2 / 128), thr, 0, stream>>>(ctx16, ca_k_w16, k_ca16,
                                                                 M2, CC, CC, nullptr, nullptr);
    gemm_bt16<1><<<dim3(1024 / 128, M2 / 128), thr, 0, stream>>>(ctx16, ca_v_w16, v_ca16,
                                                                 M2, CC, CC, nullptr, nullptr);
    transpose_v<<<dim3(M2 / 64, 1024 / 64), thr, 0, stream>>>(v_ca16, 1024, 64, 0, Vt_ca, M2);
    // CA flash: writes raw energy (final output) + attention out. All energy-region
    // scratch (ctx16/qkv16/Vt_sa/weights) is dead by this point.
    flash_attn<true><<<dim3(SQ_ / 128, BB * HH), thr, 0, stream>>>(
        q_ca16, 1024, 64, k_ca16, 1024, 64, 0, Vt_ca, M2,
        o16, energy, SK_, SQ_, SCALE);
    gemm_bt16<0><<<dim3(1024 / 128, M1 / 128), thr, 0, stream>>>(o16, ca_out_w16, E_buf,
                                                                 M1, CC, CC, ca_out_b, E_buf);

    // ---- FFN ----
    ln_kernel<1024><<<M1, thr, 0, stream>>>(E_buf, ff_ln1_g, ff_ln1_b, X0_16, 1);
    gemm_bt16<0><<<dim3(2048 / 128, M1 / 128), thr, 0, stream>>>(X0_16, ff_w1_16, C_buf,
                                                                 M1, 2048, 1024, nullptr, nullptr);
    ln_kernel<2048><<<M1, thr, 0, stream>>>(C_buf, ff_ln2_g, ff_ln2_b, X0_16, 1);
    gemm_bt16<0><<<dim3(1024 / 128, M1 / 128), thr, 0, stream>>>(X0_16, ff_w2_16, out,
                                                                 M1, CC, 2048, nullptr, E_buf);
}

// Round 4
// 842.254 us; speedup vs baseline: 4.2483x; 1.0743x over previous
//
#include <hip/hip_runtime.h>
#include <hip/hip_bf16.h>
#include <math.h>

// CrossTransformer block. Round 4: flash-attn occupancy fix (QBLK=64, CA kv-split 2,
// nontemporal energy stores, fp32-partial + merge for CA O).
// B=4, SQ=1024, SK=2048, C=1024, H=16, DH=64.

namespace {
constexpr int BB  = 4;
constexpr int SQ_ = 1024;
constexpr int SK_ = 2048;
constexpr int CC  = 1024;
constexpr int HH  = 16;
constexpr float SCALE  = 0.03125f;   // 1/sqrt(1024)
constexpr float LN_EPS = 1e-5f;
constexpr size_t OPART_STRIDE = (size_t)BB * SQ_ * CC;   // 4M elems per split
}

typedef __hip_bfloat16 bf16;
typedef __attribute__((ext_vector_type(8))) short short8;
typedef __attribute__((ext_vector_type(4))) float f32x4;

__device__ __forceinline__ void gload16(const void* g, void* l) {
    __builtin_amdgcn_global_load_lds((const __attribute__((address_space(1))) unsigned int*)g,
                                     (__attribute__((address_space(3))) unsigned int*)l,
                                     16, 0, 0);
}

// ---------------- fp32 -> bf16 convert (8 elems/thread) ----------------
__global__ __launch_bounds__(256)
void cvt_bf16(const float* __restrict__ in, bf16* __restrict__ out, int n8) {
    const int i = blockIdx.x * 256 + threadIdx.x;
    if (i >= n8) return;
    const float4 a = ((const float4*)in)[2 * i];
    const float4 b = ((const float4*)in)[2 * i + 1];
    union { ushort4 v; bf16 h[4]; } lo, hi;
    lo.h[0] = __float2bfloat16(a.x); lo.h[1] = __float2bfloat16(a.y);
    lo.h[2] = __float2bfloat16(a.z); lo.h[3] = __float2bfloat16(a.w);
    hi.h[0] = __float2bfloat16(b.x); hi.h[1] = __float2bfloat16(b.y);
    hi.h[2] = __float2bfloat16(b.z); hi.h[3] = __float2bfloat16(b.w);
    ((ushort4*)out)[2 * i]     = lo.v;
    ((ushort4*)out)[2 * i + 1] = hi.v;
}

// ---------------- LayerNorm (+optional SiLU), bf16 out ----------------
template<int NCOLS>
__global__ __launch_bounds__(256)
void ln_kernel(const float* __restrict__ x, const float* __restrict__ g,
               const float* __restrict__ b, bf16* __restrict__ out, int do_silu) {
    constexpr int PER = NCOLS / 256;
    const size_t row = blockIdx.x;
    const float* xr = x + row * NCOLS;
    float vals[PER];
    float s = 0.f, ss = 0.f;
#pragma unroll
    for (int i = 0; i < PER; ++i) {
        vals[i] = xr[threadIdx.x + i * 256];
        s += vals[i];
        ss += vals[i] * vals[i];
    }
    for (int off = 32; off > 0; off >>= 1) {
        s  += __shfl_down(s, off, 64);
        ss += __shfl_down(ss, off, 64);
    }
    __shared__ float red[10];
    const int wid = threadIdx.x >> 6, lane = threadIdx.x & 63;
    if (lane == 0) { red[wid] = s; red[wid + 4] = ss; }
    __syncthreads();
    if (threadIdx.x == 0) {
        const float ts  = red[0] + red[1] + red[2] + red[3];
        const float tss = red[4] + red[5] + red[6] + red[7];
        const float mu  = ts / NCOLS;
        const float var = tss / NCOLS - mu * mu;
        red[8] = mu;
        red[9] = rsqrtf(var + LN_EPS);
    }
    __syncthreads();
    const float mu = red[8], rstd = red[9];
    bf16* outr = out + row * NCOLS;
#pragma unroll
    for (int i = 0; i < PER; ++i) {
        const int c = threadIdx.x + i * 256;
        float y = (vals[i] - mu) * rstd * g[c] + b[c];
        if (do_silu) y = y / (1.f + __expf(-y));
        outr[c] = __float2bfloat16(y);
    }
}

// ------------- bf16 MFMA GEMM: C[M,N] = A[M,K] @ B[N,K]^T (+bias)(+resid) ---
template<int OUT16>
__global__ __launch_bounds__(256)
void gemm_bt16(const bf16* __restrict__ A, const bf16* __restrict__ B,
               void* __restrict__ Cv, int M, int N, int K,
               const float* __restrict__ bias, const float* __restrict__ resid) {
    __shared__ bf16 As[128 * 32];
    __shared__ bf16 Bs[128 * 32];
    const int tid  = threadIdx.x;
    const int lane = tid & 63;
    const int w    = tid >> 6;
    const int wr = w >> 1, wc = w & 1;
    const int m0 = blockIdx.y * 128, n0 = blockIdx.x * 128;

    f32x4 acc[4][4] = {};

    const int srow = tid >> 2;
    const int scol = (tid & 3) * 8;
    const bf16* Ap  = A + (size_t)(m0 + srow) * K + scol;
    const bf16* Ap2 = Ap + (size_t)64 * K;
    const bf16* Bp  = B + (size_t)(n0 + srow) * K + scol;
    const bf16* Bp2 = Bp + (size_t)64 * K;

    char* AsB = (char*)As + w * 1024;
    char* BsB = (char*)Bs + w * 1024;

    const int arow = wr * 64 + (lane & 15);
    const int brow = wc * 64 + (lane & 15);
    const int kgrp = (lane >> 4) * 16;

    for (int k0 = 0; k0 < K; k0 += 32) {
        gload16(Ap  + k0, AsB);
        gload16(Ap2 + k0, AsB + 4096);
        gload16(Bp  + k0, BsB);
        gload16(Bp2 + k0, BsB + 4096);
        __syncthreads();
        short8 aF[4], bF[4];
#pragma unroll
        for (int m = 0; m < 4; ++m)
            aF[m] = *(const short8*)((const char*)As + ((arow + m * 16) * 64 + kgrp));
#pragma unroll
        for (int n = 0; n < 4; ++n)
            bF[n] = *(const short8*)((const char*)Bs + ((brow + n * 16) * 64 + kgrp));
#pragma unroll
        for (int m = 0; m < 4; ++m)
#pragma unroll
            for (int n = 0; n < 4; ++n)
                acc[m][n] = __builtin_amdgcn_mfma_f32_16x16x32_bf16(aF[m], bF[n], acc[m][n], 0, 0, 0);
        __syncthreads();
    }

    const int crow0 = m0 + wr * 64 + (lane >> 4) * 4;
    const int ccol0 = n0 + wc * 64 + (lane & 15);
#pragma unroll
    for (int m = 0; m < 4; ++m) {
#pragma unroll
        for (int n = 0; n < 4; ++n) {
            const int col = ccol0 + n * 16;
            const float bv = (!OUT16 && bias) ? bias[col] : 0.f;
#pragma unroll
            for (int j = 0; j < 4; ++j) {
                const int row = crow0 + m * 16 + j;
                float v = acc[m][n][j] + bv;
                if (!OUT16 && resid) v += resid[(size_t)row * N + col];
                if (OUT16) ((bf16*)Cv)[(size_t)row * N + col] = __float2bfloat16(v);
                else       ((float*)Cv)[(size_t)row * N + col] = v;
            }
        }
    }
}

// --------- tiled transpose: T[c][r] = X[r][(c/64)*cs + co + (c%64)] ---------
__global__ __launch_bounds__(256)
void transpose_v(const bf16* __restrict__ X, int ldx, int cs, int co,
                 bf16* __restrict__ T, int ldt) {
    __shared__ bf16 t[64][66];
    const int r0 = blockIdx.x * 64, c0 = blockIdx.y * 64;
#pragma unroll
    for (int s = 0; s < 16; ++s) {
        const int r = (threadIdx.x >> 6) + s * 4;
        const int c = threadIdx.x & 63;
        const int cc = c0 + c;
        t[r][c] = X[(size_t)(r0 + r) * ldx + (size_t)(cc >> 6) * cs + co + (cc & 63)];
    }
    __syncthreads();
#pragma unroll
    for (int s = 0; s < 16; ++s) {
        const int c = (threadIdx.x >> 6) + s * 4;
        const int r = threadIdx.x & 63;
        T[(size_t)(c0 + c) * ldt + r0 + r] = t[r][c];
    }
}

// --------------- fused flash attention -------------------------------------
// 64 q-rows per block, 4 waves x 16 rows, KV tiles of 128, DH=64, H=16.
// ENERGY: also write raw QK^T to energy (nontemporal).
// NSPLIT: kv-range split across blockIdx.z; >1 -> fp32 partial O + (m,l) stats.
template<bool ENERGY, int NSPLIT>
__global__ __launch_bounds__(256)
void flash_attn(const bf16* __restrict__ Qb, int ldq, int qh_str,
                const bf16* __restrict__ Kb, int ldk, int kh_str, int kh_add,
                const bf16* __restrict__ Vt, int ldvt,
                bf16* __restrict__ O, float* __restrict__ Opart,
                float* __restrict__ stats, float* __restrict__ energy,
                int SKV, int SQl, float scale) {
    __shared__ bf16 P[64][136];
    const int tid = threadIdx.x;
    const int lane = tid & 63, wid = tid >> 6;
    const int l15 = lane & 15, l4 = lane >> 4;
    const int z = blockIdx.y, b = z >> 4, h = z & 15;
    const int q0 = blockIdx.x * 64;
    const int split = (NSPLIT > 1) ? blockIdx.z : 0;
    const int kv_begin = split * (SKV / NSPLIT);
    const int kv_end   = kv_begin + SKV / NSPLIT;

    const bf16* Qp = Qb + (size_t)b * SQl * ldq + (size_t)h * qh_str;
    const bf16* Kp = Kb + (size_t)b * SKV * ldk + (size_t)h * kh_str + kh_add;
    const bf16* Vp = Vt + (size_t)h * 64 * ldvt + (size_t)b * SKV;

    // Q fragments for this wave's 16 rows
    short8 aQ[2];
#pragma unroll
    for (int s = 0; s < 2; ++s)
        aQ[s] = *(const short8*)(Qp + (size_t)(q0 + wid * 16 + l15) * ldq + s * 32 + l4 * 8);

    f32x4 oacc[4] = {};
    float mst[4], lst[4];
#pragma unroll
    for (int j = 0; j < 4; ++j) { mst[j] = -1e30f; lst[j] = 0.f; }

    for (int kv0 = kv_begin; kv0 < kv_end; kv0 += 128) {
        // ---- S = Q @ K^T (raw, fp32 accum) ----
        f32x4 sa[8] = {};
#pragma unroll
        for (int n = 0; n < 8; ++n) {
            const bf16* kr = Kp + (size_t)(kv0 + n * 16 + l15) * ldk + l4 * 8;
            const short8 b0 = *(const short8*)(kr);
            const short8 b1 = *(const short8*)(kr + 32);
            sa[n] = __builtin_amdgcn_mfma_f32_16x16x32_bf16(aQ[0], b0, sa[n], 0, 0, 0);
            sa[n] = __builtin_amdgcn_mfma_f32_16x16x32_bf16(aQ[1], b1, sa[n], 0, 0, 0);
        }
        // ---- raw energy write (CA only), nontemporal ----
        if (ENERGY) {
            float* Ez = energy + (size_t)z * SQl * SKV;
#pragma unroll
            for (int j = 0; j < 4; ++j) {
                float* er = Ez + (size_t)(q0 + wid * 16 + l4 * 4 + j) * SKV + kv0;
#pragma unroll
                for (int n = 0; n < 8; ++n)
                    __builtin_nontemporal_store(sa[n][j], er + n * 16 + l15);
            }
        }
        // ---- online softmax ----
#pragma unroll
        for (int j = 0; j < 4; ++j) {
            float mx = sa[0][j];
#pragma unroll
            for (int n = 1; n < 8; ++n) mx = fmaxf(mx, sa[n][j]);
            mx *= scale;
            mx = fmaxf(mx, __shfl_xor(mx, 1));
            mx = fmaxf(mx, __shfl_xor(mx, 2));
            mx = fmaxf(mx, __shfl_xor(mx, 4));
            mx = fmaxf(mx, __shfl_xor(mx, 8));
            const float nm = fmaxf(mst[j], mx);
            const float f = __expf(mst[j] - nm);
            mst[j] = nm;
            float rs = 0.f;
#pragma unroll
            for (int n = 0; n < 8; ++n) {
                const float p = __expf(sa[n][j] * scale - nm);
                sa[n][j] = p;
                rs += p;
            }
            rs += __shfl_xor(rs, 1);
            rs += __shfl_xor(rs, 2);
            rs += __shfl_xor(rs, 4);
            rs += __shfl_xor(rs, 8);
            lst[j] = lst[j] * f + rs;
#pragma unroll
            for (int n = 0; n < 4; ++n) oacc[n][j] *= f;
        }
        // ---- P -> LDS (wave-private rows; no barrier) ----
#pragma unroll
        for (int n = 0; n < 8; ++n)
#pragma unroll
            for (int j = 0; j < 4; ++j)
                P[wid * 16 + l4 * 4 + j][n * 16 + l15] = __float2bfloat16(sa[n][j]);
        // ---- O += P @ V ----
#pragma unroll
        for (int ks = 0; ks < 4; ++ks) {
            const short8 aP = *(const short8*)(&P[wid * 16 + l15][ks * 32 + l4 * 8]);
#pragma unroll
            for (int n = 0; n < 4; ++n) {
                const short8 bV = *(const short8*)(Vp + (size_t)(n * 16 + l15) * ldvt + kv0 + ks * 32 + l4 * 8);
                oacc[n] = __builtin_amdgcn_mfma_f32_16x16x32_bf16(aP, bV, oacc[n], 0, 0, 0);
            }
        }
    }
    // ---- epilogue ----
    if (NSPLIT == 1) {
#pragma unroll
        for (int j = 0; j < 4; ++j) {
            const float rl = 1.f / lst[j];
            const size_t row = (size_t)b * SQl + q0 + wid * 16 + l4 * 4 + j;
#pragma unroll
            for (int n = 0; n < 4; ++n)
                O[row * 1024 + h * 64 + n * 16 + l15] = __float2bfloat16(oacc[n][j] * rl);
        }
    } else {
        float* Op = Opart + (size_t)split * OPART_STRIDE;
#pragma unroll
        for (int j = 0; j < 4; ++j) {
            const size_t row = (size_t)b * SQl + q0 + wid * 16 + l4 * 4 + j;
#pragma unroll
            for (int n = 0; n < 4; ++n)
                Op[row * 1024 + h * 64 + n * 16 + l15] = oacc[n][j];
            if (l15 == 0) {
                float2* st = (float2*)stats;
                st[((size_t)split * BB * HH + z) * SQl + q0 + wid * 16 + l4 * 4 + j] =
                    make_float2(mst[j], lst[j]);
            }
        }
    }
}

// ---- merge 2 kv-split partials: O = (O1*e^{m1-m} + O2*e^{m2-m}) / l --------
__global__ __launch_bounds__(256)
void merge_o(const float* __restrict__ Opart, const float* __restrict__ stats,
             bf16* __restrict__ O) {
    const size_t row = blockIdx.x;           // 0..B*SQ
    const int b = (int)(row >> 10), q = (int)(row & 1023);
    const int col = threadIdx.x * 4;
    const int h = col >> 6;
    const int zi = b * HH + h;
    const float2* st = (const float2*)stats;
    const float2 s1 = st[(size_t)zi * SQ_ + q];
    const float2 s2 = st[((size_t)BB * HH + zi) * SQ_ + q];
    const float m = fmaxf(s1.x, s2.x);
    const float w1 = __expf(s1.x - m), w2 = __expf(s2.x - m);
    const float invl = 1.f / (s1.y * w1 + s2.y * w2);
    const float4 o1 = *(const float4*)(Opart + row * 1024 + col);
    const float4 o2 = *(const float4*)(Opart + OPART_STRIDE + row * 1024 + col);
    union { ushort4 v; bf16 hh[4]; } r;
    r.hh[0] = __float2bfloat16((o1.x * w1 + o2.x * w2) * invl);
    r.hh[1] = __float2bfloat16((o1.y * w1 + o2.y * w2) * invl);
    r.hh[2] = __float2bfloat16((o1.z * w1 + o2.z * w2) * invl);
    r.hh[3] = __float2bfloat16((o1.w * w1 + o2.w * w2) * invl);
    *(ushort4*)(O + row * 1024 + col) = r.v;
}

extern "C" void kernel_launch(void* const* d_in, const int* in_sizes, int n_in,
                              void* d_out, int out_size, void* d_ws, size_t ws_size,
                              hipStream_t stream) {
    const float* queries  = (const float*)d_in[0];
    const float* contexts = (const float*)d_in[1];
    const float* sa_ln_g  = (const float*)d_in[2];
    const float* sa_ln_b  = (const float*)d_in[3];
    const float* sa_qkv_w = (const float*)d_in[4];
    const float* sa_out_w = (const float*)d_in[5];
    const float* sa_out_b = (const float*)d_in[6];
    const float* ca_ln_g  = (const float*)d_in[7];
    const float* ca_ln_b  = (const float*)d_in[8];
    const float* ca_q_w   = (const float*)d_in[9];
    const float* ca_k_w   = (const float*)d_in[10];
    const float* ca_v_w   = (const float*)d_in[11];
    const float* ca_out_w = (const float*)d_in[12];
    const float* ca_out_b = (const float*)d_in[13];
    const float* ff_ln1_g = (const float*)d_in[14];
    const float* ff_ln1_b = (const float*)d_in[15];
    const float* ff_w1    = (const float*)d_in[16];
    const float* ff_ln2_g = (const float*)d_in[17];
    const float* ff_ln2_b = (const float*)d_in[18];
    const float* ff_w2    = (const float*)d_in[19];

    float* out    = (float*)d_out;                     // 4M floats
    float* energy = out + (size_t)BB * SQ_ * CC;       // 128M floats

    const size_t MEG = 1024 * 1024;

    // ---- ws layout (float units) ----
    float* ws = (float*)d_ws;
    bf16*  X0_16      = (bf16*)ws;                                  // 8M bf16   [0,4M)
    bf16*  o16        = (bf16*)(ws + 4 * MEG);                      // 4M bf16   [4,6M)
    bf16*  ca_out_w16 = (bf16*)(ws + 6 * MEG);                      // 1M        [6,6.5M)
    bf16*  ff_w1_16   = (bf16*)(ws + (13 * MEG) / 2);               // 2M        [6.5,7.5M)
    bf16*  ff_w2_16   = (bf16*)(ws + (15 * MEG) / 2);               // 2M        [7.5,8.5M)
    bf16*  q_ca16     = (bf16*)(ws + (17 * MEG) / 2);               // 4M        [8.5,10.5M)
    bf16*  k_ca16     = (bf16*)(ws + (21 * MEG) / 2);               // 8M        [10.5,14.5M)
    bf16*  Vt_ca      = (bf16*)(ws + (29 * MEG) / 2);               // 8M        [14.5,18.5M)
    float* E_buf      = ws + (37 * MEG) / 2;                        // 4M fp32   [18.5,22.5M)
    float* C_buf      = ws + (45 * MEG) / 2;                        // 8M fp32   [22.5,30.5M)
    bf16*  v_ca16     = (bf16*)C_buf;            // 8M bf16 (dead after transpose)
    float* Opart      = C_buf;                   // 2 x 4M fp32 (CA flash partials)
    float* stats_buf  = ws + (61 * MEG) / 2;     // 256K floats [30.5,30.75M)

    // ---- early scratch inside energy region (dead before CA flash) ----
    bf16* EZ         = (bf16*)energy;
    bf16* ctx16      = EZ;                 // 8M
    bf16* qkv16      = EZ + 8  * MEG;      // 12M
    bf16* Vt_sa      = EZ + 20 * MEG;      // 4M
    bf16* qkv_w16    = EZ + 24 * MEG;      // 3M
    bf16* sa_out_w16 = EZ + 27 * MEG;      // 1M
    bf16* ca_q_w16   = EZ + 28 * MEG;      // 1M
    bf16* ca_k_w16   = EZ + 29 * MEG;      // 1M
    bf16* ca_v_w16   = EZ + 30 * MEG;      // 1M

    const int M1 = BB * SQ_;   // 4096
    const int M2 = BB * SK_;   // 8192
    const dim3 thr(256);
    auto cvt = [&](const float* src, bf16* dst, size_t n) {
        int n8 = (int)(n / 8);
        cvt_bf16<<<(n8 + 255) / 256, thr, 0, stream>>>(src, dst, n8);
    };

    // ---- conversions ----
    cvt(sa_qkv_w, qkv_w16,    3 * MEG);
    cvt(sa_out_w, sa_out_w16, 1 * MEG);
    cvt(ca_q_w,   ca_q_w16,   1 * MEG);
    cvt(ca_k_w,   ca_k_w16,   1 * MEG);
    cvt(ca_v_w,   ca_v_w16,   1 * MEG);
    cvt(ca_out_w, ca_out_w16, 1 * MEG);
    cvt(ff_w1,    ff_w1_16,   2 * MEG);
    cvt(ff_w2,    ff_w2_16,   2 * MEG);
    cvt(contexts, ctx16,      8 * MEG);

    // ---- Self attention ----
    ln_kernel<1024><<<M1, thr, 0, stream>>>(queries, sa_ln_g, sa_ln_b, X0_16, 0);
    gemm_bt16<1><<<dim3(3072 / 128, M1 / 128), thr, 0, stream>>>(X0_16, qkv_w16, qkv16,
                                                                 M1, 3072, 1024, nullptr, nullptr);
    transpose_v<<<dim3(M1 / 64, 1024 / 64), thr, 0, stream>>>(qkv16, 3072, 192, 128, Vt_sa, M1);
    flash_attn<false, 1><<<dim3(SQ_ / 64, BB * HH, 1), thr, 0, stream>>>(
        qkv16, 3072, 192, qkv16, 3072, 192, 64, Vt_sa, M1,
        o16, nullptr, nullptr, nullptr, SQ_, SQ_, SCALE);
    gemm_bt16<0><<<dim3(1024 / 128, M1 / 128), thr, 0, stream>>>(o16, sa_out_w16, E_buf,
                                                                 M1, CC, CC, sa_out_b, queries);

    // ---- Cross attention ----
    ln_kernel<1024><<<M1, thr, 0, stream>>>(E_buf, ca_ln_g, ca_ln_b, X0_16, 0);
    gemm_bt16<1><<<dim3(1024 / 128, M1 / 128), thr, 0, stream>>>(X0_16, ca_q_w16, q_ca16,
                                                                 M1, CC, CC, nullptr, nullptr);
    gemm_bt16<1><<<dim3(1024 / 128, M2 / 128), thr, 0, stream>>>(ctx16, ca_k_w16, k_ca16,
                                                                 M2, CC, CC, nullptr, nullptr);
    gemm_bt16<1><<<dim3(1024 / 128, M2 / 128), thr, 0, stream>>>(ctx16, ca_v_w16, v_ca16,
                                                                 M2, CC, CC, nullptr, nullptr);
    transpose_v<<<dim3(M2 / 64, 1024 / 64), thr, 0, stream>>>(v_ca16, 1024, 64, 0, Vt_ca, M2);
    // CA flash: raw energy (final) + fp32 partial O (2 kv-splits). Energy-region
    // scratch (ctx16/qkv16/Vt_sa/weights) and v_ca16 are dead by this point.
    flash_attn<true, 2><<<dim3(SQ_ / 64, BB * HH, 2), thr, 0, stream>>>(
        q_ca16, 1024, 64, k_ca16, 1024, 64, 0, Vt_ca, M2,
        nullptr, Opart, stats_buf, energy, SK_, SQ_, SCALE);
    merge_o<<<M1, thr, 0, stream>>>(Opart, stats_buf, o16);
    gemm_bt16<0><<<dim3(1024 / 128, M1 / 128), thr, 0, stream>>>(o16, ca_out_w16, E_buf,
                                                                 M1, CC, CC, ca_out_b, E_buf);

    // ---- FFN ----
    ln_kernel<1024><<<M1, thr, 0, stream>>>(E_buf, ff_ln1_g, ff_ln1_b, X0_16, 1);
    gemm_bt16<0><<<dim3(2048 / 128, M1 / 128), thr, 0, stream>>>(X0_16, ff_w1_16, C_buf,
                                                                 M1, 2048, 1024, nullptr, nullptr);
    ln_kernel<2048><<<M1, thr, 0, stream>>>(C_buf, ff_ln2_g, ff_ln2_b, X0_16, 1);
    gemm_bt16<0><<<dim3(1024 / 128, M1 / 128), thr, 0, stream>>>(X0_16, ff_w2_16, out,
                                                                 M1, CC, 2048, nullptr, E_buf);
}

// Round 6
// 821.305 us; speedup vs baseline: 4.3567x; 1.0255x over previous
//
#include <hip/hip_runtime.h>
#include <hip/hip_bf16.h>
#include <math.h>

// CrossTransformer block. Round 5b: swapped QK^T (S^T) in flash-attn ->
// coalesced f32x4 energy stores straight from registers + cheaper softmax.
// (5a failed: __builtin_nontemporal_store needs clang ext vector, not float4.)
// B=4, SQ=1024, SK=2048, C=1024, H=16, DH=64.

namespace {
constexpr int BB  = 4;
constexpr int SQ_ = 1024;
constexpr int SK_ = 2048;
constexpr int CC  = 1024;
constexpr int HH  = 16;
constexpr float SCALE  = 0.03125f;   // 1/sqrt(1024)
constexpr float LN_EPS = 1e-5f;
constexpr size_t OPART_STRIDE = (size_t)BB * SQ_ * CC;   // 4M elems per split
}

typedef __hip_bfloat16 bf16;
typedef __attribute__((ext_vector_type(8))) short short8;
typedef __attribute__((ext_vector_type(4))) float f32x4;

__device__ __forceinline__ void gload16(const void* g, void* l) {
    __builtin_amdgcn_global_load_lds((const __attribute__((address_space(1))) unsigned int*)g,
                                     (__attribute__((address_space(3))) unsigned int*)l,
                                     16, 0, 0);
}

// ---------------- fp32 -> bf16 convert (8 elems/thread) ----------------
__global__ __launch_bounds__(256)
void cvt_bf16(const float* __restrict__ in, bf16* __restrict__ out, int n8) {
    const int i = blockIdx.x * 256 + threadIdx.x;
    if (i >= n8) return;
    const float4 a = ((const float4*)in)[2 * i];
    const float4 b = ((const float4*)in)[2 * i + 1];
    union { ushort4 v; bf16 h[4]; } lo, hi;
    lo.h[0] = __float2bfloat16(a.x); lo.h[1] = __float2bfloat16(a.y);
    lo.h[2] = __float2bfloat16(a.z); lo.h[3] = __float2bfloat16(a.w);
    hi.h[0] = __float2bfloat16(b.x); hi.h[1] = __float2bfloat16(b.y);
    hi.h[2] = __float2bfloat16(b.z); hi.h[3] = __float2bfloat16(b.w);
    ((ushort4*)out)[2 * i]     = lo.v;
    ((ushort4*)out)[2 * i + 1] = hi.v;
}

// ---------------- LayerNorm (+optional SiLU), bf16 out ----------------
template<int NCOLS>
__global__ __launch_bounds__(256)
void ln_kernel(const float* __restrict__ x, const float* __restrict__ g,
               const float* __restrict__ b, bf16* __restrict__ out, int do_silu) {
    constexpr int PER = NCOLS / 256;
    const size_t row = blockIdx.x;
    const float* xr = x + row * NCOLS;
    float vals[PER];
    float s = 0.f, ss = 0.f;
#pragma unroll
    for (int i = 0; i < PER; ++i) {
        vals[i] = xr[threadIdx.x + i * 256];
        s += vals[i];
        ss += vals[i] * vals[i];
    }
    for (int off = 32; off > 0; off >>= 1) {
        s  += __shfl_down(s, off, 64);
        ss += __shfl_down(ss, off, 64);
    }
    __shared__ float red[10];
    const int wid = threadIdx.x >> 6, lane = threadIdx.x & 63;
    if (lane == 0) { red[wid] = s; red[wid + 4] = ss; }
    __syncthreads();
    if (threadIdx.x == 0) {
        const float ts  = red[0] + red[1] + red[2] + red[3];
        const float tss = red[4] + red[5] + red[6] + red[7];
        const float mu  = ts / NCOLS;
        const float var = tss / NCOLS - mu * mu;
        red[8] = mu;
        red[9] = rsqrtf(var + LN_EPS);
    }
    __syncthreads();
    const float mu = red[8], rstd = red[9];
    bf16* outr = out + row * NCOLS;
#pragma unroll
    for (int i = 0; i < PER; ++i) {
        const int c = threadIdx.x + i * 256;
        float y = (vals[i] - mu) * rstd * g[c] + b[c];
        if (do_silu) y = y / (1.f + __expf(-y));
        outr[c] = __float2bfloat16(y);
    }
}

// ------------- bf16 MFMA GEMM: C[M,N] = A[M,K] @ B[N,K]^T (+bias)(+resid) ---
template<int OUT16>
__global__ __launch_bounds__(256)
void gemm_bt16(const bf16* __restrict__ A, const bf16* __restrict__ B,
               void* __restrict__ Cv, int M, int N, int K,
               const float* __restrict__ bias, const float* __restrict__ resid) {
    __shared__ bf16 As[128 * 32];
    __shared__ bf16 Bs[128 * 32];
    const int tid  = threadIdx.x;
    const int lane = tid & 63;
    const int w    = tid >> 6;
    const int wr = w >> 1, wc = w & 1;
    const int m0 = blockIdx.y * 128, n0 = blockIdx.x * 128;

    f32x4 acc[4][4] = {};

    const int srow = tid >> 2;
    const int scol = (tid & 3) * 8;
    const bf16* Ap  = A + (size_t)(m0 + srow) * K + scol;
    const bf16* Ap2 = Ap + (size_t)64 * K;
    const bf16* Bp  = B + (size_t)(n0 + srow) * K + scol;
    const bf16* Bp2 = Bp + (size_t)64 * K;

    char* AsB = (char*)As + w * 1024;
    char* BsB = (char*)Bs + w * 1024;

    const int arow = wr * 64 + (lane & 15);
    const int brow = wc * 64 + (lane & 15);
    const int kgrp = (lane >> 4) * 16;

    for (int k0 = 0; k0 < K; k0 += 32) {
        gload16(Ap  + k0, AsB);
        gload16(Ap2 + k0, AsB + 4096);
        gload16(Bp  + k0, BsB);
        gload16(Bp2 + k0, BsB + 4096);
        __syncthreads();
        short8 aF[4], bF[4];
#pragma unroll
        for (int m = 0; m < 4; ++m)
            aF[m] = *(const short8*)((const char*)As + ((arow + m * 16) * 64 + kgrp));
#pragma unroll
        for (int n = 0; n < 4; ++n)
            bF[n] = *(const short8*)((const char*)Bs + ((brow + n * 16) * 64 + kgrp));
#pragma unroll
        for (int m = 0; m < 4; ++m)
#pragma unroll
            for (int n = 0; n < 4; ++n)
                acc[m][n] = __builtin_amdgcn_mfma_f32_16x16x32_bf16(aF[m], bF[n], acc[m][n], 0, 0, 0);
        __syncthreads();
    }

    const int crow0 = m0 + wr * 64 + (lane >> 4) * 4;
    const int ccol0 = n0 + wc * 64 + (lane & 15);
#pragma unroll
    for (int m = 0; m < 4; ++m) {
#pragma unroll
        for (int n = 0; n < 4; ++n) {
            const int col = ccol0 + n * 16;
            const float bv = (!OUT16 && bias) ? bias[col] : 0.f;
#pragma unroll
            for (int j = 0; j < 4; ++j) {
                const int row = crow0 + m * 16 + j;
                float v = acc[m][n][j] + bv;
                if (!OUT16 && resid) v += resid[(size_t)row * N + col];
                if (OUT16) ((bf16*)Cv)[(size_t)row * N + col] = __float2bfloat16(v);
                else       ((float*)Cv)[(size_t)row * N + col] = v;
            }
        }
    }
}

// --------- tiled transpose: T[c][r] = X[r][(c/64)*cs + co + (c%64)] ---------
__global__ __launch_bounds__(256)
void transpose_v(const bf16* __restrict__ X, int ldx, int cs, int co,
                 bf16* __restrict__ T, int ldt) {
    __shared__ bf16 t[64][66];
    const int r0 = blockIdx.x * 64, c0 = blockIdx.y * 64;
#pragma unroll
    for (int s = 0; s < 16; ++s) {
        const int r = (threadIdx.x >> 6) + s * 4;
        const int c = threadIdx.x & 63;
        const int cc = c0 + c;
        t[r][c] = X[(size_t)(r0 + r) * ldx + (size_t)(cc >> 6) * cs + co + (cc & 63)];
    }
    __syncthreads();
#pragma unroll
    for (int s = 0; s < 16; ++s) {
        const int c = (threadIdx.x >> 6) + s * 4;
        const int r = threadIdx.x & 63;
        T[(size_t)(c0 + c) * ldt + r0 + r] = t[r][c];
    }
}

// --------------- fused flash attention (swapped QK^T) ----------------------
// 64 q-rows per block, 4 waves x 16 rows, KV tiles of 128, DH=64, H=16.
// S^T = mfma(K, Q): per lane q = l15, kv = n*16 + l4*4 + reg -> energy is a
// direct f32x4 store (16 full 64B lines per wave-store).
// ENERGY: write raw QK^T. NSPLIT: kv-split over blockIdx.z (fp32 partials).
template<bool ENERGY, int NSPLIT>
__global__ __launch_bounds__(256)
void flash_attn(const bf16* __restrict__ Qb, int ldq, int qh_str,
                const bf16* __restrict__ Kb, int ldk, int kh_str, int kh_add,
                const bf16* __restrict__ Vt, int ldvt,
                bf16* __restrict__ O, float* __restrict__ Opart,
                float* __restrict__ stats, float* __restrict__ energy,
                int SKV, int SQl, float scale) {
    __shared__ bf16 P[64][136];
    const int tid = threadIdx.x;
    const int lane = tid & 63, wid = tid >> 6;
    const int l15 = lane & 15, l4 = lane >> 4;
    const int z = blockIdx.y, b = z >> 4, h = z & 15;
    const int q0 = blockIdx.x * 64;
    const int split = (NSPLIT > 1) ? blockIdx.z : 0;
    const int kv_begin = split * (SKV / NSPLIT);
    const int kv_end   = kv_begin + SKV / NSPLIT;

    const bf16* Qp = Qb + (size_t)b * SQl * ldq + (size_t)h * qh_str;
    const bf16* Kp = Kb + (size_t)b * SKV * ldk + (size_t)h * kh_str + kh_add;
    const bf16* Vp = Vt + (size_t)h * 64 * ldvt + (size_t)b * SKV;

    // Q fragments (B-operand): row q = q0 + wid*16 + l15, k = s*32 + l4*8
    short8 aQ[2];
#pragma unroll
    for (int s = 0; s < 2; ++s)
        aQ[s] = *(const short8*)(Qp + (size_t)(q0 + wid * 16 + l15) * ldq + s * 32 + l4 * 8);

    f32x4 oacc[4] = {};
    float mI = -1e30f, lI = 0.f;      // per-lane stats for q-row = q0+wid*16+l15

    for (int kv0 = kv_begin; kv0 < kv_end; kv0 += 128) {
        // ---- S^T = K @ Q^T (raw, fp32 accum): sa[n][j] = S[q=l15][kv=n*16+l4*4+j]
        f32x4 sa[8] = {};
#pragma unroll
        for (int n = 0; n < 8; ++n) {
            const bf16* kr = Kp + (size_t)(kv0 + n * 16 + l15) * ldk + l4 * 8;
            const short8 b0 = *(const short8*)(kr);
            const short8 b1 = *(const short8*)(kr + 32);
            sa[n] = __builtin_amdgcn_mfma_f32_16x16x32_bf16(b0, aQ[0], sa[n], 0, 0, 0);
            sa[n] = __builtin_amdgcn_mfma_f32_16x16x32_bf16(b1, aQ[1], sa[n], 0, 0, 0);
        }
        // ---- raw energy write: f32x4 per lane, fully-coalesced 64B rows ----
        if (ENERGY) {
            float* er = energy + (size_t)z * SQl * SKV
                      + (size_t)(q0 + wid * 16 + l15) * SKV + kv0 + l4 * 4;
#pragma unroll
            for (int n = 0; n < 8; ++n)
                __builtin_nontemporal_store(sa[n], (f32x4*)(er + n * 16));
        }
        // ---- online softmax (row q = l15; 32 in-lane values + 2 shfls) ----
        float mx = -1e30f;
#pragma unroll
        for (int n = 0; n < 8; ++n) {
            const float m01 = fmaxf(sa[n][0], sa[n][1]);
            const float m23 = fmaxf(sa[n][2], sa[n][3]);
            mx = fmaxf(mx, fmaxf(m01, m23));
        }
        mx *= scale;
        mx = fmaxf(mx, __shfl_xor(mx, 16, 64));
        mx = fmaxf(mx, __shfl_xor(mx, 32, 64));
        const float nm = fmaxf(mI, mx);
        const float f = __expf(mI - nm);
        mI = nm;
        float rs = 0.f;
#pragma unroll
        for (int n = 0; n < 8; ++n)
#pragma unroll
            for (int j = 0; j < 4; ++j) {
                const float p = __expf(sa[n][j] * scale - nm);
                sa[n][j] = p;
                rs += p;
            }
        rs += __shfl_xor(rs, 16, 64);
        rs += __shfl_xor(rs, 32, 64);
        lI = lI * f + rs;
        // ---- rescale O (O-layout rows are q = l4*4+j -> fetch f via shfl) ----
#pragma unroll
        for (int j = 0; j < 4; ++j) {
            const float fj = __shfl(f, l4 * 4 + j, 64);
#pragma unroll
            for (int n = 0; n < 4; ++n) oacc[n][j] *= fj;
        }
        // ---- P^T -> LDS (packed 8B, wave-private rows) ----
#pragma unroll
        for (int n = 0; n < 8; ++n) {
            union { ushort4 v; bf16 hh[4]; } pk;
            pk.hh[0] = __float2bfloat16(sa[n][0]);
            pk.hh[1] = __float2bfloat16(sa[n][1]);
            pk.hh[2] = __float2bfloat16(sa[n][2]);
            pk.hh[3] = __float2bfloat16(sa[n][3]);
            *(ushort4*)(&P[wid * 16 + l15][n * 16 + l4 * 4]) = pk.v;
        }
        // ---- O += P @ V ----
#pragma unroll
        for (int ks = 0; ks < 4; ++ks) {
            const short8 aP = *(const short8*)(&P[wid * 16 + l15][ks * 32 + l4 * 8]);
#pragma unroll
            for (int n = 0; n < 4; ++n) {
                const short8 bV = *(const short8*)(Vp + (size_t)(n * 16 + l15) * ldvt + kv0 + ks * 32 + l4 * 8);
                oacc[n] = __builtin_amdgcn_mfma_f32_16x16x32_bf16(aP, bV, oacc[n], 0, 0, 0);
            }
        }
    }
    // ---- epilogue (O rows q = l4*4+j; stats live at q = l15) ----
    if (NSPLIT == 1) {
#pragma unroll
        for (int j = 0; j < 4; ++j) {
            const float lj = __shfl(lI, l4 * 4 + j, 64);
            const float rl = 1.f / lj;
            const size_t row = (size_t)b * SQl + q0 + wid * 16 + l4 * 4 + j;
#pragma unroll
            for (int n = 0; n < 4; ++n)
                O[row * 1024 + h * 64 + n * 16 + l15] = __float2bfloat16(oacc[n][j] * rl);
        }
    } else {
        float* Op = Opart + (size_t)split * OPART_STRIDE;
#pragma unroll
        for (int j = 0; j < 4; ++j) {
            const size_t row = (size_t)b * SQl + q0 + wid * 16 + l4 * 4 + j;
#pragma unroll
            for (int n = 0; n < 4; ++n)
                Op[row * 1024 + h * 64 + n * 16 + l15] = oacc[n][j];
        }
        if (l4 == 0) {   // one writer per q-row: lane l15 holds (mI,lI) for its row
            float2* st = (float2*)stats;
            st[((size_t)split * BB * HH + z) * SQl + q0 + wid * 16 + l15] =
                make_float2(mI, lI);
        }
    }
}

// ---- merge 2 kv-split partials: O = (O1*e^{m1-m} + O2*e^{m2-m}) / l --------
__global__ __launch_bounds__(256)
void merge_o(const float* __restrict__ Opart, const float* __restrict__ stats,
             bf16* __restrict__ O) {
    const size_t row = blockIdx.x;           // 0..B*SQ
    const int b = (int)(row >> 10), q = (int)(row & 1023);
    const int col = threadIdx.x * 4;
    const int h = col >> 6;
    const int zi = b * HH + h;
    const float2* st = (const float2*)stats;
    const float2 s1 = st[(size_t)zi * SQ_ + q];
    const float2 s2 = st[((size_t)BB * HH + zi) * SQ_ + q];
    const float m = fmaxf(s1.x, s2.x);
    const float w1 = __expf(s1.x - m), w2 = __expf(s2.x - m);
    const float invl = 1.f / (s1.y * w1 + s2.y * w2);
    const float4 o1 = *(const float4*)(Opart + row * 1024 + col);
    const float4 o2 = *(const float4*)(Opart + OPART_STRIDE + row * 1024 + col);
    union { ushort4 v; bf16 hh[4]; } r;
    r.hh[0] = __float2bfloat16((o1.x * w1 + o2.x * w2) * invl);
    r.hh[1] = __float2bfloat16((o1.y * w1 + o2.y * w2) * invl);
    r.hh[2] = __float2bfloat16((o1.z * w1 + o2.z * w2) * invl);
    r.hh[3] = __float2bfloat16((o1.w * w1 + o2.w * w2) * invl);
    *(ushort4*)(O + row * 1024 + col) = r.v;
}

extern "C" void kernel_launch(void* const* d_in, const int* in_sizes, int n_in,
                              void* d_out, int out_size, void* d_ws, size_t ws_size,
                              hipStream_t stream) {
    const float* queries  = (const float*)d_in[0];
    const float* contexts = (const float*)d_in[1];
    const float* sa_ln_g  = (const float*)d_in[2];
    const float* sa_ln_b  = (const float*)d_in[3];
    const float* sa_qkv_w = (const float*)d_in[4];
    const float* sa_out_w = (const float*)d_in[5];
    const float* sa_out_b = (const float*)d_in[6];
    const float* ca_ln_g  = (const float*)d_in[7];
    const float* ca_ln_b  = (const float*)d_in[8];
    const float* ca_q_w   = (const float*)d_in[9];
    const float* ca_k_w   = (const float*)d_in[10];
    const float* ca_v_w   = (const float*)d_in[11];
    const float* ca_out_w = (const float*)d_in[12];
    const float* ca_out_b = (const float*)d_in[13];
    const float* ff_ln1_g = (const float*)d_in[14];
    const float* ff_ln1_b = (const float*)d_in[15];
    const float* ff_w1    = (const float*)d_in[16];
    const float* ff_ln2_g = (const float*)d_in[17];
    const float* ff_ln2_b = (const float*)d_in[18];
    const float* ff_w2    = (const float*)d_in[19];

    float* out    = (float*)d_out;                     // 4M floats
    float* energy = out + (size_t)BB * SQ_ * CC;       // 128M floats

    const size_t MEG = 1024 * 1024;

    // ---- ws layout (float units) ----
    float* ws = (float*)d_ws;
    bf16*  X0_16      = (bf16*)ws;                                  // 8M bf16   [0,4M)
    bf16*  o16        = (bf16*)(ws + 4 * MEG);                      // 4M bf16   [4,6M)
    bf16*  ca_out_w16 = (bf16*)(ws + 6 * MEG);                      // 1M        [6,6.5M)
    bf16*  ff_w1_16   = (bf16*)(ws + (13 * MEG) / 2);               // 2M        [6.5,7.5M)
    bf16*  ff_w2_16   = (bf16*)(ws + (15 * MEG) / 2);               // 2M        [7.5,8.5M)
    bf16*  q_ca16     = (bf16*)(ws + (17 * MEG) / 2);               // 4M        [8.5,10.5M)
    bf16*  k_ca16     = (bf16*)(ws + (21 * MEG) / 2);               // 8M        [10.5,14.5M)
    bf16*  Vt_ca      = (bf16*)(ws + (29 * MEG) / 2);               // 8M        [14.5,18.5M)
    float* E_buf      = ws + (37 * MEG) / 2;                        // 4M fp32   [18.5,22.5M)
    float* C_buf      = ws + (45 * MEG) / 2;                        // 8M fp32   [22.5,30.5M)
    bf16*  v_ca16     = (bf16*)C_buf;            // 8M bf16 (dead after transpose)
    float* Opart      = C_buf;                   // 2 x 4M fp32 (CA flash partials)
    float* stats_buf  = ws + (61 * MEG) / 2;     // 256K floats [30.5,30.75M)

    // ---- early scratch inside energy region (dead before CA flash) ----
    bf16* EZ         = (bf16*)energy;
    bf16* ctx16      = EZ;                 // 8M
    bf16* qkv16      = EZ + 8  * MEG;      // 12M
    bf16* Vt_sa      = EZ + 20 * MEG;      // 4M
    bf16* qkv_w16    = EZ + 24 * MEG;      // 3M
    bf16* sa_out_w16 = EZ + 27 * MEG;      // 1M
    bf16* ca_q_w16   = EZ + 28 * MEG;      // 1M
    bf16* ca_k_w16   = EZ + 29 * MEG;      // 1M
    bf16* ca_v_w16   = EZ + 30 * MEG;      // 1M

    const int M1 = BB * SQ_;   // 4096
    const int M2 = BB * SK_;   // 8192
    const dim3 thr(256);
    auto cvt = [&](const float* src, bf16* dst, size_t n) {
        int n8 = (int)(n / 8);
        cvt_bf16<<<(n8 + 255) / 256, thr, 0, stream>>>(src, dst, n8);
    };

    // ---- conversions ----
    cvt(sa_qkv_w, qkv_w16,    3 * MEG);
    cvt(sa_out_w, sa_out_w16, 1 * MEG);
    cvt(ca_q_w,   ca_q_w16,   1 * MEG);
    cvt(ca_k_w,   ca_k_w16,   1 * MEG);
    cvt(ca_v_w,   ca_v_w16,   1 * MEG);
    cvt(ca_out_w, ca_out_w16, 1 * MEG);
    cvt(ff_w1,    ff_w1_16,   2 * MEG);
    cvt(ff_w2,    ff_w2_16,   2 * MEG);
    cvt(contexts, ctx16,      8 * MEG);

    // ---- Self attention ----
    ln_kernel<1024><<<M1, thr, 0, stream>>>(queries, sa_ln_g, sa_ln_b, X0_16, 0);
    gemm_bt16<1><<<dim3(3072 / 128, M1 / 128), thr, 0, stream>>>(X0_16, qkv_w16, qkv16,
                                                                 M1, 3072, 1024, nullptr, nullptr);
    transpose_v<<<dim3(M1 / 64, 1024 / 64), thr, 0, stream>>>(qkv16, 3072, 192, 128, Vt_sa, M1);
    flash_attn<false, 1><<<dim3(SQ_ / 64, BB * HH, 1), thr, 0, stream>>>(
        qkv16, 3072, 192, qkv16, 3072, 192, 64, Vt_sa, M1,
        o16, nullptr, nullptr, nullptr, SQ_, SQ_, SCALE);
    gemm_bt16<0><<<dim3(1024 / 128, M1 / 128), thr, 0, stream>>>(o16, sa_out_w16, E_buf,
                                                                 M1, CC, CC, sa_out_b, queries);

    // ---- Cross attention ----
    ln_kernel<1024><<<M1, thr, 0, stream>>>(E_buf, ca_ln_g, ca_ln_b, X0_16, 0);
    gemm_bt16<1><<<dim3(1024 / 128, M1 / 128), thr, 0, stream>>>(X0_16, ca_q_w16, q_ca16,
                                                                 M1, CC, CC, nullptr, nullptr);
    gemm_bt16<1><<<dim3(1024 / 128, M2 / 128), thr, 0, stream>>>(ctx16, ca_k_w16, k_ca16,
                                                                 M2, CC, CC, nullptr, nullptr);
    gemm_bt16<1><<<dim3(1024 / 128, M2 / 128), thr, 0, stream>>>(ctx16, ca_v_w16, v_ca16,
                                                                 M2, CC, CC, nullptr, nullptr);
    transpose_v<<<dim3(M2 / 64, 1024 / 64), thr, 0, stream>>>(v_ca16, 1024, 64, 0, Vt_ca, M2);
    // CA flash: raw energy (final) + fp32 partial O (2 kv-splits). Energy-region
    // scratch (ctx16/qkv16/Vt_sa/weights) and v_ca16 are dead by this point.
    flash_attn<true, 2><<<dim3(SQ_ / 64, BB * HH, 2), thr, 0, stream>>>(
        q_ca16, 1024, 64, k_ca16, 1024, 64, 0, Vt_ca, M2,
        nullptr, Opart, stats_buf, energy, SK_, SQ_, SCALE);
    merge_o<<<M1, thr, 0, stream>>>(Opart, stats_buf, o16);
    gemm_bt16<0><<<dim3(1024 / 128, M1 / 128), thr, 0, stream>>>(o16, ca_out_w16, E_buf,
                                                                 M1, CC, CC, ca_out_b, E_buf);

    // ---- FFN ----
    ln_kernel<1024><<<M1, thr, 0, stream>>>(E_buf, ff_ln1_g, ff_ln1_b, X0_16, 1);
    gemm_bt16<0><<<dim3(2048 / 128, M1 / 128), thr, 0, stream>>>(X0_16, ff_w1_16, C_buf,
                                                                 M1, 2048, 1024, nullptr, nullptr);
    ln_kernel<2048><<<M1, thr, 0, stream>>>(C_buf, ff_ln2_g, ff_ln2_b, X0_16, 1);
    gemm_bt16<0><<<dim3(1024 / 128, M1 / 128), thr, 0, stream>>>(X0_16, ff_w2_16, out,
                                                                 M1, CC, 2048, nullptr, E_buf);
}

// Round 7
// 759.969 us; speedup vs baseline: 4.7083x; 1.0807x over previous
//
#include <hip/hip_runtime.h>
#include <hip/hip_bf16.h>
#include <math.h>

// CrossTransformer block. Round 7: flash-attn VGPR cut (KV tile 64, lb(256,4)
// -> 4 waves/SIMD) + XCD-aware block swizzle on flash + GEMMs.
// B=4, SQ=1024, SK=2048, C=1024, H=16, DH=64.

namespace {
constexpr int BB  = 4;
constexpr int SQ_ = 1024;
constexpr int SK_ = 2048;
constexpr int CC  = 1024;
constexpr int HH  = 16;
constexpr float SCALE  = 0.03125f;   // 1/sqrt(1024)
constexpr float LN_EPS = 1e-5f;
constexpr size_t OPART_STRIDE = (size_t)BB * SQ_ * CC;   // 4M elems per split
}

typedef __hip_bfloat16 bf16;
typedef __attribute__((ext_vector_type(8))) short short8;
typedef __attribute__((ext_vector_type(4))) float f32x4;

__device__ __forceinline__ void gload16(const void* g, void* l) {
    __builtin_amdgcn_global_load_lds((const __attribute__((address_space(1))) unsigned int*)g,
                                     (__attribute__((address_space(3))) unsigned int*)l,
                                     16, 0, 0);
}

// ---------------- fp32 -> bf16 convert (8 elems/thread) ----------------
__global__ __launch_bounds__(256)
void cvt_bf16(const float* __restrict__ in, bf16* __restrict__ out, int n8) {
    const int i = blockIdx.x * 256 + threadIdx.x;
    if (i >= n8) return;
    const float4 a = ((const float4*)in)[2 * i];
    const float4 b = ((const float4*)in)[2 * i + 1];
    union { ushort4 v; bf16 h[4]; } lo, hi;
    lo.h[0] = __float2bfloat16(a.x); lo.h[1] = __float2bfloat16(a.y);
    lo.h[2] = __float2bfloat16(a.z); lo.h[3] = __float2bfloat16(a.w);
    hi.h[0] = __float2bfloat16(b.x); hi.h[1] = __float2bfloat16(b.y);
    hi.h[2] = __float2bfloat16(b.z); hi.h[3] = __float2bfloat16(b.w);
    ((ushort4*)out)[2 * i]     = lo.v;
    ((ushort4*)out)[2 * i + 1] = hi.v;
}

// ---------------- LayerNorm (+optional SiLU), bf16 out ----------------
template<int NCOLS>
__global__ __launch_bounds__(256)
void ln_kernel(const float* __restrict__ x, const float* __restrict__ g,
               const float* __restrict__ b, bf16* __restrict__ out, int do_silu) {
    constexpr int PER = NCOLS / 256;
    const size_t row = blockIdx.x;
    const float* xr = x + row * NCOLS;
    float vals[PER];
    float s = 0.f, ss = 0.f;
#pragma unroll
    for (int i = 0; i < PER; ++i) {
        vals[i] = xr[threadIdx.x + i * 256];
        s += vals[i];
        ss += vals[i] * vals[i];
    }
    for (int off = 32; off > 0; off >>= 1) {
        s  += __shfl_down(s, off, 64);
        ss += __shfl_down(ss, off, 64);
    }
    __shared__ float red[10];
    const int wid = threadIdx.x >> 6, lane = threadIdx.x & 63;
    if (lane == 0) { red[wid] = s; red[wid + 4] = ss; }
    __syncthreads();
    if (threadIdx.x == 0) {
        const float ts  = red[0] + red[1] + red[2] + red[3];
        const float tss = red[4] + red[5] + red[6] + red[7];
        const float mu  = ts / NCOLS;
        const float var = tss / NCOLS - mu * mu;
        red[8] = mu;
        red[9] = rsqrtf(var + LN_EPS);
    }
    __syncthreads();
    const float mu = red[8], rstd = red[9];
    bf16* outr = out + row * NCOLS;
#pragma unroll
    for (int i = 0; i < PER; ++i) {
        const int c = threadIdx.x + i * 256;
        float y = (vals[i] - mu) * rstd * g[c] + b[c];
        if (do_silu) y = y / (1.f + __expf(-y));
        outr[c] = __float2bfloat16(y);
    }
}

// ------------- bf16 MFMA GEMM: C[M,N] = A[M,K] @ B[N,K]^T (+bias)(+resid) ---
// XCD-swizzled blockIdx for A-panel L2 locality (all grids are %8 == 0).
template<int OUT16>
__global__ __launch_bounds__(256)
void gemm_bt16(const bf16* __restrict__ A, const bf16* __restrict__ B,
               void* __restrict__ Cv, int M, int N, int K,
               const float* __restrict__ bias, const float* __restrict__ resid) {
    __shared__ bf16 As[128 * 32];
    __shared__ bf16 Bs[128 * 32];
    const int tid  = threadIdx.x;
    const int lane = tid & 63;
    const int w    = tid >> 6;
    const int wr = w >> 1, wc = w & 1;

    const int nwg = gridDim.x * gridDim.y;
    const int bid = blockIdx.x + gridDim.x * blockIdx.y;
    const int logical = (bid & 7) * (nwg >> 3) + (bid >> 3);
    const int m0 = (logical / gridDim.x) * 128;
    const int n0 = (logical % gridDim.x) * 128;

    f32x4 acc[4][4] = {};

    const int srow = tid >> 2;
    const int scol = (tid & 3) * 8;
    const bf16* Ap  = A + (size_t)(m0 + srow) * K + scol;
    const bf16* Ap2 = Ap + (size_t)64 * K;
    const bf16* Bp  = B + (size_t)(n0 + srow) * K + scol;
    const bf16* Bp2 = Bp + (size_t)64 * K;

    char* AsB = (char*)As + w * 1024;
    char* BsB = (char*)Bs + w * 1024;

    const int arow = wr * 64 + (lane & 15);
    const int brow = wc * 64 + (lane & 15);
    const int kgrp = (lane >> 4) * 16;

    for (int k0 = 0; k0 < K; k0 += 32) {
        gload16(Ap  + k0, AsB);
        gload16(Ap2 + k0, AsB + 4096);
        gload16(Bp  + k0, BsB);
        gload16(Bp2 + k0, BsB + 4096);
        __syncthreads();
        short8 aF[4], bF[4];
#pragma unroll
        for (int m = 0; m < 4; ++m)
            aF[m] = *(const short8*)((const char*)As + ((arow + m * 16) * 64 + kgrp));
#pragma unroll
        for (int n = 0; n < 4; ++n)
            bF[n] = *(const short8*)((const char*)Bs + ((brow + n * 16) * 64 + kgrp));
#pragma unroll
        for (int m = 0; m < 4; ++m)
#pragma unroll
            for (int n = 0; n < 4; ++n)
                acc[m][n] = __builtin_amdgcn_mfma_f32_16x16x32_bf16(aF[m], bF[n], acc[m][n], 0, 0, 0);
        __syncthreads();
    }

    const int crow0 = m0 + wr * 64 + (lane >> 4) * 4;
    const int ccol0 = n0 + wc * 64 + (lane & 15);
#pragma unroll
    for (int m = 0; m < 4; ++m) {
#pragma unroll
        for (int n = 0; n < 4; ++n) {
            const int col = ccol0 + n * 16;
            const float bv = (!OUT16 && bias) ? bias[col] : 0.f;
#pragma unroll
            for (int j = 0; j < 4; ++j) {
                const int row = crow0 + m * 16 + j;
                float v = acc[m][n][j] + bv;
                if (!OUT16 && resid) v += resid[(size_t)row * N + col];
                if (OUT16) ((bf16*)Cv)[(size_t)row * N + col] = __float2bfloat16(v);
                else       ((float*)Cv)[(size_t)row * N + col] = v;
            }
        }
    }
}

// --------- tiled transpose: T[c][r] = X[r][(c/64)*cs + co + (c%64)] ---------
__global__ __launch_bounds__(256)
void transpose_v(const bf16* __restrict__ X, int ldx, int cs, int co,
                 bf16* __restrict__ T, int ldt) {
    __shared__ bf16 t[64][66];
    const int r0 = blockIdx.x * 64, c0 = blockIdx.y * 64;
#pragma unroll
    for (int s = 0; s < 16; ++s) {
        const int r = (threadIdx.x >> 6) + s * 4;
        const int c = threadIdx.x & 63;
        const int cc = c0 + c;
        t[r][c] = X[(size_t)(r0 + r) * ldx + (size_t)(cc >> 6) * cs + co + (cc & 63)];
    }
    __syncthreads();
#pragma unroll
    for (int s = 0; s < 16; ++s) {
        const int c = (threadIdx.x >> 6) + s * 4;
        const int r = threadIdx.x & 63;
        T[(size_t)(c0 + c) * ldt + r0 + r] = t[r][c];
    }
}

// --------------- fused flash attention (swapped QK^T, KV tile 64) -----------
// 64 q-rows per block, 4 waves x 16 rows, KV tiles of 64 (sa[4] keeps VGPR
// under 128 -> 4 waves/SIMD with launch_bounds(256,4)), DH=64, H=16.
// S^T = mfma(K, Q): per lane q = l15, kv = n*16 + l4*4 + reg -> energy is a
// direct f32x4 store. XCD-swizzled blockIdx: all q-blocks of one (z,split)
// K/V group land on one XCD (K/V L2-resident per XCD).
// ENERGY: write raw QK^T. NSPLIT: kv-split (fp32 partials + stats).
template<bool ENERGY, int NSPLIT>
__global__ __launch_bounds__(256, 4)
void flash_attn(const bf16* __restrict__ Qb, int ldq, int qh_str,
                const bf16* __restrict__ Kb, int ldk, int kh_str, int kh_add,
                const bf16* __restrict__ Vt, int ldvt,
                bf16* __restrict__ O, float* __restrict__ Opart,
                float* __restrict__ stats, float* __restrict__ energy,
                int SKV, int SQl, float scale) {
    __shared__ bf16 P[64][136];
    const int tid = threadIdx.x;
    const int lane = tid & 63, wid = tid >> 6;
    const int l15 = lane & 15, l4 = lane >> 4;

    // XCD-aware remap (nwg % 8 == 0 for all our launches)
    const int gx  = gridDim.x;
    const int nwg = gx * gridDim.y * gridDim.z;
    const int bid = blockIdx.x + gx * (blockIdx.y + gridDim.y * blockIdx.z);
    const int logical = (bid & 7) * (nwg >> 3) + (bid >> 3);
    const int xq = logical % gx;
    const int z  = (logical / gx) % (BB * HH);
    const int split = (NSPLIT > 1) ? (logical / (gx * BB * HH)) : 0;

    const int b = z >> 4, h = z & 15;
    const int q0 = xq * 64;
    const int kv_begin = split * (SKV / NSPLIT);
    const int kv_end   = kv_begin + SKV / NSPLIT;

    const bf16* Qp = Qb + (size_t)b * SQl * ldq + (size_t)h * qh_str;
    const bf16* Kp = Kb + (size_t)b * SKV * ldk + (size_t)h * kh_str + kh_add;
    const bf16* Vp = Vt + (size_t)h * 64 * ldvt + (size_t)b * SKV;

    // Q fragments (B-operand): row q = q0 + wid*16 + l15, k = s*32 + l4*8
    short8 aQ[2];
#pragma unroll
    for (int s = 0; s < 2; ++s)
        aQ[s] = *(const short8*)(Qp + (size_t)(q0 + wid * 16 + l15) * ldq + s * 32 + l4 * 8);

    f32x4 oacc[4] = {};
    float mI = -1e30f, lI = 0.f;      // per-lane stats for q-row = q0+wid*16+l15

    for (int kv0 = kv_begin; kv0 < kv_end; kv0 += 64) {
        // ---- S^T tile (64 kv x 16 q): sa[n][j] = S[q=l15][kv=n*16+l4*4+j] ----
        f32x4 sa[4] = {};
#pragma unroll
        for (int n = 0; n < 4; ++n) {
            const bf16* kr = Kp + (size_t)(kv0 + n * 16 + l15) * ldk + l4 * 8;
            const short8 b0 = *(const short8*)(kr);
            const short8 b1 = *(const short8*)(kr + 32);
            sa[n] = __builtin_amdgcn_mfma_f32_16x16x32_bf16(b0, aQ[0], sa[n], 0, 0, 0);
            sa[n] = __builtin_amdgcn_mfma_f32_16x16x32_bf16(b1, aQ[1], sa[n], 0, 0, 0);
        }
        // ---- raw energy write: f32x4 per lane, 64B-coalesced rows ----
        if (ENERGY) {
            float* er = energy + (size_t)z * SQl * SKV
                      + (size_t)(q0 + wid * 16 + l15) * SKV + kv0 + l4 * 4;
#pragma unroll
            for (int n = 0; n < 4; ++n)
                __builtin_nontemporal_store(sa[n], (f32x4*)(er + n * 16));
        }
        // ---- online softmax (row q = l15; 16 in-lane values + 2 shfls) ----
        float mx = fmaxf(fmaxf(fmaxf(sa[0][0], sa[0][1]), fmaxf(sa[0][2], sa[0][3])),
                         fmaxf(fmaxf(sa[1][0], sa[1][1]), fmaxf(sa[1][2], sa[1][3])));
        mx = fmaxf(mx, fmaxf(fmaxf(sa[2][0], sa[2][1]), fmaxf(sa[2][2], sa[2][3])));
        mx = fmaxf(mx, fmaxf(fmaxf(sa[3][0], sa[3][1]), fmaxf(sa[3][2], sa[3][3])));
        mx *= scale;
        mx = fmaxf(mx, __shfl_xor(mx, 16, 64));
        mx = fmaxf(mx, __shfl_xor(mx, 32, 64));
        const float nm = fmaxf(mI, mx);
        const float f = __expf(mI - nm);
        mI = nm;
        float rs = 0.f;
#pragma unroll
        for (int n = 0; n < 4; ++n)
#pragma unroll
            for (int j = 0; j < 4; ++j) {
                const float p = __expf(sa[n][j] * scale - nm);
                sa[n][j] = p;
                rs += p;
            }
        rs += __shfl_xor(rs, 16, 64);
        rs += __shfl_xor(rs, 32, 64);
        lI = lI * f + rs;
        // ---- rescale O (O-layout rows are q = l4*4+j -> fetch f via shfl) ----
#pragma unroll
        for (int j = 0; j < 4; ++j) {
            const float fj = __shfl(f, l4 * 4 + j, 64);
#pragma unroll
            for (int n = 0; n < 4; ++n) oacc[n][j] *= fj;
        }
        // ---- P^T -> LDS (packed 8B, wave-private rows) ----
#pragma unroll
        for (int n = 0; n < 4; ++n) {
            union { ushort4 v; bf16 hh[4]; } pk;
            pk.hh[0] = __float2bfloat16(sa[n][0]);
            pk.hh[1] = __float2bfloat16(sa[n][1]);
            pk.hh[2] = __float2bfloat16(sa[n][2]);
            pk.hh[3] = __float2bfloat16(sa[n][3]);
            *(ushort4*)(&P[wid * 16 + l15][n * 16 + l4 * 4]) = pk.v;
        }
        // ---- O += P @ V (2 k-slices of 32) ----
#pragma unroll
        for (int ks = 0; ks < 2; ++ks) {
            const short8 aP = *(const short8*)(&P[wid * 16 + l15][ks * 32 + l4 * 8]);
#pragma unroll
            for (int n = 0; n < 4; ++n) {
                const short8 bV = *(const short8*)(Vp + (size_t)(n * 16 + l15) * ldvt + kv0 + ks * 32 + l4 * 8);
                oacc[n] = __builtin_amdgcn_mfma_f32_16x16x32_bf16(aP, bV, oacc[n], 0, 0, 0);
            }
        }
    }
    // ---- epilogue (O rows q = l4*4+j; stats live at q = l15) ----
    if (NSPLIT == 1) {
#pragma unroll
        for (int j = 0; j < 4; ++j) {
            const float lj = __shfl(lI, l4 * 4 + j, 64);
            const float rl = 1.f / lj;
            const size_t row = (size_t)b * SQl + q0 + wid * 16 + l4 * 4 + j;
#pragma unroll
            for (int n = 0; n < 4; ++n)
                O[row * 1024 + h * 64 + n * 16 + l15] = __float2bfloat16(oacc[n][j] * rl);
        }
    } else {
        float* Op = Opart + (size_t)split * OPART_STRIDE;
#pragma unroll
        for (int j = 0; j < 4; ++j) {
            const size_t row = (size_t)b * SQl + q0 + wid * 16 + l4 * 4 + j;
#pragma unroll
            for (int n = 0; n < 4; ++n)
                Op[row * 1024 + h * 64 + n * 16 + l15] = oacc[n][j];
        }
        if (l4 == 0) {   // one writer per q-row: lane l15 holds (mI,lI) for its row
            float2* st = (float2*)stats;
            st[((size_t)split * BB * HH + z) * SQl + q0 + wid * 16 + l15] =
                make_float2(mI, lI);
        }
    }
}

// ---- merge 2 kv-split partials: O = (O1*e^{m1-m} + O2*e^{m2-m}) / l --------
__global__ __launch_bounds__(256)
void merge_o(const float* __restrict__ Opart, const float* __restrict__ stats,
             bf16* __restrict__ O) {
    const size_t row = blockIdx.x;           // 0..B*SQ
    const int b = (int)(row >> 10), q = (int)(row & 1023);
    const int col = threadIdx.x * 4;
    const int h = col >> 6;
    const int zi = b * HH + h;
    const float2* st = (const float2*)stats;
    const float2 s1 = st[(size_t)zi * SQ_ + q];
    const float2 s2 = st[((size_t)BB * HH + zi) * SQ_ + q];
    const float m = fmaxf(s1.x, s2.x);
    const float w1 = __expf(s1.x - m), w2 = __expf(s2.x - m);
    const float invl = 1.f / (s1.y * w1 + s2.y * w2);
    const float4 o1 = *(const float4*)(Opart + row * 1024 + col);
    const float4 o2 = *(const float4*)(Opart + OPART_STRIDE + row * 1024 + col);
    union { ushort4 v; bf16 hh[4]; } r;
    r.hh[0] = __float2bfloat16((o1.x * w1 + o2.x * w2) * invl);
    r.hh[1] = __float2bfloat16((o1.y * w1 + o2.y * w2) * invl);
    r.hh[2] = __float2bfloat16((o1.z * w1 + o2.z * w2) * invl);
    r.hh[3] = __float2bfloat16((o1.w * w1 + o2.w * w2) * invl);
    *(ushort4*)(O + row * 1024 + col) = r.v;
}

extern "C" void kernel_launch(void* const* d_in, const int* in_sizes, int n_in,
                              void* d_out, int out_size, void* d_ws, size_t ws_size,
                              hipStream_t stream) {
    const float* queries  = (const float*)d_in[0];
    const float* contexts = (const float*)d_in[1];
    const float* sa_ln_g  = (const float*)d_in[2];
    const float* sa_ln_b  = (const float*)d_in[3];
    const float* sa_qkv_w = (const float*)d_in[4];
    const float* sa_out_w = (const float*)d_in[5];
    const float* sa_out_b = (const float*)d_in[6];
    const float* ca_ln_g  = (const float*)d_in[7];
    const float* ca_ln_b  = (const float*)d_in[8];
    const float* ca_q_w   = (const float*)d_in[9];
    const float* ca_k_w   = (const float*)d_in[10];
    const float* ca_v_w   = (const float*)d_in[11];
    const float* ca_out_w = (const float*)d_in[12];
    const float* ca_out_b = (const float*)d_in[13];
    const float* ff_ln1_g = (const float*)d_in[14];
    const float* ff_ln1_b = (const float*)d_in[15];
    const float* ff_w1    = (const float*)d_in[16];
    const float* ff_ln2_g = (const float*)d_in[17];
    const float* ff_ln2_b = (const float*)d_in[18];
    const float* ff_w2    = (const float*)d_in[19];

    float* out    = (float*)d_out;                     // 4M floats
    float* energy = out + (size_t)BB * SQ_ * CC;       // 128M floats

    const size_t MEG = 1024 * 1024;

    // ---- ws layout (float units) ----
    float* ws = (float*)d_ws;
    bf16*  X0_16      = (bf16*)ws;                                  // 8M bf16   [0,4M)
    bf16*  o16        = (bf16*)(ws + 4 * MEG);                      // 4M bf16   [4,6M)
    bf16*  ca_out_w16 = (bf16*)(ws + 6 * MEG);                      // 1M        [6,6.5M)
    bf16*  ff_w1_16   = (bf16*)(ws + (13 * MEG) / 2);               // 2M        [6.5,7.5M)
    bf16*  ff_w2_16   = (bf16*)(ws + (15 * MEG) / 2);               // 2M        [7.5,8.5M)
    bf16*  q_ca16     = (bf16*)(ws + (17 * MEG) / 2);               // 4M        [8.5,10.5M)
    bf16*  k_ca16     = (bf16*)(ws + (21 * MEG) / 2);               // 8M        [10.5,14.5M)
    bf16*  Vt_ca      = (bf16*)(ws + (29 * MEG) / 2);               // 8M        [14.5,18.5M)
    float* E_buf      = ws + (37 * MEG) / 2;                        // 4M fp32   [18.5,22.5M)
    float* C_buf      = ws + (45 * MEG) / 2;                        // 8M fp32   [22.5,30.5M)
    bf16*  v_ca16     = (bf16*)C_buf;            // 8M bf16 (dead after transpose)
    float* Opart      = C_buf;                   // 2 x 4M fp32 (CA flash partials)
    float* stats_buf  = ws + (61 * MEG) / 2;     // 256K floats [30.5,30.75M)

    // ---- early scratch inside energy region (dead before CA flash) ----
    bf16* EZ         = (bf16*)energy;
    bf16* ctx16      = EZ;                 // 8M
    bf16* qkv16      = EZ + 8  * MEG;      // 12M
    bf16* Vt_sa      = EZ + 20 * MEG;      // 4M
    bf16* qkv_w16    = EZ + 24 * MEG;      // 3M
    bf16* sa_out_w16 = EZ + 27 * MEG;      // 1M
    bf16* ca_q_w16   = EZ + 28 * MEG;      // 1M
    bf16* ca_k_w16   = EZ + 29 * MEG;      // 1M
    bf16* ca_v_w16   = EZ + 30 * MEG;      // 1M

    const int M1 = BB * SQ_;   // 4096
    const int M2 = BB * SK_;   // 8192
    const dim3 thr(256);
    auto cvt = [&](const float* src, bf16* dst, size_t n) {
        int n8 = (int)(n / 8);
        cvt_bf16<<<(n8 + 255) / 256, thr, 0, stream>>>(src, dst, n8);
    };

    // ---- conversions ----
    cvt(sa_qkv_w, qkv_w16,    3 * MEG);
    cvt(sa_out_w, sa_out_w16, 1 * MEG);
    cvt(ca_q_w,   ca_q_w16,   1 * MEG);
    cvt(ca_k_w,   ca_k_w16,   1 * MEG);
    cvt(ca_v_w,   ca_v_w16,   1 * MEG);
    cvt(ca_out_w, ca_out_w16, 1 * MEG);
    cvt(ff_w1,    ff_w1_16,   2 * MEG);
    cvt(ff_w2,    ff_w2_16,   2 * MEG);
    cvt(contexts, ctx16,      8 * MEG);

    // ---- Self attention ----
    ln_kernel<1024><<<M1, thr, 0, stream>>>(queries, sa_ln_g, sa_ln_b, X0_16, 0);
    gemm_bt16<1><<<dim3(3072 / 128, M1 / 128), thr, 0, stream>>>(X0_16, qkv_w16, qkv16,
                                                                 M1, 3072, 1024, nullptr, nullptr);
    transpose_v<<<dim3(M1 / 64, 1024 / 64), thr, 0, stream>>>(qkv16, 3072, 192, 128, Vt_sa, M1);
    flash_attn<false, 1><<<dim3(SQ_ / 64, BB * HH, 1), thr, 0, stream>>>(
        qkv16, 3072, 192, qkv16, 3072, 192, 64, Vt_sa, M1,
        o16, nullptr, nullptr, nullptr, SQ_, SQ_, SCALE);
    gemm_bt16<0><<<dim3(1024 / 128, M1 / 128), thr, 0, stream>>>(o16, sa_out_w16, E_buf,
                                                                 M1, CC, CC, sa_out_b, queries);

    // ---- Cross attention ----
    ln_kernel<1024><<<M1, thr, 0, stream>>>(E_buf, ca_ln_g, ca_ln_b, X0_16, 0);
    gemm_bt16<1><<<dim3(1024 / 128, M1 / 128), thr, 0, stream>>>(X0_16, ca_q_w16, q_ca16,
                                                                 M1, CC, CC, nullptr, nullptr);
    gemm_bt16<1><<<dim3(1024 / 128, M2 / 128), thr, 0, stream>>>(ctx16, ca_k_w16, k_ca16,
                                                                 M2, CC, CC, nullptr, nullptr);
    gemm_bt16<1><<<dim3(1024 / 128, M2 / 128), thr, 0, stream>>>(ctx16, ca_v_w16, v_ca16,
                                                                 M2, CC, CC, nullptr, nullptr);
    transpose_v<<<dim3(M2 / 64, 1024 / 64), thr, 0, stream>>>(v_ca16, 1024, 64, 0, Vt_ca, M2);
    // CA flash: raw energy (final) + fp32 partial O (2 kv-splits). Energy-region
    // scratch (ctx16/qkv16/Vt_sa/weights) and v_ca16 are dead by this point.
    flash_attn<true, 2><<<dim3(SQ_ / 64, BB * HH, 2), thr, 0, stream>>>(
        q_ca16, 1024, 64, k_ca16, 1024, 64, 0, Vt_ca, M2,
        nullptr, Opart, stats_buf, energy, SK_, SQ_, SCALE);
    merge_o<<<M1, thr, 0, stream>>>(Opart, stats_buf, o16);
    gemm_bt16<0><<<dim3(1024 / 128, M1 / 128), thr, 0, stream>>>(o16, ca_out_w16, E_buf,
                                                                 M1, CC, CC, ca_out_b, E_buf);

    // ---- FFN ----
    ln_kernel<1024><<<M1, thr, 0, stream>>>(E_buf, ff_ln1_g, ff_ln1_b, X0_16, 1);
    gemm_bt16<0><<<dim3(2048 / 128, M1 / 128), thr, 0, stream>>>(X0_16, ff_w1_16, C_buf,
                                                                 M1, 2048, 1024, nullptr, nullptr);
    ln_kernel<2048><<<M1, thr, 0, stream>>>(C_buf, ff_ln2_g, ff_ln2_b, X0_16, 1);
    gemm_bt16<0><<<dim3(1024 / 128, M1 / 128), thr, 0, stream>>>(X0_16, ff_w2_16, out,
                                                                 M1, CC, 2048, nullptr, E_buf);
}

// Round 8
// 714.182 us; speedup vs baseline: 5.0101x; 1.0641x over previous
//
#include <hip/hip_runtime.h>
#include <hip/hip_bf16.h>
#include <math.h>

// CrossTransformer block. Round 8: 2-phase double-buffered GEMM K-loop,
// CA flash without kv-split (direct O), single cvt_all kernel, fused KV GEMM.
// B=4, SQ=1024, SK=2048, C=1024, H=16, DH=64.

namespace {
constexpr int BB  = 4;
constexpr int SQ_ = 1024;
constexpr int SK_ = 2048;
constexpr int CC  = 1024;
constexpr int HH  = 16;
constexpr float SCALE  = 0.03125f;   // 1/sqrt(1024)
constexpr float LN_EPS = 1e-5f;
}

typedef __hip_bfloat16 bf16;
typedef __attribute__((ext_vector_type(8))) short short8;
typedef __attribute__((ext_vector_type(4))) float f32x4;

__device__ __forceinline__ void gload16(const void* g, void* l) {
    __builtin_amdgcn_global_load_lds((const __attribute__((address_space(1))) unsigned int*)g,
                                     (__attribute__((address_space(3))) unsigned int*)l,
                                     16, 0, 0);
}

// ---------------- all fp32 -> bf16 conversions in one kernel ----------------
#define MAXJOBS 10
struct CvtJobs {
    const float* src[MAXJOBS];
    bf16*        dst[MAXJOBS];
    int          end[MAXJOBS];   // cumulative n8 (elements/8)
    int          njobs;
};

__global__ __launch_bounds__(256)
void cvt_all(CvtJobs J) {
    const int i = blockIdx.x * 256 + threadIdx.x;
    if (i >= J.end[J.njobs - 1]) return;
    int j = 0;
    while (i >= J.end[j]) ++j;
    const int base = j ? J.end[j - 1] : 0;
    const int k = i - base;
    const float4 a = ((const float4*)J.src[j])[2 * k];
    const float4 b = ((const float4*)J.src[j])[2 * k + 1];
    union { ushort4 v; bf16 h[4]; } lo, hi;
    lo.h[0] = __float2bfloat16(a.x); lo.h[1] = __float2bfloat16(a.y);
    lo.h[2] = __float2bfloat16(a.z); lo.h[3] = __float2bfloat16(a.w);
    hi.h[0] = __float2bfloat16(b.x); hi.h[1] = __float2bfloat16(b.y);
    hi.h[2] = __float2bfloat16(b.z); hi.h[3] = __float2bfloat16(b.w);
    ((ushort4*)J.dst[j])[2 * k]     = lo.v;
    ((ushort4*)J.dst[j])[2 * k + 1] = hi.v;
}

// ---------------- LayerNorm (+optional SiLU), bf16 out ----------------
template<int NCOLS>
__global__ __launch_bounds__(256)
void ln_kernel(const float* __restrict__ x, const float* __restrict__ g,
               const float* __restrict__ b, bf16* __restrict__ out, int do_silu) {
    constexpr int PER = NCOLS / 256;
    const size_t row = blockIdx.x;
    const float* xr = x + row * NCOLS;
    float vals[PER];
    float s = 0.f, ss = 0.f;
#pragma unroll
    for (int i = 0; i < PER; ++i) {
        vals[i] = xr[threadIdx.x + i * 256];
        s += vals[i];
        ss += vals[i] * vals[i];
    }
    for (int off = 32; off > 0; off >>= 1) {
        s  += __shfl_down(s, off, 64);
        ss += __shfl_down(ss, off, 64);
    }
    __shared__ float red[10];
    const int wid = threadIdx.x >> 6, lane = threadIdx.x & 63;
    if (lane == 0) { red[wid] = s; red[wid + 4] = ss; }
    __syncthreads();
    if (threadIdx.x == 0) {
        const float ts  = red[0] + red[1] + red[2] + red[3];
        const float tss = red[4] + red[5] + red[6] + red[7];
        const float mu  = ts / NCOLS;
        const float var = tss / NCOLS - mu * mu;
        red[8] = mu;
        red[9] = rsqrtf(var + LN_EPS);
    }
    __syncthreads();
    const float mu = red[8], rstd = red[9];
    bf16* outr = out + row * NCOLS;
#pragma unroll
    for (int i = 0; i < PER; ++i) {
        const int c = threadIdx.x + i * 256;
        float y = (vals[i] - mu) * rstd * g[c] + b[c];
        if (do_silu) y = y / (1.f + __expf(-y));
        outr[c] = __float2bfloat16(y);
    }
}

// ------------- bf16 MFMA GEMM: C[M,N] = A[M,K] @ B[N,K]^T (+bias)(+resid) ---
// 2-phase double-buffered K-loop: stage tile t+1 BEFORE computing tile t,
// single __syncthreads per iteration (vmcnt(0) drain doubles as "next ready").
// XCD-swizzled blockIdx (all grids %8==0).
template<int OUT16>
__global__ __launch_bounds__(256)
void gemm_bt16(const bf16* __restrict__ A, const bf16* __restrict__ B,
               void* __restrict__ Cv, int M, int N, int K,
               const float* __restrict__ bias, const float* __restrict__ resid) {
    __shared__ bf16 As[2][128 * 32];
    __shared__ bf16 Bs[2][128 * 32];
    const int tid  = threadIdx.x;
    const int lane = tid & 63;
    const int w    = tid >> 6;
    const int wr = w >> 1, wc = w & 1;

    const int nwg = gridDim.x * gridDim.y;
    const int bid = blockIdx.x + gridDim.x * blockIdx.y;
    const int logical = (bid & 7) * (nwg >> 3) + (bid >> 3);
    const int m0 = (logical / gridDim.x) * 128;
    const int n0 = (logical % gridDim.x) * 128;

    f32x4 acc[4][4] = {};

    const int srow = tid >> 2;
    const int scol = (tid & 3) * 8;
    const bf16* Ap  = A + (size_t)(m0 + srow) * K + scol;
    const bf16* Ap2 = Ap + (size_t)64 * K;
    const bf16* Bp  = B + (size_t)(n0 + srow) * K + scol;
    const bf16* Bp2 = Bp + (size_t)64 * K;

    const int arow = wr * 64 + (lane & 15);
    const int brow = wc * 64 + (lane & 15);
    const int kgrp = (lane >> 4) * 16;

    auto stage = [&](int buf, int k0) {
        char* AsB = (char*)As[buf] + w * 1024;
        char* BsB = (char*)Bs[buf] + w * 1024;
        gload16(Ap  + k0, AsB);
        gload16(Ap2 + k0, AsB + 4096);
        gload16(Bp  + k0, BsB);
        gload16(Bp2 + k0, BsB + 4096);
    };

    const int nt = K >> 5;
    stage(0, 0);
    __syncthreads();
    for (int t = 0; t < nt; ++t) {
        if (t + 1 < nt) stage((t + 1) & 1, (t + 1) << 5);
        const char* Ab = (const char*)As[t & 1];
        const char* Bb = (const char*)Bs[t & 1];
        short8 aF[4], bF[4];
#pragma unroll
        for (int m = 0; m < 4; ++m)
            aF[m] = *(const short8*)(Ab + ((arow + m * 16) * 64 + kgrp));
#pragma unroll
        for (int n = 0; n < 4; ++n)
            bF[n] = *(const short8*)(Bb + ((brow + n * 16) * 64 + kgrp));
#pragma unroll
        for (int m = 0; m < 4; ++m)
#pragma unroll
            for (int n = 0; n < 4; ++n)
                acc[m][n] = __builtin_amdgcn_mfma_f32_16x16x32_bf16(aF[m], bF[n], acc[m][n], 0, 0, 0);
        __syncthreads();   // drains vmcnt(0): tile t+1 landed; all reads of tile t done
    }

    const int crow0 = m0 + wr * 64 + (lane >> 4) * 4;
    const int ccol0 = n0 + wc * 64 + (lane & 15);
#pragma unroll
    for (int m = 0; m < 4; ++m) {
#pragma unroll
        for (int n = 0; n < 4; ++n) {
            const int col = ccol0 + n * 16;
            const float bv = (!OUT16 && bias) ? bias[col] : 0.f;
#pragma unroll
            for (int j = 0; j < 4; ++j) {
                const int row = crow0 + m * 16 + j;
                float v = acc[m][n][j] + bv;
                if (!OUT16 && resid) v += resid[(size_t)row * N + col];
                if (OUT16) ((bf16*)Cv)[(size_t)row * N + col] = __float2bfloat16(v);
                else       ((float*)Cv)[(size_t)row * N + col] = v;
            }
        }
    }
}

// --------- tiled transpose: T[c][r] = X[r][(c/64)*cs + co + (c%64)] ---------
__global__ __launch_bounds__(256)
void transpose_v(const bf16* __restrict__ X, int ldx, int cs, int co,
                 bf16* __restrict__ T, int ldt) {
    __shared__ bf16 t[64][66];
    const int r0 = blockIdx.x * 64, c0 = blockIdx.y * 64;
#pragma unroll
    for (int s = 0; s < 16; ++s) {
        const int r = (threadIdx.x >> 6) + s * 4;
        const int c = threadIdx.x & 63;
        const int cc = c0 + c;
        t[r][c] = X[(size_t)(r0 + r) * ldx + (size_t)(cc >> 6) * cs + co + (cc & 63)];
    }
    __syncthreads();
#pragma unroll
    for (int s = 0; s < 16; ++s) {
        const int c = (threadIdx.x >> 6) + s * 4;
        const int r = threadIdx.x & 63;
        T[(size_t)(c0 + c) * ldt + r0 + r] = t[r][c];
    }
}

// --------------- fused flash attention (swapped QK^T, KV tile 64) -----------
// 64 q-rows per block, 4 waves x 16 rows, KV tiles of 64, DH=64, H=16.
// S^T = mfma(K, Q): per lane q = l15, kv = n*16 + l4*4 + reg -> energy is a
// direct f32x4 NT store. XCD-swizzled blockIdx keeps one (z) K/V group's
// q-blocks on one XCD (K/V L2-resident).
template<bool ENERGY>
__global__ __launch_bounds__(256, 4)
void flash_attn(const bf16* __restrict__ Qb, int ldq, int qh_str,
                const bf16* __restrict__ Kb, int ldk, int kh_str, int kh_add,
                const bf16* __restrict__ Vt, int ldvt,
                bf16* __restrict__ O, float* __restrict__ energy,
                int SKV, int SQl, float scale) {
    __shared__ bf16 P[64][136];
    const int tid = threadIdx.x;
    const int lane = tid & 63, wid = tid >> 6;
    const int l15 = lane & 15, l4 = lane >> 4;

    // XCD-aware remap (nwg % 8 == 0)
    const int gx  = gridDim.x;
    const int nwg = gx * gridDim.y;
    const int bid = blockIdx.x + gx * blockIdx.y;
    const int logical = (bid & 7) * (nwg >> 3) + (bid >> 3);
    const int xq = logical % gx;
    const int z  = logical / gx;

    const int b = z >> 4, h = z & 15;
    const int q0 = xq * 64;

    const bf16* Qp = Qb + (size_t)b * SQl * ldq + (size_t)h * qh_str;
    const bf16* Kp = Kb + (size_t)b * SKV * ldk + (size_t)h * kh_str + kh_add;
    const bf16* Vp = Vt + (size_t)h * 64 * ldvt + (size_t)b * SKV;

    // Q fragments (B-operand): row q = q0 + wid*16 + l15, k = s*32 + l4*8
    short8 aQ[2];
#pragma unroll
    for (int s = 0; s < 2; ++s)
        aQ[s] = *(const short8*)(Qp + (size_t)(q0 + wid * 16 + l15) * ldq + s * 32 + l4 * 8);

    f32x4 oacc[4] = {};
    float mI = -1e30f, lI = 0.f;      // per-lane stats for q-row = q0+wid*16+l15

    for (int kv0 = 0; kv0 < SKV; kv0 += 64) {
        // ---- S^T tile (64 kv x 16 q): sa[n][j] = S[q=l15][kv=n*16+l4*4+j] ----
        f32x4 sa[4] = {};
#pragma unroll
        for (int n = 0; n < 4; ++n) {
            const bf16* kr = Kp + (size_t)(kv0 + n * 16 + l15) * ldk + l4 * 8;
            const short8 b0 = *(const short8*)(kr);
            const short8 b1 = *(const short8*)(kr + 32);
            sa[n] = __builtin_amdgcn_mfma_f32_16x16x32_bf16(b0, aQ[0], sa[n], 0, 0, 0);
            sa[n] = __builtin_amdgcn_mfma_f32_16x16x32_bf16(b1, aQ[1], sa[n], 0, 0, 0);
        }
        // ---- raw energy write: f32x4 per lane, 64B-coalesced rows ----
        if (ENERGY) {
            float* er = energy + (size_t)z * SQl * SKV
                      + (size_t)(q0 + wid * 16 + l15) * SKV + kv0 + l4 * 4;
#pragma unroll
            for (int n = 0; n < 4; ++n)
                __builtin_nontemporal_store(sa[n], (f32x4*)(er + n * 16));
        }
        // ---- online softmax (row q = l15; 16 in-lane values + 2 shfls) ----
        float mx = fmaxf(fmaxf(fmaxf(sa[0][0], sa[0][1]), fmaxf(sa[0][2], sa[0][3])),
                         fmaxf(fmaxf(sa[1][0], sa[1][1]), fmaxf(sa[1][2], sa[1][3])));
        mx = fmaxf(mx, fmaxf(fmaxf(sa[2][0], sa[2][1]), fmaxf(sa[2][2], sa[2][3])));
        mx = fmaxf(mx, fmaxf(fmaxf(sa[3][0], sa[3][1]), fmaxf(sa[3][2], sa[3][3])));
        mx *= scale;
        mx = fmaxf(mx, __shfl_xor(mx, 16, 64));
        mx = fmaxf(mx, __shfl_xor(mx, 32, 64));
        const float nm = fmaxf(mI, mx);
        const float f = __expf(mI - nm);
        mI = nm;
        float rs = 0.f;
#pragma unroll
        for (int n = 0; n < 4; ++n)
#pragma unroll
            for (int j = 0; j < 4; ++j) {
                const float p = __expf(sa[n][j] * scale - nm);
                sa[n][j] = p;
                rs += p;
            }
        rs += __shfl_xor(rs, 16, 64);
        rs += __shfl_xor(rs, 32, 64);
        lI = lI * f + rs;
        // ---- rescale O (O-layout rows are q = l4*4+j -> fetch f via shfl) ----
#pragma unroll
        for (int j = 0; j < 4; ++j) {
            const float fj = __shfl(f, l4 * 4 + j, 64);
#pragma unroll
            for (int n = 0; n < 4; ++n) oacc[n][j] *= fj;
        }
        // ---- P^T -> LDS (packed 8B, wave-private rows) ----
#pragma unroll
        for (int n = 0; n < 4; ++n) {
            union { ushort4 v; bf16 hh[4]; } pk;
            pk.hh[0] = __float2bfloat16(sa[n][0]);
            pk.hh[1] = __float2bfloat16(sa[n][1]);
            pk.hh[2] = __float2bfloat16(sa[n][2]);
            pk.hh[3] = __float2bfloat16(sa[n][3]);
            *(ushort4*)(&P[wid * 16 + l15][n * 16 + l4 * 4]) = pk.v;
        }
        // ---- O += P @ V (2 k-slices of 32) ----
#pragma unroll
        for (int ks = 0; ks < 2; ++ks) {
            const short8 aP = *(const short8*)(&P[wid * 16 + l15][ks * 32 + l4 * 8]);
#pragma unroll
            for (int n = 0; n < 4; ++n) {
                const short8 bV = *(const short8*)(Vp + (size_t)(n * 16 + l15) * ldvt + kv0 + ks * 32 + l4 * 8);
                oacc[n] = __builtin_amdgcn_mfma_f32_16x16x32_bf16(aP, bV, oacc[n], 0, 0, 0);
            }
        }
    }
    // ---- epilogue (O rows q = l4*4+j; stats live at q = l15) ----
#pragma unroll
    for (int j = 0; j < 4; ++j) {
        const float lj = __shfl(lI, l4 * 4 + j, 64);
        const float rl = 1.f / lj;
        const size_t row = (size_t)b * SQl + q0 + wid * 16 + l4 * 4 + j;
#pragma unroll
        for (int n = 0; n < 4; ++n)
            O[row * 1024 + h * 64 + n * 16 + l15] = __float2bfloat16(oacc[n][j] * rl);
    }
}

extern "C" void kernel_launch(void* const* d_in, const int* in_sizes, int n_in,
                              void* d_out, int out_size, void* d_ws, size_t ws_size,
                              hipStream_t stream) {
    const float* queries  = (const float*)d_in[0];
    const float* contexts = (const float*)d_in[1];
    const float* sa_ln_g  = (const float*)d_in[2];
    const float* sa_ln_b  = (const float*)d_in[3];
    const float* sa_qkv_w = (const float*)d_in[4];
    const float* sa_out_w = (const float*)d_in[5];
    const float* sa_out_b = (const float*)d_in[6];
    const float* ca_ln_g  = (const float*)d_in[7];
    const float* ca_ln_b  = (const float*)d_in[8];
    const float* ca_q_w   = (const float*)d_in[9];
    const float* ca_k_w   = (const float*)d_in[10];
    const float* ca_v_w   = (const float*)d_in[11];
    const float* ca_out_w = (const float*)d_in[12];
    const float* ca_out_b = (const float*)d_in[13];
    const float* ff_ln1_g = (const float*)d_in[14];
    const float* ff_ln1_b = (const float*)d_in[15];
    const float* ff_w1    = (const float*)d_in[16];
    const float* ff_ln2_g = (const float*)d_in[17];
    const float* ff_ln2_b = (const float*)d_in[18];
    const float* ff_w2    = (const float*)d_in[19];

    float* out    = (float*)d_out;                     // 4M floats
    float* energy = out + (size_t)BB * SQ_ * CC;       // 128M floats

    const size_t MEG = 1024 * 1024;

    // ---- ws layout (float units) ----
    float* ws = (float*)d_ws;
    bf16*  X0_16      = (bf16*)ws;                                  // 8M bf16   [0,4M)
    bf16*  o16        = (bf16*)(ws + 4 * MEG);                      // 4M bf16   [4,6M)
    bf16*  ca_out_w16 = (bf16*)(ws + 6 * MEG);                      // 1M        [6,6.5M)
    bf16*  ff_w1_16   = (bf16*)(ws + (13 * MEG) / 2);               // 2M        [6.5,7.5M)
    bf16*  ff_w2_16   = (bf16*)(ws + (15 * MEG) / 2);               // 2M        [7.5,8.5M)
    bf16*  q_ca16     = (bf16*)(ws + (17 * MEG) / 2);               // 4M        [8.5,10.5M)
    bf16*  KV_ca      = (bf16*)(ws + (21 * MEG) / 2);               // 16M       [10.5,18.5M)
    bf16*  Vt_ca      = (bf16*)(ws + (37 * MEG) / 2);               // 8M        [18.5,22.5M)
    float* E_buf      = ws + (45 * MEG) / 2;                        // 4M fp32   [22.5,26.5M)
    float* C_buf      = ws + (53 * MEG) / 2;                        // 8M fp32   [26.5,34.5M)

    // ---- early scratch inside energy region (dead before CA flash) ----
    bf16* EZ         = (bf16*)energy;
    bf16* ctx16      = EZ;                 // 8M
    bf16* qkv16      = EZ + 8  * MEG;      // 12M
    bf16* Vt_sa      = EZ + 20 * MEG;      // 4M
    bf16* qkv_w16    = EZ + 24 * MEG;      // 3M
    bf16* sa_out_w16 = EZ + 27 * MEG;      // 1M
    bf16* ca_q_w16   = EZ + 28 * MEG;      // 1M
    bf16* ca_k_w16   = EZ + 29 * MEG;      // 1M (ca_k|ca_v adjacent for fused KV GEMM)
    bf16* ca_v_w16   = EZ + 30 * MEG;      // 1M

    const int M1 = BB * SQ_;   // 4096
    const int M2 = BB * SK_;   // 8192
    const dim3 thr(256);

    // ---- all conversions in one dispatch ----
    {
        CvtJobs J;
        const float* srcs[9] = { sa_qkv_w, sa_out_w, ca_q_w, ca_k_w, ca_v_w,
                                 ca_out_w, ff_w1, ff_w2, contexts };
        bf16* dsts[9] = { qkv_w16, sa_out_w16, ca_q_w16, ca_k_w16, ca_v_w16,
                          ca_out_w16, ff_w1_16, ff_w2_16, ctx16 };
        const size_t ns[9] = { 3 * MEG, 1 * MEG, 1 * MEG, 1 * MEG, 1 * MEG,
                               1 * MEG, 2 * MEG, 2 * MEG, 8 * MEG };
        int acc_n8 = 0;
        for (int j = 0; j < 9; ++j) {
            J.src[j] = srcs[j];
            J.dst[j] = dsts[j];
            acc_n8 += (int)(ns[j] / 8);
            J.end[j] = acc_n8;
        }
        J.njobs = 9;
        cvt_all<<<(acc_n8 + 255) / 256, thr, 0, stream>>>(J);
    }

    // ---- Self attention ----
    ln_kernel<1024><<<M1, thr, 0, stream>>>(queries, sa_ln_g, sa_ln_b, X0_16, 0);
    gemm_bt16<1><<<dim3(3072 / 128, M1 / 128), thr, 0, stream>>>(X0_16, qkv_w16, qkv16,
                                                                 M1, 3072, 1024, nullptr, nullptr);
    transpose_v<<<dim3(M1 / 64, 1024 / 64), thr, 0, stream>>>(qkv16, 3072, 192, 128, Vt_sa, M1);
    flash_attn<false><<<dim3(SQ_ / 64, BB * HH), thr, 0, stream>>>(
        qkv16, 3072, 192, qkv16, 3072, 192, 64, Vt_sa, M1,
        o16, nullptr, SQ_, SQ_, SCALE);
    gemm_bt16<0><<<dim3(1024 / 128, M1 / 128), thr, 0, stream>>>(o16, sa_out_w16, E_buf,
                                                                 M1, CC, CC, sa_out_b, queries);

    // ---- Cross attention ----
    ln_kernel<1024><<<M1, thr, 0, stream>>>(E_buf, ca_ln_g, ca_ln_b, X0_16, 0);
    gemm_bt16<1><<<dim3(1024 / 128, M1 / 128), thr, 0, stream>>>(X0_16, ca_q_w16, q_ca16,
                                                                 M1, CC, CC, nullptr, nullptr);
    // fused K|V projection: B = [ca_k_w16; ca_v_w16] (adjacent), N=2048
    gemm_bt16<1><<<dim3(2048 / 128, M2 / 128), thr, 0, stream>>>(ctx16, ca_k_w16, KV_ca,
                                                                 M2, 2048, 1024, nullptr, nullptr);
    // V columns (1024..2047) of KV_ca -> transposed Vt_ca[h*64+d][b*SK+kv]
    transpose_v<<<dim3(M2 / 64, 1024 / 64), thr, 0, stream>>>(KV_ca, 2048, 64, 1024, Vt_ca, M2);
    // CA flash: raw energy (final output) + direct bf16 O. Energy-region
    // scratch (ctx16/qkv16/Vt_sa/weights) is dead by this point.
    flash_attn<true><<<dim3(SQ_ / 64, BB * HH), thr, 0, stream>>>(
        q_ca16, 1024, 64, KV_ca, 2048, 64, 0, Vt_ca, M2,
        o16, energy, SK_, SQ_, SCALE);
    gemm_bt16<0><<<dim3(1024 / 128, M1 / 128), thr, 0, stream>>>(o16, ca_out_w16, E_buf,
                                                                 M1, CC, CC, ca_out_b, E_buf);

    // ---- FFN ----
    ln_kernel<1024><<<M1, thr, 0, stream>>>(E_buf, ff_ln1_g, ff_ln1_b, X0_16, 1);
    gemm_bt16<0><<<dim3(2048 / 128, M1 / 128), thr, 0, stream>>>(X0_16, ff_w1_16, C_buf,
                                                                 M1, 2048, 1024, nullptr, nullptr);
    ln_kernel<2048><<<M1, thr, 0, stream>>>(C_buf, ff_ln2_g, ff_ln2_b, X0_16, 1);
    gemm_bt16<0><<<dim3(1024 / 128, M1 / 128), thr, 0, stream>>>(X0_16, ff_w2_16, out,
                                                                 M1, CC, 2048, nullptr, E_buf);
}

// Round 9
// 666.574 us; speedup vs baseline: 5.3680x; 1.0714x over previous
//
#include <hip/hip_runtime.h>
#include <hip/hip_bf16.h>
#include <math.h>

// CrossTransformer block. Round 9: BM=64 GEMM variant for N=1024 GEMMs
// (2 blocks/CU to hide barrier drain), vectorized LN loads.
// B=4, SQ=1024, SK=2048, C=1024, H=16, DH=64.

namespace {
constexpr int BB  = 4;
constexpr int SQ_ = 1024;
constexpr int SK_ = 2048;
constexpr int CC  = 1024;
constexpr int HH  = 16;
constexpr float SCALE  = 0.03125f;   // 1/sqrt(1024)
constexpr float LN_EPS = 1e-5f;
}

typedef __hip_bfloat16 bf16;
typedef __attribute__((ext_vector_type(8))) short short8;
typedef __attribute__((ext_vector_type(4))) float f32x4;

__device__ __forceinline__ void gload16(const void* g, void* l) {
    __builtin_amdgcn_global_load_lds((const __attribute__((address_space(1))) unsigned int*)g,
                                     (__attribute__((address_space(3))) unsigned int*)l,
                                     16, 0, 0);
}

// ---------------- all fp32 -> bf16 conversions in one kernel ----------------
#define MAXJOBS 10
struct CvtJobs {
    const float* src[MAXJOBS];
    bf16*        dst[MAXJOBS];
    int          end[MAXJOBS];   // cumulative n8 (elements/8)
    int          njobs;
};

__global__ __launch_bounds__(256)
void cvt_all(CvtJobs J) {
    const int i = blockIdx.x * 256 + threadIdx.x;
    if (i >= J.end[J.njobs - 1]) return;
    int j = 0;
    while (i >= J.end[j]) ++j;
    const int base = j ? J.end[j - 1] : 0;
    const int k = i - base;
    const float4 a = ((const float4*)J.src[j])[2 * k];
    const float4 b = ((const float4*)J.src[j])[2 * k + 1];
    union { ushort4 v; bf16 h[4]; } lo, hi;
    lo.h[0] = __float2bfloat16(a.x); lo.h[1] = __float2bfloat16(a.y);
    lo.h[2] = __float2bfloat16(a.z); lo.h[3] = __float2bfloat16(a.w);
    hi.h[0] = __float2bfloat16(b.x); hi.h[1] = __float2bfloat16(b.y);
    hi.h[2] = __float2bfloat16(b.z); hi.h[3] = __float2bfloat16(b.w);
    ((ushort4*)J.dst[j])[2 * k]     = lo.v;
    ((ushort4*)J.dst[j])[2 * k + 1] = hi.v;
}

// ---------------- LayerNorm (+optional SiLU), bf16 out, float4 loads --------
template<int NCOLS>
__global__ __launch_bounds__(256)
void ln_kernel(const float* __restrict__ x, const float* __restrict__ g,
               const float* __restrict__ b, bf16* __restrict__ out, int do_silu) {
    constexpr int PER = NCOLS / 1024;   // float4 chunks per thread
    const size_t row = blockIdx.x;
    const float4* xr = (const float4*)(x + row * NCOLS);
    float4 vals[PER];
    float s = 0.f, ss = 0.f;
#pragma unroll
    for (int i = 0; i < PER; ++i) {
        vals[i] = xr[threadIdx.x + i * 256];
        s  += vals[i].x + vals[i].y + vals[i].z + vals[i].w;
        ss += vals[i].x * vals[i].x + vals[i].y * vals[i].y
            + vals[i].z * vals[i].z + vals[i].w * vals[i].w;
    }
    for (int off = 32; off > 0; off >>= 1) {
        s  += __shfl_down(s, off, 64);
        ss += __shfl_down(ss, off, 64);
    }
    __shared__ float red[10];
    const int wid = threadIdx.x >> 6, lane = threadIdx.x & 63;
    if (lane == 0) { red[wid] = s; red[wid + 4] = ss; }
    __syncthreads();
    if (threadIdx.x == 0) {
        const float ts  = red[0] + red[1] + red[2] + red[3];
        const float tss = red[4] + red[5] + red[6] + red[7];
        const float mu  = ts / NCOLS;
        const float var = tss / NCOLS - mu * mu;
        red[8] = mu;
        red[9] = rsqrtf(var + LN_EPS);
    }
    __syncthreads();
    const float mu = red[8], rstd = red[9];
    bf16* outr = out + row * NCOLS;
#pragma unroll
    for (int i = 0; i < PER; ++i) {
        const int c = (threadIdx.x + i * 256) * 4;
        const float4 gg = *(const float4*)(g + c);
        const float4 bb = *(const float4*)(b + c);
        float y0 = (vals[i].x - mu) * rstd * gg.x + bb.x;
        float y1 = (vals[i].y - mu) * rstd * gg.y + bb.y;
        float y2 = (vals[i].z - mu) * rstd * gg.z + bb.z;
        float y3 = (vals[i].w - mu) * rstd * gg.w + bb.w;
        if (do_silu) {
            y0 = y0 / (1.f + __expf(-y0));
            y1 = y1 / (1.f + __expf(-y1));
            y2 = y2 / (1.f + __expf(-y2));
            y3 = y3 / (1.f + __expf(-y3));
        }
        union { ushort4 v; bf16 h[4]; } pk;
        pk.h[0] = __float2bfloat16(y0); pk.h[1] = __float2bfloat16(y1);
        pk.h[2] = __float2bfloat16(y2); pk.h[3] = __float2bfloat16(y3);
        *(ushort4*)(outr + c) = pk.v;
    }
}

// ------------- bf16 MFMA GEMM: C[M,N] = A[M,K] @ B[N,K]^T (+bias)(+resid) ---
// 2-phase double-buffered K-loop. BMT = 128 (2x2 waves, 64x64 each) or
// 64 (1x4 waves, 64x32 each -> doubled grid, 2 blocks/CU for latency hiding).
// XCD-swizzled blockIdx (all grids %8==0).
template<int OUT16, int BMT>
__global__ __launch_bounds__(256)
void gemm_bt16(const bf16* __restrict__ A, const bf16* __restrict__ B,
               void* __restrict__ Cv, int M, int N, int K,
               const float* __restrict__ bias, const float* __restrict__ resid) {
    constexpr int WC = (BMT == 128) ? 2 : 4;   // waves in N dir
    constexpr int NF = (BMT == 128) ? 4 : 2;   // 16-col fragments per wave
    __shared__ bf16 As[2][BMT * 32];
    __shared__ bf16 Bs[2][128 * 32];
    const int tid  = threadIdx.x;
    const int lane = tid & 63;
    const int w    = tid >> 6;
    const int wr = w / WC, wc = w % WC;

    const int nwg = gridDim.x * gridDim.y;
    const int bid = blockIdx.x + gridDim.x * blockIdx.y;
    const int logical = (bid & 7) * (nwg >> 3) + (bid >> 3);
    const int m0 = (logical / gridDim.x) * BMT;
    const int n0 = (logical % gridDim.x) * 128;

    f32x4 acc[4][NF] = {};

    const int srow = tid >> 2;
    const int scol = (tid & 3) * 8;
    const bf16* Ap  = A + (size_t)(m0 + srow) * K + scol;
    const bf16* Ap2 = Ap + (size_t)64 * K;      // used only when BMT==128
    const bf16* Bp  = B + (size_t)(n0 + srow) * K + scol;
    const bf16* Bp2 = Bp + (size_t)64 * K;

    const int arow = wr * 64 + (lane & 15);
    const int brow = wc * (NF * 16) + (lane & 15);
    const int kgrp = (lane >> 4) * 16;

    auto stage = [&](int buf, int k0) {
        char* AsB = (char*)As[buf] + w * 1024;
        char* BsB = (char*)Bs[buf] + w * 1024;
        gload16(Ap  + k0, AsB);
        if (BMT == 128) gload16(Ap2 + k0, AsB + 4096);
        gload16(Bp  + k0, BsB);
        gload16(Bp2 + k0, BsB + 4096);
    };

    const int nt = K >> 5;
    stage(0, 0);
    __syncthreads();
    for (int t = 0; t < nt; ++t) {
        if (t + 1 < nt) stage((t + 1) & 1, (t + 1) << 5);
        const char* Ab = (const char*)As[t & 1];
        const char* Bb = (const char*)Bs[t & 1];
        short8 aF[4], bF[NF];
#pragma unroll
        for (int m = 0; m < 4; ++m)
            aF[m] = *(const short8*)(Ab + ((arow + m * 16) * 64 + kgrp));
#pragma unroll
        for (int n = 0; n < NF; ++n)
            bF[n] = *(const short8*)(Bb + ((brow + n * 16) * 64 + kgrp));
#pragma unroll
        for (int m = 0; m < 4; ++m)
#pragma unroll
            for (int n = 0; n < NF; ++n)
                acc[m][n] = __builtin_amdgcn_mfma_f32_16x16x32_bf16(aF[m], bF[n], acc[m][n], 0, 0, 0);
        __syncthreads();   // drains vmcnt(0): tile t+1 landed; reads of tile t done
    }

    const int crow0 = m0 + wr * 64 + (lane >> 4) * 4;
    const int ccol0 = n0 + wc * (NF * 16) + (lane & 15);
#pragma unroll
    for (int m = 0; m < 4; ++m) {
#pragma unroll
        for (int n = 0; n < NF; ++n) {
            const int col = ccol0 + n * 16;
            const float bv = (!OUT16 && bias) ? bias[col] : 0.f;
#pragma unroll
            for (int j = 0; j < 4; ++j) {
                const int row = crow0 + m * 16 + j;
                float v = acc[m][n][j] + bv;
                if (!OUT16 && resid) v += resid[(size_t)row * N + col];
                if (OUT16) ((bf16*)Cv)[(size_t)row * N + col] = __float2bfloat16(v);
                else       ((float*)Cv)[(size_t)row * N + col] = v;
            }
        }
    }
}

// --------- tiled transpose: T[c][r] = X[r][(c/64)*cs + co + (c%64)] ---------
__global__ __launch_bounds__(256)
void transpose_v(const bf16* __restrict__ X, int ldx, int cs, int co,
                 bf16* __restrict__ T, int ldt) {
    __shared__ bf16 t[64][66];
    const int r0 = blockIdx.x * 64, c0 = blockIdx.y * 64;
#pragma unroll
    for (int s = 0; s < 16; ++s) {
        const int r = (threadIdx.x >> 6) + s * 4;
        const int c = threadIdx.x & 63;
        const int cc = c0 + c;
        t[r][c] = X[(size_t)(r0 + r) * ldx + (size_t)(cc >> 6) * cs + co + (cc & 63)];
    }
    __syncthreads();
#pragma unroll
    for (int s = 0; s < 16; ++s) {
        const int c = (threadIdx.x >> 6) + s * 4;
        const int r = threadIdx.x & 63;
        T[(size_t)(c0 + c) * ldt + r0 + r] = t[r][c];
    }
}

// --------------- fused flash attention (swapped QK^T, KV tile 64) -----------
template<bool ENERGY>
__global__ __launch_bounds__(256, 4)
void flash_attn(const bf16* __restrict__ Qb, int ldq, int qh_str,
                const bf16* __restrict__ Kb, int ldk, int kh_str, int kh_add,
                const bf16* __restrict__ Vt, int ldvt,
                bf16* __restrict__ O, float* __restrict__ energy,
                int SKV, int SQl, float scale) {
    __shared__ bf16 P[64][136];
    const int tid = threadIdx.x;
    const int lane = tid & 63, wid = tid >> 6;
    const int l15 = lane & 15, l4 = lane >> 4;

    // XCD-aware remap (nwg % 8 == 0)
    const int gx  = gridDim.x;
    const int nwg = gx * gridDim.y;
    const int bid = blockIdx.x + gx * blockIdx.y;
    const int logical = (bid & 7) * (nwg >> 3) + (bid >> 3);
    const int xq = logical % gx;
    const int z  = logical / gx;

    const int b = z >> 4, h = z & 15;
    const int q0 = xq * 64;

    const bf16* Qp = Qb + (size_t)b * SQl * ldq + (size_t)h * qh_str;
    const bf16* Kp = Kb + (size_t)b * SKV * ldk + (size_t)h * kh_str + kh_add;
    const bf16* Vp = Vt + (size_t)h * 64 * ldvt + (size_t)b * SKV;

    short8 aQ[2];
#pragma unroll
    for (int s = 0; s < 2; ++s)
        aQ[s] = *(const short8*)(Qp + (size_t)(q0 + wid * 16 + l15) * ldq + s * 32 + l4 * 8);

    f32x4 oacc[4] = {};
    float mI = -1e30f, lI = 0.f;

    for (int kv0 = 0; kv0 < SKV; kv0 += 64) {
        f32x4 sa[4] = {};
#pragma unroll
        for (int n = 0; n < 4; ++n) {
            const bf16* kr = Kp + (size_t)(kv0 + n * 16 + l15) * ldk + l4 * 8;
            const short8 b0 = *(const short8*)(kr);
            const short8 b1 = *(const short8*)(kr + 32);
            sa[n] = __builtin_amdgcn_mfma_f32_16x16x32_bf16(b0, aQ[0], sa[n], 0, 0, 0);
            sa[n] = __builtin_amdgcn_mfma_f32_16x16x32_bf16(b1, aQ[1], sa[n], 0, 0, 0);
        }
        if (ENERGY) {
            float* er = energy + (size_t)z * SQl * SKV
                      + (size_t)(q0 + wid * 16 + l15) * SKV + kv0 + l4 * 4;
#pragma unroll
            for (int n = 0; n < 4; ++n)
                __builtin_nontemporal_store(sa[n], (f32x4*)(er + n * 16));
        }
        float mx = fmaxf(fmaxf(fmaxf(sa[0][0], sa[0][1]), fmaxf(sa[0][2], sa[0][3])),
                         fmaxf(fmaxf(sa[1][0], sa[1][1]), fmaxf(sa[1][2], sa[1][3])));
        mx = fmaxf(mx, fmaxf(fmaxf(sa[2][0], sa[2][1]), fmaxf(sa[2][2], sa[2][3])));
        mx = fmaxf(mx, fmaxf(fmaxf(sa[3][0], sa[3][1]), fmaxf(sa[3][2], sa[3][3])));
        mx *= scale;
        mx = fmaxf(mx, __shfl_xor(mx, 16, 64));
        mx = fmaxf(mx, __shfl_xor(mx, 32, 64));
        const float nm = fmaxf(mI, mx);
        const float f = __expf(mI - nm);
        mI = nm;
        float rs = 0.f;
#pragma unroll
        for (int n = 0; n < 4; ++n)
#pragma unroll
            for (int j = 0; j < 4; ++j) {
                const float p = __expf(sa[n][j] * scale - nm);
                sa[n][j] = p;
                rs += p;
            }
        rs += __shfl_xor(rs, 16, 64);
        rs += __shfl_xor(rs, 32, 64);
        lI = lI * f + rs;
#pragma unroll
        for (int j = 0; j < 4; ++j) {
            const float fj = __shfl(f, l4 * 4 + j, 64);
#pragma unroll
            for (int n = 0; n < 4; ++n) oacc[n][j] *= fj;
        }
#pragma unroll
        for (int n = 0; n < 4; ++n) {
            union { ushort4 v; bf16 hh[4]; } pk;
            pk.hh[0] = __float2bfloat16(sa[n][0]);
            pk.hh[1] = __float2bfloat16(sa[n][1]);
            pk.hh[2] = __float2bfloat16(sa[n][2]);
            pk.hh[3] = __float2bfloat16(sa[n][3]);
            *(ushort4*)(&P[wid * 16 + l15][n * 16 + l4 * 4]) = pk.v;
        }
#pragma unroll
        for (int ks = 0; ks < 2; ++ks) {
            const short8 aP = *(const short8*)(&P[wid * 16 + l15][ks * 32 + l4 * 8]);
#pragma unroll
            for (int n = 0; n < 4; ++n) {
                const short8 bV = *(const short8*)(Vp + (size_t)(n * 16 + l15) * ldvt + kv0 + ks * 32 + l4 * 8);
                oacc[n] = __builtin_amdgcn_mfma_f32_16x16x32_bf16(aP, bV, oacc[n], 0, 0, 0);
            }
        }
    }
#pragma unroll
    for (int j = 0; j < 4; ++j) {
        const float lj = __shfl(lI, l4 * 4 + j, 64);
        const float rl = 1.f / lj;
        const size_t row = (size_t)b * SQl + q0 + wid * 16 + l4 * 4 + j;
#pragma unroll
        for (int n = 0; n < 4; ++n)
            O[row * 1024 + h * 64 + n * 16 + l15] = __float2bfloat16(oacc[n][j] * rl);
    }
}

extern "C" void kernel_launch(void* const* d_in, const int* in_sizes, int n_in,
                              void* d_out, int out_size, void* d_ws, size_t ws_size,
                              hipStream_t stream) {
    const float* queries  = (const float*)d_in[0];
    const float* contexts = (const float*)d_in[1];
    const float* sa_ln_g  = (const float*)d_in[2];
    const float* sa_ln_b  = (const float*)d_in[3];
    const float* sa_qkv_w = (const float*)d_in[4];
    const float* sa_out_w = (const float*)d_in[5];
    const float* sa_out_b = (const float*)d_in[6];
    const float* ca_ln_g  = (const float*)d_in[7];
    const float* ca_ln_b  = (const float*)d_in[8];
    const float* ca_q_w   = (const float*)d_in[9];
    const float* ca_k_w   = (const float*)d_in[10];
    const float* ca_v_w   = (const float*)d_in[11];
    const float* ca_out_w = (const float*)d_in[12];
    const float* ca_out_b = (const float*)d_in[13];
    const float* ff_ln1_g = (const float*)d_in[14];
    const float* ff_ln1_b = (const float*)d_in[15];
    const float* ff_w1    = (const float*)d_in[16];
    const float* ff_ln2_g = (const float*)d_in[17];
    const float* ff_ln2_b = (const float*)d_in[18];
    const float* ff_w2    = (const float*)d_in[19];

    float* out    = (float*)d_out;                     // 4M floats
    float* energy = out + (size_t)BB * SQ_ * CC;       // 128M floats

    const size_t MEG = 1024 * 1024;

    // ---- ws layout (float units) ----
    float* ws = (float*)d_ws;
    bf16*  X0_16      = (bf16*)ws;                                  // 8M bf16   [0,4M)
    bf16*  o16        = (bf16*)(ws + 4 * MEG);                      // 4M bf16   [4,6M)
    bf16*  ca_out_w16 = (bf16*)(ws + 6 * MEG);                      // 1M        [6,6.5M)
    bf16*  ff_w1_16   = (bf16*)(ws + (13 * MEG) / 2);               // 2M        [6.5,7.5M)
    bf16*  ff_w2_16   = (bf16*)(ws + (15 * MEG) / 2);               // 2M        [7.5,8.5M)
    bf16*  q_ca16     = (bf16*)(ws + (17 * MEG) / 2);               // 4M        [8.5,10.5M)
    bf16*  KV_ca      = (bf16*)(ws + (21 * MEG) / 2);               // 16M       [10.5,18.5M)
    bf16*  Vt_ca      = (bf16*)(ws + (37 * MEG) / 2);               // 8M        [18.5,22.5M)
    float* E_buf      = ws + (45 * MEG) / 2;                        // 4M fp32   [22.5,26.5M)
    float* C_buf      = ws + (53 * MEG) / 2;                        // 8M fp32   [26.5,34.5M)

    // ---- early scratch inside energy region (dead before CA flash) ----
    bf16* EZ         = (bf16*)energy;
    bf16* ctx16      = EZ;                 // 8M
    bf16* qkv16      = EZ + 8  * MEG;      // 12M
    bf16* Vt_sa      = EZ + 20 * MEG;      // 4M
    bf16* qkv_w16    = EZ + 24 * MEG;      // 3M
    bf16* sa_out_w16 = EZ + 27 * MEG;      // 1M
    bf16* ca_q_w16   = EZ + 28 * MEG;      // 1M
    bf16* ca_k_w16   = EZ + 29 * MEG;      // 1M (ca_k|ca_v adjacent for fused KV GEMM)
    bf16* ca_v_w16   = EZ + 30 * MEG;      // 1M

    const int M1 = BB * SQ_;   // 4096
    const int M2 = BB * SK_;   // 8192
    const dim3 thr(256);

    // ---- all conversions in one dispatch ----
    {
        CvtJobs J;
        const float* srcs[9] = { sa_qkv_w, sa_out_w, ca_q_w, ca_k_w, ca_v_w,
                                 ca_out_w, ff_w1, ff_w2, contexts };
        bf16* dsts[9] = { qkv_w16, sa_out_w16, ca_q_w16, ca_k_w16, ca_v_w16,
                          ca_out_w16, ff_w1_16, ff_w2_16, ctx16 };
        const size_t ns[9] = { 3 * MEG, 1 * MEG, 1 * MEG, 1 * MEG, 1 * MEG,
                               1 * MEG, 2 * MEG, 2 * MEG, 8 * MEG };
        int acc_n8 = 0;
        for (int j = 0; j < 9; ++j) {
            J.src[j] = srcs[j];
            J.dst[j] = dsts[j];
            acc_n8 += (int)(ns[j] / 8);
            J.end[j] = acc_n8;
        }
        J.njobs = 9;
        cvt_all<<<(acc_n8 + 255) / 256, thr, 0, stream>>>(J);
    }

    // ---- Self attention ----
    ln_kernel<1024><<<M1, thr, 0, stream>>>(queries, sa_ln_g, sa_ln_b, X0_16, 0);
    gemm_bt16<1, 128><<<dim3(3072 / 128, M1 / 128), thr, 0, stream>>>(X0_16, qkv_w16, qkv16,
                                                                      M1, 3072, 1024, nullptr, nullptr);
    transpose_v<<<dim3(M1 / 64, 1024 / 64), thr, 0, stream>>>(qkv16, 3072, 192, 128, Vt_sa, M1);
    flash_attn<false><<<dim3(SQ_ / 64, BB * HH), thr, 0, stream>>>(
        qkv16, 3072, 192, qkv16, 3072, 192, 64, Vt_sa, M1,
        o16, nullptr, SQ_, SQ_, SCALE);
    gemm_bt16<0, 64><<<dim3(1024 / 128, M1 / 64), thr, 0, stream>>>(o16, sa_out_w16, E_buf,
                                                                    M1, CC, CC, sa_out_b, queries);

    // ---- Cross attention ----
    ln_kernel<1024><<<M1, thr, 0, stream>>>(E_buf, ca_ln_g, ca_ln_b, X0_16, 0);
    gemm_bt16<1, 64><<<dim3(1024 / 128, M1 / 64), thr, 0, stream>>>(X0_16, ca_q_w16, q_ca16,
                                                                    M1, CC, CC, nullptr, nullptr);
    // fused K|V projection: B = [ca_k_w16; ca_v_w16] (adjacent), N=2048
    gemm_bt16<1, 128><<<dim3(2048 / 128, M2 / 128), thr, 0, stream>>>(ctx16, ca_k_w16, KV_ca,
                                                                      M2, 2048, 1024, nullptr, nullptr);
    transpose_v<<<dim3(M2 / 64, 1024 / 64), thr, 0, stream>>>(KV_ca, 2048, 64, 1024, Vt_ca, M2);
    flash_attn<true><<<dim3(SQ_ / 64, BB * HH), thr, 0, stream>>>(
        q_ca16, 1024, 64, KV_ca, 2048, 64, 0, Vt_ca, M2,
        o16, energy, SK_, SQ_, SCALE);
    gemm_bt16<0, 64><<<dim3(1024 / 128, M1 / 64), thr, 0, stream>>>(o16, ca_out_w16, E_buf,
                                                                    M1, CC, CC, ca_out_b, E_buf);

    // ---- FFN ----
    ln_kernel<1024><<<M1, thr, 0, stream>>>(E_buf, ff_ln1_g, ff_ln1_b, X0_16, 1);
    gemm_bt16<0, 128><<<dim3(2048 / 128, M1 / 128), thr, 0, stream>>>(X0_16, ff_w1_16, C_buf,
                                                                      M1, 2048, 1024, nullptr, nullptr);
    ln_kernel<2048><<<M1, thr, 0, stream>>>(C_buf, ff_ln2_g, ff_ln2_b, X0_16, 1);
    gemm_bt16<0, 64><<<dim3(1024 / 128, M1 / 64), thr, 0, stream>>>(X0_16, ff_w2_16, out,
                                                                    M1, CC, 2048, nullptr, E_buf);
}

// Round 10
// 652.517 us; speedup vs baseline: 5.4836x; 1.0215x over previous
//
#include <hip/hip_runtime.h>
#include <hip/hip_bf16.h>
#include <math.h>

// CrossTransformer block. Round 10: V-transpose fused into producer GEMM
// epilogues (2 fewer dispatches), bf16 FFN intermediate, exact defer-max in
// flash. B=4, SQ=1024, SK=2048, C=1024, H=16, DH=64.

namespace {
constexpr int BB  = 4;
constexpr int SQ_ = 1024;
constexpr int SK_ = 2048;
constexpr int CC  = 1024;
constexpr int HH  = 16;
constexpr float SCALE  = 0.03125f;   // 1/sqrt(1024)
constexpr float LN_EPS = 1e-5f;
}

typedef __hip_bfloat16 bf16;
typedef __attribute__((ext_vector_type(8))) short short8;
typedef __attribute__((ext_vector_type(4))) float f32x4;

__device__ __forceinline__ void gload16(const void* g, void* l) {
    __builtin_amdgcn_global_load_lds((const __attribute__((address_space(1))) unsigned int*)g,
                                     (__attribute__((address_space(3))) unsigned int*)l,
                                     16, 0, 0);
}

// ---------------- all fp32 -> bf16 conversions in one kernel ----------------
#define MAXJOBS 10
struct CvtJobs {
    const float* src[MAXJOBS];
    bf16*        dst[MAXJOBS];
    int          end[MAXJOBS];   // cumulative n8 (elements/8)
    int          njobs;
};

__global__ __launch_bounds__(256)
void cvt_all(CvtJobs J) {
    const int i = blockIdx.x * 256 + threadIdx.x;
    if (i >= J.end[J.njobs - 1]) return;
    int j = 0;
    while (i >= J.end[j]) ++j;
    const int base = j ? J.end[j - 1] : 0;
    const int k = i - base;
    const float4 a = ((const float4*)J.src[j])[2 * k];
    const float4 b = ((const float4*)J.src[j])[2 * k + 1];
    union { ushort4 v; bf16 h[4]; } lo, hi;
    lo.h[0] = __float2bfloat16(a.x); lo.h[1] = __float2bfloat16(a.y);
    lo.h[2] = __float2bfloat16(a.z); lo.h[3] = __float2bfloat16(a.w);
    hi.h[0] = __float2bfloat16(b.x); hi.h[1] = __float2bfloat16(b.y);
    hi.h[2] = __float2bfloat16(b.z); hi.h[3] = __float2bfloat16(b.w);
    ((ushort4*)J.dst[j])[2 * k]     = lo.v;
    ((ushort4*)J.dst[j])[2 * k + 1] = hi.v;
}

// ---------------- LayerNorm (+optional SiLU), bf16 out, vector loads --------
__device__ __forceinline__ float4 ld4(const float* p, int idx) {
    return ((const float4*)p)[idx];
}
__device__ __forceinline__ float4 ld4(const bf16* p, int idx) {
    const ushort4 u = ((const ushort4*)p)[idx];
    float4 r;
    r.x = __bfloat162float(*(const bf16*)&u.x);
    r.y = __bfloat162float(*(const bf16*)&u.y);
    r.z = __bfloat162float(*(const bf16*)&u.z);
    r.w = __bfloat162float(*(const bf16*)&u.w);
    return r;
}

template<int NCOLS, typename TI>
__global__ __launch_bounds__(256)
void ln_kernel(const TI* __restrict__ x, const float* __restrict__ g,
               const float* __restrict__ b, bf16* __restrict__ out, int do_silu) {
    constexpr int PER = NCOLS / 1024;   // 4-elem chunks per thread
    const size_t row = blockIdx.x;
    const TI* xr = x + row * NCOLS;
    float4 vals[PER];
    float s = 0.f, ss = 0.f;
#pragma unroll
    for (int i = 0; i < PER; ++i) {
        vals[i] = ld4(xr, threadIdx.x + i * 256);
        s  += vals[i].x + vals[i].y + vals[i].z + vals[i].w;
        ss += vals[i].x * vals[i].x + vals[i].y * vals[i].y
            + vals[i].z * vals[i].z + vals[i].w * vals[i].w;
    }
    for (int off = 32; off > 0; off >>= 1) {
        s  += __shfl_down(s, off, 64);
        ss += __shfl_down(ss, off, 64);
    }
    __shared__ float red[10];
    const int wid = threadIdx.x >> 6, lane = threadIdx.x & 63;
    if (lane == 0) { red[wid] = s; red[wid + 4] = ss; }
    __syncthreads();
    if (threadIdx.x == 0) {
        const float ts  = red[0] + red[1] + red[2] + red[3];
        const float tss = red[4] + red[5] + red[6] + red[7];
        const float mu  = ts / NCOLS;
        const float var = tss / NCOLS - mu * mu;
        red[8] = mu;
        red[9] = rsqrtf(var + LN_EPS);
    }
    __syncthreads();
    const float mu = red[8], rstd = red[9];
    bf16* outr = out + row * NCOLS;
#pragma unroll
    for (int i = 0; i < PER; ++i) {
        const int c = (threadIdx.x + i * 256) * 4;
        const float4 gg = *(const float4*)(g + c);
        const float4 bb = *(const float4*)(b + c);
        float y0 = (vals[i].x - mu) * rstd * gg.x + bb.x;
        float y1 = (vals[i].y - mu) * rstd * gg.y + bb.y;
        float y2 = (vals[i].z - mu) * rstd * gg.z + bb.z;
        float y3 = (vals[i].w - mu) * rstd * gg.w + bb.w;
        if (do_silu) {
            y0 = y0 / (1.f + __expf(-y0));
            y1 = y1 / (1.f + __expf(-y1));
            y2 = y2 / (1.f + __expf(-y2));
            y3 = y3 / (1.f + __expf(-y3));
        }
        union { ushort4 v; bf16 h[4]; } pk;
        pk.h[0] = __float2bfloat16(y0); pk.h[1] = __float2bfloat16(y1);
        pk.h[2] = __float2bfloat16(y2); pk.h[3] = __float2bfloat16(y3);
        *(ushort4*)(outr + c) = pk.v;
    }
}

// ------------- bf16 MFMA GEMM: C[M,N] = A[M,K] @ B[N,K]^T (+bias)(+resid) ---
// 2-phase double-buffered K-loop. BMT = 128 (2x2 waves) or 64 (1x4 waves,
// doubled grid for latency hiding). XCD-swizzled blockIdx (grids %8==0).
// VMODE (OUT16 only): v-columns are written TRANSPOSED into Vt instead of C.
//   VMODE 1 (qkv): col%192>=128 -> Vt[(col/192)*64 + col%192-128][row]
//   VMODE 2 (kv):  col>=1024    -> Vt[col-1024][row]
template<int OUT16, int BMT, int VMODE>
__global__ __launch_bounds__(256)
void gemm_bt16(const bf16* __restrict__ A, const bf16* __restrict__ B,
               void* __restrict__ Cv, int M, int N, int K,
               const float* __restrict__ bias, const float* __restrict__ resid,
               bf16* __restrict__ Vt, int ldt) {
    constexpr int WC = (BMT == 128) ? 2 : 4;   // waves in N dir
    constexpr int NF = (BMT == 128) ? 4 : 2;   // 16-col fragments per wave
    __shared__ bf16 As[2][BMT * 32];
    __shared__ bf16 Bs[2][128 * 32];
    const int tid  = threadIdx.x;
    const int lane = tid & 63;
    const int w    = tid >> 6;
    const int wr = w / WC, wc = w % WC;

    const int nwg = gridDim.x * gridDim.y;
    const int bid = blockIdx.x + gridDim.x * blockIdx.y;
    const int logical = (bid & 7) * (nwg >> 3) + (bid >> 3);
    const int m0 = (logical / gridDim.x) * BMT;
    const int n0 = (logical % gridDim.x) * 128;

    f32x4 acc[4][NF] = {};

    const int srow = tid >> 2;
    const int scol = (tid & 3) * 8;
    const bf16* Ap  = A + (size_t)(m0 + srow) * K + scol;
    const bf16* Ap2 = Ap + (size_t)64 * K;      // used only when BMT==128
    const bf16* Bp  = B + (size_t)(n0 + srow) * K + scol;
    const bf16* Bp2 = Bp + (size_t)64 * K;

    const int arow = wr * 64 + (lane & 15);
    const int brow = wc * (NF * 16) + (lane & 15);
    const int kgrp = (lane >> 4) * 16;

    auto stage = [&](int buf, int k0) {
        char* AsB = (char*)As[buf] + w * 1024;
        char* BsB = (char*)Bs[buf] + w * 1024;
        gload16(Ap  + k0, AsB);
        if (BMT == 128) gload16(Ap2 + k0, AsB + 4096);
        gload16(Bp  + k0, BsB);
        gload16(Bp2 + k0, BsB + 4096);
    };

    const int nt = K >> 5;
    stage(0, 0);
    __syncthreads();
    for (int t = 0; t < nt; ++t) {
        if (t + 1 < nt) stage((t + 1) & 1, (t + 1) << 5);
        const char* Ab = (const char*)As[t & 1];
        const char* Bb = (const char*)Bs[t & 1];
        short8 aF[4], bF[NF];
#pragma unroll
        for (int m = 0; m < 4; ++m)
            aF[m] = *(const short8*)(Ab + ((arow + m * 16) * 64 + kgrp));
#pragma unroll
        for (int n = 0; n < NF; ++n)
            bF[n] = *(const short8*)(Bb + ((brow + n * 16) * 64 + kgrp));
#pragma unroll
        for (int m = 0; m < 4; ++m)
#pragma unroll
            for (int n = 0; n < NF; ++n)
                acc[m][n] = __builtin_amdgcn_mfma_f32_16x16x32_bf16(aF[m], bF[n], acc[m][n], 0, 0, 0);
        __syncthreads();   // drains vmcnt(0): tile t+1 landed; reads of tile t done
    }

    const int crow0 = m0 + wr * 64 + (lane >> 4) * 4;
    const int ccol0 = n0 + wc * (NF * 16) + (lane & 15);
#pragma unroll
    for (int m = 0; m < 4; ++m) {
#pragma unroll
        for (int n = 0; n < NF; ++n) {
            const int col = ccol0 + n * 16;
            const int row0 = crow0 + m * 16;
            if (OUT16) {
                int vrow = -1;
                if (VMODE == 1) {
                    const int r = col % 192;
                    if (r >= 128) vrow = (col / 192) * 64 + r - 128;
                } else if (VMODE == 2) {
                    if (col >= 1024) vrow = col - 1024;
                }
                union { ushort4 v; bf16 h[4]; } pk;
#pragma unroll
                for (int j = 0; j < 4; ++j) pk.h[j] = __float2bfloat16(acc[m][n][j]);
                if (VMODE && vrow >= 0) {
                    *(ushort4*)(Vt + (size_t)vrow * ldt + row0) = pk.v;
                } else {
#pragma unroll
                    for (int j = 0; j < 4; ++j)
                        ((bf16*)Cv)[(size_t)(row0 + j) * N + col] = pk.h[j];
                }
            } else {
                const float bv = bias ? bias[col] : 0.f;
#pragma unroll
                for (int j = 0; j < 4; ++j) {
                    const int row = row0 + j;
                    float v = acc[m][n][j] + bv;
                    if (resid) v += resid[(size_t)row * N + col];
                    ((float*)Cv)[(size_t)row * N + col] = v;
                }
            }
        }
    }
}

// --------------- fused flash attention (swapped QK^T, KV tile 64) -----------
// 64 q-rows per block, 4 waves x 16 rows, DH=64, H=16. S^T = mfma(K, Q):
// per lane q = l15, kv = n*16 + l4*4 + reg -> energy is a direct f32x4 NT
// store. Exact defer-max: rescale only when a lane's tile max grew.
template<bool ENERGY>
__global__ __launch_bounds__(256, 4)
void flash_attn(const bf16* __restrict__ Qb, int ldq, int qh_str,
                const bf16* __restrict__ Kb, int ldk, int kh_str, int kh_add,
                const bf16* __restrict__ Vt, int ldvt,
                bf16* __restrict__ O, float* __restrict__ energy,
                int SKV, int SQl, float scale) {
    __shared__ bf16 P[64][136];
    const int tid = threadIdx.x;
    const int lane = tid & 63, wid = tid >> 6;
    const int l15 = lane & 15, l4 = lane >> 4;

    // XCD-aware remap (nwg % 8 == 0)
    const int gx  = gridDim.x;
    const int nwg = gx * gridDim.y;
    const int bid = blockIdx.x + gx * blockIdx.y;
    const int logical = (bid & 7) * (nwg >> 3) + (bid >> 3);
    const int xq = logical % gx;
    const int z  = logical / gx;

    const int b = z >> 4, h = z & 15;
    const int q0 = xq * 64;

    const bf16* Qp = Qb + (size_t)b * SQl * ldq + (size_t)h * qh_str;
    const bf16* Kp = Kb + (size_t)b * SKV * ldk + (size_t)h * kh_str + kh_add;
    const bf16* Vp = Vt + (size_t)h * 64 * ldvt + (size_t)b * SKV;

    short8 aQ[2];
#pragma unroll
    for (int s = 0; s < 2; ++s)
        aQ[s] = *(const short8*)(Qp + (size_t)(q0 + wid * 16 + l15) * ldq + s * 32 + l4 * 8);

    f32x4 oacc[4] = {};
    float mI = -1e30f, lI = 0.f;

    for (int kv0 = 0; kv0 < SKV; kv0 += 64) {
        f32x4 sa[4] = {};
#pragma unroll
        for (int n = 0; n < 4; ++n) {
            const bf16* kr = Kp + (size_t)(kv0 + n * 16 + l15) * ldk + l4 * 8;
            const short8 b0 = *(const short8*)(kr);
            const short8 b1 = *(const short8*)(kr + 32);
            sa[n] = __builtin_amdgcn_mfma_f32_16x16x32_bf16(b0, aQ[0], sa[n], 0, 0, 0);
            sa[n] = __builtin_amdgcn_mfma_f32_16x16x32_bf16(b1, aQ[1], sa[n], 0, 0, 0);
        }
        if (ENERGY) {
            float* er = energy + (size_t)z * SQl * SKV
                      + (size_t)(q0 + wid * 16 + l15) * SKV + kv0 + l4 * 4;
#pragma unroll
            for (int n = 0; n < 4; ++n)
                __builtin_nontemporal_store(sa[n], (f32x4*)(er + n * 16));
        }
        // ---- online softmax, exact defer-max ----
        float mx = fmaxf(fmaxf(fmaxf(sa[0][0], sa[0][1]), fmaxf(sa[0][2], sa[0][3])),
                         fmaxf(fmaxf(sa[1][0], sa[1][1]), fmaxf(sa[1][2], sa[1][3])));
        mx = fmaxf(mx, fmaxf(fmaxf(sa[2][0], sa[2][1]), fmaxf(sa[2][2], sa[2][3])));
        mx = fmaxf(mx, fmaxf(fmaxf(sa[3][0], sa[3][1]), fmaxf(sa[3][2], sa[3][3])));
        mx *= scale;
        mx = fmaxf(mx, __shfl_xor(mx, 16, 64));
        mx = fmaxf(mx, __shfl_xor(mx, 32, 64));
        if (__any(mx > mI)) {          // rescale needed (f != 1 for some row)
            const float nm = fmaxf(mI, mx);
            const float f = __expf(mI - nm);
            mI = nm;
            lI *= f;
#pragma unroll
            for (int j = 0; j < 4; ++j) {
                const float fj = __shfl(f, l4 * 4 + j, 64);
#pragma unroll
                for (int n = 0; n < 4; ++n) oacc[n][j] *= fj;
            }
        }
        float rs = 0.f;
#pragma unroll
        for (int n = 0; n < 4; ++n)
#pragma unroll
            for (int j = 0; j < 4; ++j) {
                const float p = __expf(sa[n][j] * scale - mI);
                sa[n][j] = p;
                rs += p;
            }
        rs += __shfl_xor(rs, 16, 64);
        rs += __shfl_xor(rs, 32, 64);
        lI += rs;
#pragma unroll
        for (int n = 0; n < 4; ++n) {
            union { ushort4 v; bf16 hh[4]; } pk;
            pk.hh[0] = __float2bfloat16(sa[n][0]);
            pk.hh[1] = __float2bfloat16(sa[n][1]);
            pk.hh[2] = __float2bfloat16(sa[n][2]);
            pk.hh[3] = __float2bfloat16(sa[n][3]);
            *(ushort4*)(&P[wid * 16 + l15][n * 16 + l4 * 4]) = pk.v;
        }
#pragma unroll
        for (int ks = 0; ks < 2; ++ks) {
            const short8 aP = *(const short8*)(&P[wid * 16 + l15][ks * 32 + l4 * 8]);
#pragma unroll
            for (int n = 0; n < 4; ++n) {
                const short8 bV = *(const short8*)(Vp + (size_t)(n * 16 + l15) * ldvt + kv0 + ks * 32 + l4 * 8);
                oacc[n] = __builtin_amdgcn_mfma_f32_16x16x32_bf16(aP, bV, oacc[n], 0, 0, 0);
            }
        }
    }
#pragma unroll
    for (int j = 0; j < 4; ++j) {
        const float lj = __shfl(lI, l4 * 4 + j, 64);
        const float rl = 1.f / lj;
        const size_t row = (size_t)b * SQl + q0 + wid * 16 + l4 * 4 + j;
#pragma unroll
        for (int n = 0; n < 4; ++n)
            O[row * 1024 + h * 64 + n * 16 + l15] = __float2bfloat16(oacc[n][j] * rl);
    }
}

extern "C" void kernel_launch(void* const* d_in, const int* in_sizes, int n_in,
                              void* d_out, int out_size, void* d_ws, size_t ws_size,
                              hipStream_t stream) {
    const float* queries  = (const float*)d_in[0];
    const float* contexts = (const float*)d_in[1];
    const float* sa_ln_g  = (const float*)d_in[2];
    const float* sa_ln_b  = (const float*)d_in[3];
    const float* sa_qkv_w = (const float*)d_in[4];
    const float* sa_out_w = (const float*)d_in[5];
    const float* sa_out_b = (const float*)d_in[6];
    const float* ca_ln_g  = (const float*)d_in[7];
    const float* ca_ln_b  = (const float*)d_in[8];
    const float* ca_q_w   = (const float*)d_in[9];
    const float* ca_k_w   = (const float*)d_in[10];
    const float* ca_v_w   = (const float*)d_in[11];
    const float* ca_out_w = (const float*)d_in[12];
    const float* ca_out_b = (const float*)d_in[13];
    const float* ff_ln1_g = (const float*)d_in[14];
    const float* ff_ln1_b = (const float*)d_in[15];
    const float* ff_w1    = (const float*)d_in[16];
    const float* ff_ln2_g = (const float*)d_in[17];
    const float* ff_ln2_b = (const float*)d_in[18];
    const float* ff_w2    = (const float*)d_in[19];

    float* out    = (float*)d_out;                     // 4M floats
    float* energy = out + (size_t)BB * SQ_ * CC;       // 128M floats

    const size_t MEG = 1024 * 1024;

    // ---- ws layout (float units) ----
    float* ws = (float*)d_ws;
    bf16*  X0_16      = (bf16*)ws;                                  // 8M bf16   [0,4M)
    bf16*  o16        = (bf16*)(ws + 4 * MEG);                      // 4M bf16   [4,6M)
    bf16*  ca_out_w16 = (bf16*)(ws + 6 * MEG);                      // 1M        [6,6.5M)
    bf16*  ff_w1_16   = (bf16*)(ws + (13 * MEG) / 2);               // 2M        [6.5,7.5M)
    bf16*  ff_w2_16   = (bf16*)(ws + (15 * MEG) / 2);               // 2M        [7.5,8.5M)
    bf16*  q_ca16     = (bf16*)(ws + (17 * MEG) / 2);               // 4M        [8.5,10.5M)
    bf16*  KV_ca      = (bf16*)(ws + (21 * MEG) / 2);               // 16M       [10.5,18.5M)
    bf16*  Vt_ca      = (bf16*)(ws + (37 * MEG) / 2);               // 8M        [18.5,22.5M)
    float* E_buf      = ws + (45 * MEG) / 2;                        // 4M fp32   [22.5,26.5M)
    float* C_buf      = ws + (53 * MEG) / 2;                        // 8M fp32   [26.5,34.5M)
    bf16*  C_buf16    = (bf16*)C_buf;                               // 8M bf16 (FFN mid)

    // ---- early scratch inside energy region (dead before CA flash) ----
    bf16* EZ         = (bf16*)energy;
    bf16* ctx16      = EZ;                 // 8M
    bf16* qkv16      = EZ + 8  * MEG;      // 12M (v-cols unwritten; Q/K only)
    bf16* Vt_sa      = EZ + 20 * MEG;      // 4M
    bf16* qkv_w16    = EZ + 24 * MEG;      // 3M
    bf16* sa_out_w16 = EZ + 27 * MEG;      // 1M
    bf16* ca_q_w16   = EZ + 28 * MEG;      // 1M
    bf16* ca_k_w16   = EZ + 29 * MEG;      // 1M (ca_k|ca_v adjacent for fused KV GEMM)
    bf16* ca_v_w16   = EZ + 30 * MEG;      // 1M

    const int M1 = BB * SQ_;   // 4096
    const int M2 = BB * SK_;   // 8192
    const dim3 thr(256);

    // ---- all conversions in one dispatch ----
    {
        CvtJobs J;
        const float* srcs[9] = { sa_qkv_w, sa_out_w, ca_q_w, ca_k_w, ca_v_w,
                                 ca_out_w, ff_w1, ff_w2, contexts };
        bf16* dsts[9] = { qkv_w16, sa_out_w16, ca_q_w16, ca_k_w16, ca_v_w16,
                          ca_out_w16, ff_w1_16, ff_w2_16, ctx16 };
        const size_t ns[9] = { 3 * MEG, 1 * MEG, 1 * MEG, 1 * MEG, 1 * MEG,
                               1 * MEG, 2 * MEG, 2 * MEG, 8 * MEG };
        int acc_n8 = 0;
        for (int j = 0; j < 9; ++j) {
            J.src[j] = srcs[j];
            J.dst[j] = dsts[j];
            acc_n8 += (int)(ns[j] / 8);
            J.end[j] = acc_n8;
        }
        J.njobs = 9;
        cvt_all<<<(acc_n8 + 255) / 256, thr, 0, stream>>>(J);
    }

    // ---- Self attention ----
    ln_kernel<1024, float><<<M1, thr, 0, stream>>>(queries, sa_ln_g, sa_ln_b, X0_16, 0);
    // qkv projection; v columns go straight to Vt_sa (transposed)
    gemm_bt16<1, 128, 1><<<dim3(3072 / 128, M1 / 128), thr, 0, stream>>>(
        X0_16, qkv_w16, qkv16, M1, 3072, 1024, nullptr, nullptr, Vt_sa, M1);
    flash_attn<false><<<dim3(SQ_ / 64, BB * HH), thr, 0, stream>>>(
        qkv16, 3072, 192, qkv16, 3072, 192, 64, Vt_sa, M1,
        o16, nullptr, SQ_, SQ_, SCALE);
    gemm_bt16<0, 64, 0><<<dim3(1024 / 128, M1 / 64), thr, 0, stream>>>(
        o16, sa_out_w16, E_buf, M1, CC, CC, sa_out_b, queries, nullptr, 0);

    // ---- Cross attention ----
    ln_kernel<1024, float><<<M1, thr, 0, stream>>>(E_buf, ca_ln_g, ca_ln_b, X0_16, 0);
    gemm_bt16<1, 64, 0><<<dim3(1024 / 128, M1 / 64), thr, 0, stream>>>(
        X0_16, ca_q_w16, q_ca16, M1, CC, CC, nullptr, nullptr, nullptr, 0);
    // fused K|V projection: B = [ca_k_w16; ca_v_w16]; V half transposed to Vt_ca
    gemm_bt16<1, 128, 2><<<dim3(2048 / 128, M2 / 128), thr, 0, stream>>>(
        ctx16, ca_k_w16, KV_ca, M2, 2048, 1024, nullptr, nullptr, Vt_ca, M2);
    flash_attn<true><<<dim3(SQ_ / 64, BB * HH), thr, 0, stream>>>(
        q_ca16, 1024, 64, KV_ca, 2048, 64, 0, Vt_ca, M2,
        o16, energy, SK_, SQ_, SCALE);
    gemm_bt16<0, 64, 0><<<dim3(1024 / 128, M1 / 64), thr, 0, stream>>>(
        o16, ca_out_w16, E_buf, M1, CC, CC, ca_out_b, E_buf, nullptr, 0);

    // ---- FFN ----
    ln_kernel<1024, float><<<M1, thr, 0, stream>>>(E_buf, ff_ln1_g, ff_ln1_b, X0_16, 1);
    gemm_bt16<1, 128, 0><<<dim3(2048 / 128, M1 / 128), thr, 0, stream>>>(
        X0_16, ff_w1_16, C_buf16, M1, 2048, 1024, nullptr, nullptr, nullptr, 0);
    ln_kernel<2048, bf16><<<M1, thr, 0, stream>>>(C_buf16, ff_ln2_g, ff_ln2_b, X0_16, 1);
    gemm_bt16<0, 64, 0><<<dim3(1024 / 128, M1 / 64), thr, 0, stream>>>(
        X0_16, ff_w2_16, out, M1, CC, 2048, nullptr, E_buf, nullptr, 0);
}